// Round 5
// baseline (414.107 us; speedup 1.0000x reference)
//
#include <hip/hip_runtime.h>
#include <math.h>

#define B_ 4
#define C_ 512
#define L_ 4096
#define H_ 8
#define DH_ 64
#define MLP_ 2048
#define BL_ (B_*L_)      // 16384
#define LK_ (L_+1)       // 4097

typedef _Float16 f16;
typedef _Float16 f16x8 __attribute__((ext_vector_type(8)));
typedef _Float16 f16x4 __attribute__((ext_vector_type(4)));
typedef float f32x4 __attribute__((ext_vector_type(4)));

// async global->LDS, 16B per lane (m97 pattern)
__device__ __forceinline__ void gl16(void* lds, const void* g) {
  __builtin_amdgcn_global_load_lds((const __attribute__((address_space(1))) void*)g,
                                   (__attribute__((address_space(3))) void*)lds,
                                   16, 0, 0);
}

__device__ __forceinline__ float frcp(float x) { return __builtin_amdgcn_rcpf(x); }

// ---------------------------------------------------------------- transposes
// z-merged 512x512 weight transposes; outputs contiguous at dst + z*C*C
__global__ __launch_bounds__(256) void transpose_w5(const float* __restrict__ Wq,
                                                    const float* __restrict__ Wk,
                                                    const float* __restrict__ Wv,
                                                    const float* __restrict__ Wkq,
                                                    const float* __restrict__ Wkk,
                                                    f16* __restrict__ dst) {
  int z = blockIdx.z;
  const float* W = (z == 0) ? Wq : (z == 1) ? Wk : (z == 2) ? Wv : (z == 3) ? Wkq : Wkk;
  f16* Wt = dst + (size_t)z * C_ * C_;
  __shared__ float tile[32][33];
  int n0 = blockIdx.x * 32, k0 = blockIdx.y * 32;
  int tx = threadIdx.x & 31, ty = threadIdx.x >> 5;
#pragma unroll
  for (int i = 0; i < 4; ++i)
    tile[ty + i * 8][tx] = W[(size_t)(k0 + ty + i * 8) * C_ + n0 + tx];
  __syncthreads();
#pragma unroll
  for (int i = 0; i < 4; ++i)
    Wt[(size_t)(n0 + ty + i * 8) * C_ + k0 + tx] = (f16)tile[tx][ty + i * 8];
}

__global__ __launch_bounds__(256) void transpose_w(const float* __restrict__ W,
                                                   f16* __restrict__ Wt, int K, int N) {
  __shared__ float tile[32][33];
  int n0 = blockIdx.x * 32, k0 = blockIdx.y * 32;
  int tx = threadIdx.x & 31, ty = threadIdx.x >> 5;
#pragma unroll
  for (int i = 0; i < 4; ++i)
    tile[ty + i * 8][tx] = W[(size_t)(k0 + ty + i * 8) * N + n0 + tx];
  __syncthreads();
#pragma unroll
  for (int i = 0; i < 4; ++i)
    Wt[(size_t)(n0 + ty + i * 8) * K + k0 + tx] = (f16)tile[tx][ty + i * 8];
}

__global__ __launch_bounds__(256) void transpose_x(const float* __restrict__ x,
                                                   f16* __restrict__ xf) {
  __shared__ float tile[32][33];
  int b = blockIdx.z;
  int l0 = blockIdx.x * 32, c0 = blockIdx.y * 32;
  int tx = threadIdx.x & 31, ty = threadIdx.x >> 5;
#pragma unroll
  for (int i = 0; i < 4; ++i)
    tile[ty + i * 8][tx] = x[((size_t)b * C_ + c0 + ty + i * 8) * L_ + l0 + tx];
  __syncthreads();
#pragma unroll
  for (int i = 0; i < 4; ++i)
    xf[((size_t)b * L_ + l0 + ty + i * 8) * C_ + c0 + tx] = (f16)tile[tx][ty + i * 8];
}

// ------------------------------------------------- pack small param vectors
__global__ __launch_bounds__(256) void pack_params(
    const float* bq, const float* bk, const float* bv,
    const float* gq, const float* gk, const float* gv,
    const float* betaq, const float* betak, const float* betav,
    const float* bkq, const float* bkk,
    float* bqkv, float* gqkv, float* betaqkv, float* bphi) {
  int i = blockIdx.x * 256 + threadIdx.x;  // 0..1535
  int w = i >> 9, c = i & 511;
  bqkv[i]    = (w == 0 ? bq : (w == 1 ? bk : bv))[c];
  gqkv[i]    = (w == 0 ? gq : (w == 1 ? gk : gv))[c];
  betaqkv[i] = (w == 0 ? betaq : (w == 1 ? betak : betav))[c];
  if (i < 1024) bphi[i] = (i < 512) ? bkq[i] : bkk[i - 512];
}

// ---------------------------------------------------------------- GEMM (MFMA)
// C[M,N](f16) = act(A[M,K] @ Bt[N,K]^T + bias)
// BK=64, double-buffered LDS (prefetch after barrier -> loads overlap MFMA),
// XOR-swizzled k-chunks (conflict-free ds_read_b128), LDS-transposed epilogue.
// (round-0 verified config, 393 us total baseline)
// EPI: 1 tanh(v)+1   2 gelu (tanh approx)   5 plain bias
//      6 plain bias + a-residual + transposed f32 out (+x)    [MLP-down fusion]
template <int EPI>
__global__ __launch_bounds__(256, 2) void gemm64(const f16* __restrict__ A,
                                                 const f16* __restrict__ Bt,
                                                 const float* __restrict__ bias,
                                                 f16* __restrict__ Ch,
                                                 int N, int K,
                                                 const f16* __restrict__ Ares,
                                                 const float* __restrict__ Xres,
                                                 float* __restrict__ Fout,
                                                 long long zA, long long zB,
                                                 long long zC, long long zBias) {
  __shared__ f16 smem[2 * 128 * 128];  // 64 KB: [As|Bs] x 2 buffers; epi: [128][128]
  A  += (size_t)blockIdx.z * zA;
  Bt += (size_t)blockIdx.z * zB;
  if (EPI != 6) Ch += (size_t)blockIdx.z * zC;
  bias += (size_t)blockIdx.z * zBias;

  const int tid = threadIdx.x;
  const int lane = tid & 63, wv = tid >> 6;
  const int wm = wv >> 1, wn = wv & 1;
  const int bm = blockIdx.x * 128, bn = blockIdx.y * 128;
  const int l15 = lane & 15, q = lane >> 4;

  // staging: inst p covers rows p*32+(tid>>3); lane fetches global k-chunk
  // (tid&7)^(row&7) into LDS slot tid*16B -> LDS[r][c] holds chunk c^(r&7)
  const int srow = tid >> 3;
  const int schunk = (tid & 7) ^ (srow & 7);
  const f16* pa = A + (size_t)(bm + srow) * K + schunk * 8;
  const f16* pb = Bt + (size_t)(bn + srow) * K + schunk * 8;
  f16* la = smem + tid * 8;
  f16* lb = smem + 8192 + tid * 8;
  const int sw0 = (q ^ (lane & 7)) * 8;        // frag read swizzle, ks=0
  const int sw1 = ((4 + q) ^ (lane & 7)) * 8;  // ks=1

  f32x4 acc[4][4] = {};

  // prologue: fill buffer 0
#pragma unroll
  for (int p = 0; p < 4; ++p) gl16(la + p * 2048, pa + (size_t)p * 32 * K);
#pragma unroll
  for (int p = 0; p < 4; ++p) gl16(lb + p * 2048, pb + (size_t)p * 32 * K);

  int cur = 0;
  for (int k0 = 0; k0 < K; k0 += 64) {
    __syncthreads();                 // vmcnt(0) drain: buf(cur) staged; buf(nxt) readers done
    const int nxt = cur ^ 1;
    if (k0 + 64 < K) {               // prefetch next chunk into the other buffer
#pragma unroll
      for (int p = 0; p < 4; ++p) gl16(la + nxt * 16384 + p * 2048, pa + (size_t)p * 32 * K + k0 + 64);
#pragma unroll
      for (int p = 0; p < 4; ++p) gl16(lb + nxt * 16384 + p * 2048, pb + (size_t)p * 32 * K + k0 + 64);
    }
    const f16* As = smem + cur * 16384;
    const f16* Bs = As + 8192;
#pragma unroll
    for (int ks = 0; ks < 2; ++ks) {
      const int sw = ks ? sw1 : sw0;
      f16x8 af[4], bf[4];
#pragma unroll
      for (int i = 0; i < 4; ++i)
        af[i] = *(const f16x8*)&As[(wm * 64 + i * 16 + l15) * 64 + sw];
#pragma unroll
      for (int j = 0; j < 4; ++j)
        bf[j] = *(const f16x8*)&Bs[(wn * 64 + j * 16 + l15) * 64 + sw];
#pragma unroll
      for (int i = 0; i < 4; ++i)
#pragma unroll
        for (int j = 0; j < 4; ++j)
          acc[i][j] = __builtin_amdgcn_mfma_f32_16x16x32_f16(af[i], bf[j], acc[i][j], 0, 0, 0);
    }
    cur = nxt;
  }

  // ---- epilogue: act -> smem[0..16K) (col-chunk XOR swizzle)
  __syncthreads();
#pragma unroll
  for (int j = 0; j < 4; ++j) {
    int lc = wn * 64 + j * 16 + l15;
    float bb = bias[bn + lc];
#pragma unroll
    for (int i = 0; i < 4; ++i) {
#pragma unroll
      for (int r = 0; r < 4; ++r) {
        int lr = wm * 64 + i * 16 + q * 4 + r;
        float v = acc[i][j][r] + bb;
        if (EPI == 1) {
          v = 2.0f * frcp(1.0f + __expf(-2.0f * v));      // tanh(v)+1
        } else if (EPI == 2) {
          v = v * frcp(1.0f + __expf(-1.5957691f * (v + 0.044715f * v * v * v)));
        }
        smem[lr * 128 + ((((lc >> 3) ^ (lr & 15)) << 3) | (lc & 7))] = (f16)v;
      }
    }
  }
  __syncthreads();

  if (EPI != 6) {
    // coalesced f16x8 row store
#pragma unroll
    for (int p = 0; p < 8; ++p) {
      int idx = p * 256 + tid;
      int row = idx >> 4, ch = idx & 15;
      f16x8 vv = *(const f16x8*)&smem[row * 128 + ((ch ^ (row & 15)) << 3)];
      *(f16x8*)&Ch[(size_t)(bm + row) * N + bn + ch * 8] = vv;
    }
  } else {
    // add a-residual (row-coalesced RMW in LDS)
#pragma unroll
    for (int p = 0; p < 8; ++p) {
      int idx = p * 256 + tid;
      int row = idx >> 4, ch = idx & 15;
      f16x8 av = *(const f16x8*)&Ares[(size_t)(bm + row) * C_ + bn + ch * 8];
      f16* sp = &smem[row * 128 + ((ch ^ (row & 15)) << 3)];
      f16x8 sv = *(const f16x8*)sp;
#pragma unroll
      for (int jj = 0; jj < 8; ++jj) sv[jj] = (f16)((float)sv[jj] + (float)av[jj]);
      *(f16x8*)sp = sv;
    }
    __syncthreads();
    // transposed f32 write: out[b][c][l] = tile[l][c] + x[b][c][l]
    int c = tid & 127, lh = tid >> 7;
    int b = bm >> 12, lbase = (bm & 4095) + lh * 64;
    const float* xp = Xres + ((size_t)b * C_ + bn + c) * L_ + lbase;
    float* op = Fout + ((size_t)b * C_ + bn + c) * L_ + lbase;
    int chi = c >> 3, clo = c & 7;
#pragma unroll
    for (int s = 0; s < 16; ++s) {
      int l = lh * 64 + s * 4;
      float4 xv = *(const float4*)(xp + s * 4);
      float4 r;
      r.x = (float)smem[(l + 0) * 128 + (((chi ^ ((l + 0) & 15)) << 3) | clo)] + xv.x;
      r.y = (float)smem[(l + 1) * 128 + (((chi ^ ((l + 1) & 15)) << 3) | clo)] + xv.y;
      r.z = (float)smem[(l + 2) * 128 + (((chi ^ ((l + 2) & 15)) << 3) | clo)] + xv.z;
      r.w = (float)smem[(l + 3) * 128 + (((chi ^ ((l + 3) & 15)) << 3) | clo)] + xv.w;
      *(float4*)(op + s * 4) = r;
    }
  }
}

// ---------------------------------------------------------------- attention out
// O[l, h*64+e] = (sum_d phiQ[l, h*64+d] * kvT[b][h][e][d]) / (bot[l,h] + 1e-6)
// Exploits the block-diagonal structure: per-head K=64 GEMM (8x fewer FLOPs
// than the dense 512x512 block-diagonal form; HBM-bound ~32 MB).
// Grid (BL/128, H), 256 thr. Same staging/read XOR swizzle as gemm64 (K=64
// = one BK=64 step, conflict-free verified).
__global__ __launch_bounds__(256, 4) void attn_out(const f16* __restrict__ phiQ,
                                                   const f16* __restrict__ kvt,
                                                   const float* __restrict__ bot,
                                                   f16* __restrict__ Ch) {
  __shared__ f16 smem[12288];  // As [128][64] (16 KB) + Bs [64][64] (8 KB); epi reuses As
  const int tid = threadIdx.x;
  const int lane = tid & 63, wv = tid >> 6;
  const int bm = blockIdx.x * 128;     // token tile (over BL)
  const int h = blockIdx.y;
  const int b = bm >> 12;
  const int l15 = lane & 15, q = lane >> 4;

  const int srow = tid >> 3;                       // 0..31
  const int schunk = (tid & 7) ^ (srow & 7);
  const f16* pa = phiQ + (size_t)(bm + srow) * C_ + h * DH_ + schunk * 8;
  const f16* pb = kvt + ((size_t)(b * H_ + h) * DH_ + srow) * DH_ + schunk * 8;
  f16* la = smem + tid * 8;
  f16* lb = smem + 8192 + tid * 8;
  const int sw0 = (q ^ (lane & 7)) * 8;
  const int sw1 = ((4 + q) ^ (lane & 7)) * 8;

  // stage A tile (128x64) + B tile (64x64)
#pragma unroll
  for (int p = 0; p < 4; ++p) gl16(la + p * 2048, pa + (size_t)p * 32 * C_);
#pragma unroll
  for (int p = 0; p < 2; ++p) gl16(lb + p * 2048, pb + (size_t)p * 32 * DH_);
  __syncthreads();

  // wave wv: rows wv*32 + i*16, all 64 cols (4 j-tiles); K=64 = 2 ks
  f32x4 acc[2][4] = {};
#pragma unroll
  for (int ks = 0; ks < 2; ++ks) {
    const int sw = ks ? sw1 : sw0;
    f16x8 af[2], bf[4];
#pragma unroll
    for (int i = 0; i < 2; ++i)
      af[i] = *(const f16x8*)&smem[(wv * 32 + i * 16 + l15) * 64 + sw];
#pragma unroll
    for (int j = 0; j < 4; ++j)
      bf[j] = *(const f16x8*)&smem[8192 + (j * 16 + l15) * 64 + sw];
#pragma unroll
    for (int i = 0; i < 2; ++i)
#pragma unroll
      for (int j = 0; j < 4; ++j)
        acc[i][j] = __builtin_amdgcn_mfma_f32_16x16x32_f16(af[i], bf[j], acc[i][j], 0, 0, 0);
  }
  __syncthreads();

  // epilogue: divide by bottom, swizzled LDS transpose
#pragma unroll
  for (int j = 0; j < 4; ++j) {
    int lc = j * 16 + l15;
#pragma unroll
    for (int i = 0; i < 2; ++i) {
#pragma unroll
      for (int r = 0; r < 4; ++r) {
        int lr = wv * 32 + i * 16 + q * 4 + r;
        float v = acc[i][j][r] * frcp(bot[(size_t)(bm + lr) * H_ + h] + 1e-6f);
        smem[lr * 64 + ((((lc >> 3) ^ (lr & 7)) << 3) | (lc & 7))] = (f16)v;
      }
    }
  }
  __syncthreads();

  // coalesced f16x8 stores into the head's column slice
#pragma unroll
  for (int p = 0; p < 4; ++p) {
    int idx = p * 256 + tid;
    int row = idx >> 3, ch = idx & 7;
    f16x8 vv = *(const f16x8*)&smem[row * 64 + ((ch ^ (row & 7)) << 3)];
    *(f16x8*)&Ch[(size_t)(bm + row) * C_ + h * DH_ + ch * 8] = vv;
  }
}

// ---------------------------------------------------------------- LayerNorm (f16 in/out)
// threeway=1: X is [49152][512] rows (token*3+which); out which*BL + token.
__global__ __launch_bounds__(256) void ln16(const f16* __restrict__ X,
                                            const float* __restrict__ g,
                                            const float* __restrict__ bta,
                                            f16* __restrict__ Y, int threeway) {
  int wv = threadIdx.x >> 6, lane = threadIdx.x & 63;
  int r = blockIdx.x * 4 + wv;
  int token = r, which = 0;
  if (threeway) { token = r / 3; which = r - token * 3; }
  const f16* xr = X + (size_t)r * C_;
  f16x8 v = *(const f16x8*)(xr + lane * 8);
  float vals[8];
  float s = 0.f, s2 = 0.f;
#pragma unroll
  for (int j = 0; j < 8; ++j) { vals[j] = (float)v[j]; s += vals[j]; s2 += vals[j] * vals[j]; }
#pragma unroll
  for (int m_ = 1; m_ < 64; m_ <<= 1) { s += __shfl_xor(s, m_); s2 += __shfl_xor(s2, m_); }
  float mu = s * (1.f / C_);
  float var = s2 * (1.f / C_) - mu * mu;
  float rstd = rsqrtf(var + 1e-5f);
  const float* gp = g + which * C_;
  const float* bp = bta + which * C_;
  f16x8 o;
#pragma unroll
  for (int j = 0; j < 8; ++j) {
    int c = lane * 8 + j;
    o[j] = (f16)((vals[j] - mu) * rstd * gp[c] + bp[c]);
  }
  *(f16x8*)(Y + ((size_t)which * BL_ + token) * C_ + lane * 8) = o;
}

// ---------------------------------------------------------------- q_probe
__global__ __launch_bounds__(256) void qprobe2(const f16* __restrict__ Q,
                                               float* __restrict__ qp) {
  int blk = blockIdx.x;
  int b = blk >> 6;             // 64 blocks per batch
  int r0 = blk * 64;
  int t = threadIdx.x;
  int c8 = (t & 63) * 8, rg = t >> 6;
  float s[8] = {0.f, 0.f, 0.f, 0.f, 0.f, 0.f, 0.f, 0.f};
#pragma unroll
  for (int i = 0; i < 16; ++i) {
    const f16* row = Q + ((size_t)r0 + rg + i * 4) * C_ + c8;
    f16x8 v = *(const f16x8*)row;
#pragma unroll
    for (int j = 0; j < 8; ++j) s[j] += (float)v[j];
  }
  __shared__ float red[4][520];
#pragma unroll
  for (int j = 0; j < 8; ++j) red[rg][c8 + j] = s[j];
  __syncthreads();
  int c = t * 2;
  float a0 = red[0][c] + red[1][c] + red[2][c] + red[3][c];
  float a1 = red[0][c + 1] + red[1][c + 1] + red[2][c + 1] + red[3][c + 1];
  atomicAdd(&qp[b * C_ + c], a0);
  atomicAdd(&qp[b * C_ + c + 1], a1);
}

// ---------------------------------------------------------------- score logits
__global__ __launch_bounds__(256) void logits_kernel(const f16* __restrict__ Kh,
                                                     const float* __restrict__ qp,
                                                     float* __restrict__ score) {
  int wv = threadIdx.x >> 6, lane = threadIdx.x & 63;
  int token = blockIdx.x * 4 + wv;  // b*L + l
  int b = token >> 12;
  int l = token & (L_ - 1);
  const f16* row = Kh + (size_t)token * C_;
  int h = lane >> 3, j0 = (lane & 7) * 8;
  const float* qph = qp + b * C_ + h * DH_ + j0;
  float p = 0.f;
#pragma unroll
  for (int j = 0; j < 8; ++j) p += qph[j] * (float)row[h * DH_ + j0 + j];
  p += __shfl_xor(p, 1); p += __shfl_xor(p, 2); p += __shfl_xor(p, 4);
  if ((lane & 7) == 0)
    score[((size_t)b * H_ + h) * LK_ + 1 + l] = p * (1.f / L_) * 0.125f;  // /L mean, /sqrt(64)
}

__global__ __launch_bounds__(256) void softmax_kernel(float* __restrict__ score) {
  int bh = blockIdx.x, t = threadIdx.x;
  float* s = score + (size_t)bh * LK_;
  __shared__ float red[256];
  float mx = 0.f;  // logit[0] == 0 participates
  for (int i = t; i < L_; i += 256) mx = fmaxf(mx, s[1 + i]);
  red[t] = mx; __syncthreads();
  for (int k = 128; k; k >>= 1) { if (t < k) red[t] = fmaxf(red[t], red[t + k]); __syncthreads(); }
  mx = red[0]; __syncthreads();
  float sum = (t == 0) ? expf(-mx) : 0.f;
  for (int i = t; i < L_; i += 256) { float e = expf(s[1 + i] - mx); s[1 + i] = e; sum += e; }
  red[t] = sum; __syncthreads();
  for (int k = 128; k; k >>= 1) { if (t < k) red[t] += red[t + k]; __syncthreads(); }
  float inv = 1.f / red[0];
  __syncthreads();
  for (int i = t; i < L_; i += 256) s[1 + i] *= inv;
  if (t == 0) s[0] = expf(-mx) * inv;
}

// ---------------------------------------------------------------- kv / ksum
__global__ __launch_bounds__(256) void ksum_init(const float* __restrict__ score,
                                                 const float* __restrict__ bkk,
                                                 float* __restrict__ ksum) {
  int i = blockIdx.x * 256 + threadIdx.x;  // 0..2047
  int bh = i >> 6, d = i & 63, h = bh & 7;
  float pk0 = tanhf(bkk[h * DH_ + d]) + 1.f;
  ksum[i] = score[(size_t)bh * LK_] * pk0;
}

// kv partials: grid (16 parts, 32 bh), 256 thr. Each block: 256 l-rows.
#define PIDX(l, c) ((l) * 68 + (c))
#define AIDX(d, e) ((d) * 68 + (e) + ((((d) >> 3)) << 2))   // bank-skewed
__global__ __launch_bounds__(256, 2) void kv_part_kernel(const f16* __restrict__ phiK,
                                                         const f16* __restrict__ Vh,
                                                         const float* __restrict__ score,
                                                         float* __restrict__ kvp,
                                                         float* __restrict__ ksum) {
  __shared__ float sm0[4416];   // weighted phiK chunk  [64][68] / later accum
  __shared__ float sm1[4416];   // V chunk              [64][68] / later ksum red
  int bh = blockIdx.y, b = bh >> 3, h = bh & 7;
  int part = blockIdx.x;
  int l0 = part * 256;
  int t = threadIdx.x, lane = t & 63, wv = t >> 6;
  int R = (lane >> 3) * 8, Cc = (lane & 7) * 8;
  float acc[8][8] = {};
  float ks[8] = {0.f, 0.f, 0.f, 0.f, 0.f, 0.f, 0.f, 0.f};

  for (int c = 0; c < 4; ++c) {      // chunks of 64 l
    int lc = l0 + c * 64;
    __syncthreads();                 // prior chunk's reads done
#pragma unroll
    for (int p = 0; p < 4; ++p) {
      int l = p * 16 + (t >> 4);
      int c4 = (t & 15) * 4;
      size_t grow = ((size_t)b * L_ + lc + l) * C_ + h * DH_ + c4;
      float w = score[(size_t)bh * LK_ + 1 + lc + l];
      f16x4 pk = *(const f16x4*)(phiK + grow);
      f16x4 vvv = *(const f16x4*)(Vh + grow);
      sm0[PIDX(l, c4) + 0] = w * (float)pk[0];
      sm0[PIDX(l, c4) + 1] = w * (float)pk[1];
      sm0[PIDX(l, c4) + 2] = w * (float)pk[2];
      sm0[PIDX(l, c4) + 3] = w * (float)pk[3];
      sm1[PIDX(l, c4) + 0] = (float)vvv[0];
      sm1[PIDX(l, c4) + 1] = (float)vvv[1];
      sm1[PIDX(l, c4) + 2] = (float)vvv[2];
      sm1[PIDX(l, c4) + 3] = (float)vvv[3];
    }
    __syncthreads();
#pragma unroll
    for (int i = 0; i < 16; ++i) {   // wave wv owns rows wv*16..+15
      int ll = wv * 16 + i;
      float4 a0 = *(const float4*)&sm0[PIDX(ll, R)];
      float4 a1 = *(const float4*)&sm0[PIDX(ll, R + 4)];
      float4 b0 = *(const float4*)&sm1[PIDX(ll, Cc)];
      float4 b1 = *(const float4*)&sm1[PIDX(ll, Cc + 4)];
      float av[8] = {a0.x, a0.y, a0.z, a0.w, a1.x, a1.y, a1.z, a1.w};
      float bv2[8] = {b0.x, b0.y, b0.z, b0.w, b1.x, b1.y, b1.z, b1.w};
#pragma unroll
      for (int ii = 0; ii < 8; ++ii)
#pragma unroll
        for (int jj = 0; jj < 8; ++jj) acc[ii][jj] += av[ii] * bv2[jj];
      if ((lane & 7) == 0) {
#pragma unroll
        for (int ii = 0; ii < 8; ++ii) ks[ii] += av[ii];
      }
    }
  }

  __syncthreads();                   // done with staging buffers
  if ((lane & 7) == 0) {
#pragma unroll
    for (int i = 0; i < 8; ++i) sm1[wv * 64 + R + i] = ks[i];
  }
  for (int w = 0; w < 4; ++w) {
    if (wv == w) {
#pragma unroll
      for (int i = 0; i < 8; ++i) {
        float* p0 = &sm0[AIDX(R + i, Cc)];
        if (w == 0) {
          *(float4*)p0 = make_float4(acc[i][0], acc[i][1], acc[i][2], acc[i][3]);
          *(float4*)(p0 + 4) = make_float4(acc[i][4], acc[i][5], acc[i][6], acc[i][7]);
        } else {
          float4 o0 = *(const float4*)p0, o1 = *(const float4*)(p0 + 4);
          o0.x += acc[i][0]; o0.y += acc[i][1]; o0.z += acc[i][2]; o0.w += acc[i][3];
          o1.x += acc[i][4]; o1.y += acc[i][5]; o1.z += acc[i][6]; o1.w += acc[i][7];
          *(float4*)p0 = o0;
          *(float4*)(p0 + 4) = o1;
        }
      }
    }
    __syncthreads();
  }
  if (t < 64) {
    float s = sm1[t] + sm1[64 + t] + sm1[128 + t] + sm1[192 + t];
    atomicAdd(&ksum[bh * 64 + t], s);
  }
  float* dst = kvp + ((size_t)bh * 16 + part) * 4096;
#pragma unroll
  for (int i = 0; i < 16; ++i) {
    int idx = i * 256 + t;           // idx = e*64+d
    dst[idx] = sm0[AIDX(idx & 63, idx >> 6)];
  }
}

// compact per-head kvT[b][h][e][d] (f16), summing 16 partials.
// kvp part layout: [e*64+d] = kv[d][e], so linear copy IS the transpose.
__global__ __launch_bounds__(256) void build_kvt(const float* __restrict__ kvp,
                                                 f16* __restrict__ kvt) {
  int i = blockIdx.x * 256 + threadIdx.x;  // over 4*8*4096 = 131072
  int bh = i >> 12;
  const float* p = kvp + ((size_t)bh * 16) * 4096 + (i & 4095);
  float v = 0.f;
#pragma unroll
  for (int pp = 0; pp < 16; ++pp) v += p[pp * 4096];
  kvt[i] = (f16)v;
}

// bottom[b*L*H]: phiQ . ksum per (token, head)
__global__ __launch_bounds__(256) void bottom_kernel(const f16* __restrict__ phiQ,
                                                     const float* __restrict__ ksum,
                                                     float* __restrict__ bot) {
  int wv = threadIdx.x >> 6, lane = threadIdx.x & 63;
  int token = blockIdx.x * 4 + wv;  // b*L + l
  int b = token >> 12;
  const f16* row = phiQ + (size_t)token * C_;
  int h = lane >> 3, j0 = (lane & 7) * 8;
  const float* ks = ksum + (b * H_ + h) * 64 + j0;
  float p = 0.f;
#pragma unroll
  for (int j = 0; j < 8; ++j) p += ks[j] * (float)row[h * DH_ + j0 + j];
  p += __shfl_xor(p, 1); p += __shfl_xor(p, 2); p += __shfl_xor(p, 4);
  if ((lane & 7) == 0) bot[(size_t)token * H_ + h] = p;
}

// ---------------------------------------------------------------- launch
extern "C" void kernel_launch(void* const* d_in, const int* in_sizes, int n_in,
                              void* d_out, int out_size, void* d_ws, size_t ws_size,
                              hipStream_t stream) {
  (void)in_sizes; (void)n_in; (void)out_size; (void)ws_size;
  const float* x     = (const float*)d_in[0];
  const float* Wq    = (const float*)d_in[1];
  const float* bq    = (const float*)d_in[2];
  const float* gq    = (const float*)d_in[3];
  const float* betaq = (const float*)d_in[4];
  const float* Wk    = (const float*)d_in[5];
  const float* bk    = (const float*)d_in[6];
  const float* gk    = (const float*)d_in[7];
  const float* betak = (const float*)d_in[8];
  const float* Wv    = (const float*)d_in[9];
  const float* bv    = (const float*)d_in[10];
  const float* gv    = (const float*)d_in[11];
  const float* betav = (const float*)d_in[12];
  const float* Wkq   = (const float*)d_in[13];
  const float* bkq   = (const float*)d_in[14];
  const float* Wkk   = (const float*)d_in[15];
  const float* bkk   = (const float*)d_in[16];
  const float* g_at  = (const float*)d_in[17];
  const float* b_at  = (const float*)d_in[18];
  const float* W1    = (const float*)d_in[19];
  const float* b1    = (const float*)d_in[20];
  const float* W2    = (const float*)d_in[21];
  const float* b2    = (const float*)d_in[22];
  float* out = (float*)d_out;

  char* ws = (char*)d_ws;
  size_t off = 0;
  auto alloc = [&](size_t bytes) -> void* {
    void* p = ws + off;
    off += (bytes + 255) & ~(size_t)255;
    return p;
  };
  // U1: tmpqkv(48MB) -> tmpA(16MB) -> h1(64MB), temporally disjoint
  f16* U1    = (f16*)alloc((size_t)BL_ * MLP_ * 2);       // 64 MB
  f16* QKVh  = (f16*)alloc((size_t)3 * BL_ * C_ * 2);     // 48 MB (Qh|Kh|Vh; ah reuses Qh)
  f16* phiQK = (f16*)alloc((size_t)2 * BL_ * C_ * 2);     // 32 MB (phiQ|phiK)
  f16* xf    = (f16*)alloc((size_t)BL_ * C_ * 2);         // 16 MB
  f16* WqkvT = (f16*)alloc((size_t)3 * C_ * C_ * 2);      // Wq|Wk|Wv transposed
  f16* WkqT  = (f16*)alloc((size_t)C_ * C_ * 2);          // contiguous after WqkvT
  f16* WkkT  = (f16*)alloc((size_t)C_ * C_ * 2);          // contiguous after WkqT
  f16* W1T   = (f16*)alloc((size_t)C_ * MLP_ * 2);
  f16* W2T   = (f16*)alloc((size_t)MLP_ * C_ * 2);
  f16* kvt   = (f16*)alloc((size_t)B_ * H_ * DH_ * DH_ * 2);  // 256 KB
  float* score = (float*)alloc((size_t)B_ * H_ * LK_ * 4);
  float* qp    = (float*)alloc((size_t)B_ * C_ * 4);
  float* kvp   = (float*)alloc((size_t)B_ * H_ * 16 * 4096 * 4);
  float* ksum  = (float*)alloc((size_t)B_ * H_ * DH_ * 4);
  float* bot   = (float*)alloc((size_t)BL_ * H_ * 4);
  float* bqkv    = (float*)alloc(1536 * 4);
  float* gqkv    = (float*)alloc(1536 * 4);
  float* betaqkv = (float*)alloc(1536 * 4);
  float* bphi    = (float*)alloc(1024 * 4);

  f16* tmpqkv = U1;                  // [49152][512] f16
  f16* tmpA   = U1;                  // [16384][512] f16
  f16* h1     = U1;                  // [16384][2048] f16
  f16* Qh = QKVh;
  f16* Kh = QKVh + (size_t)BL_ * C_;
  f16* Vh = QKVh + (size_t)2 * BL_ * C_;
  f16* ah = QKVh;                    // reuse Qh region after phi/qprobe done
  f16* phiQ = phiQK;
  f16* phiK = phiQK + (size_t)BL_ * C_;

  dim3 blk(256);

  pack_params<<<6, blk, 0, stream>>>(bq, bk, bv, gq, gk, gv, betaq, betak, betav,
                                     bkq, bkk, bqkv, gqkv, betaqkv, bphi);

  // weight transposes to [N,K] f16 (5x 512x512 in one z-launch; outputs contiguous)
  transpose_w5<<<dim3(16, 16, 5), blk, 0, stream>>>(Wq, Wk, Wv, Wkq, Wkk, WqkvT);
  transpose_w<<<dim3(MLP_ / 32, C_ / 32), blk, 0, stream>>>(W1, W1T, C_, MLP_);
  transpose_w<<<dim3(C_ / 32, MLP_ / 32), blk, 0, stream>>>(W2, W2T, MLP_, C_);

  transpose_x<<<dim3(L_ / 32, C_ / 32, B_), blk, 0, stream>>>(x, xf);

  // fused QKV projection: [16384,512] @ [512,1536] -> tmpqkv f16
  gemm64<5><<<dim3(BL_ / 128, 1536 / 128), blk, 0, stream>>>(
      xf, WqkvT, bqkv, tmpqkv, 1536, C_, nullptr, nullptr, nullptr, 0, 0, 0, 0);
  // LN all three in one pass: rows [49152][512] -> Qh/Kh/Vh
  ln16<<<3 * BL_ / 4, blk, 0, stream>>>(tmpqkv, gqkv, betaqkv, QKVh, 1);

  hipMemsetAsync(qp, 0, (size_t)B_ * C_ * 4, stream);
  qprobe2<<<BL_ / 64, blk, 0, stream>>>(Qh, qp);

  // phi projections, z-batched (z=0: Qh@Wkq->phiQ, z=1: Kh@Wkk->phiK)
  gemm64<1><<<dim3(BL_ / 128, C_ / 128, 2), blk, 0, stream>>>(
      Qh, WkqT, bphi, phiQ, C_, C_, nullptr, nullptr, nullptr,
      (long long)BL_ * C_, (long long)C_ * C_, (long long)BL_ * C_, (long long)C_);

  logits_kernel<<<BL_ / 4, blk, 0, stream>>>(Kh, qp, score);
  softmax_kernel<<<B_ * H_, blk, 0, stream>>>(score);

  ksum_init<<<(B_ * H_ * DH_) / 256, blk, 0, stream>>>(score, bkk, ksum);
  kv_part_kernel<<<dim3(16, B_ * H_), blk, 0, stream>>>(phiK, Vh, score, kvp, ksum);

  build_kvt<<<(B_ * H_ * DH_ * DH_) / 256, blk, 0, stream>>>(kvp, kvt);
  bottom_kernel<<<BL_ / 4, blk, 0, stream>>>(phiQ, ksum, bot);

  // attention out: per-head K=64 GEMM (block-diagonal exploited), /bottom
  attn_out<<<dim3(BL_ / 128, H_), blk, 0, stream>>>(phiQ, kvt, bot, tmpA);

  ln16<<<BL_ / 4, blk, 0, stream>>>(tmpA, g_at, b_at, ah, 0);

  // MLP up
  gemm64<2><<<dim3(BL_ / 128, MLP_ / 128), blk, 0, stream>>>(
      ah, W1T, b1, h1, MLP_, C_, nullptr, nullptr, nullptr, 0, 0, 0, 0);
  // MLP down fused with residual-add + transpose + x-add -> out
  gemm64<6><<<dim3(BL_ / 128, C_ / 128), blk, 0, stream>>>(
      h1, W2T, b2, nullptr, C_, MLP_, ah, x, out, 0, 0, 0, 0);
}

// Round 6
// 397.874 us; speedup vs baseline: 1.0408x; 1.0408x over previous
//
#include <hip/hip_runtime.h>
#include <math.h>

#define B_ 4
#define C_ 512
#define L_ 4096
#define H_ 8
#define DH_ 64
#define MLP_ 2048
#define BL_ (B_*L_)      // 16384
#define LK_ (L_+1)       // 4097

typedef _Float16 f16;
typedef _Float16 f16x8 __attribute__((ext_vector_type(8)));
typedef _Float16 f16x4 __attribute__((ext_vector_type(4)));
typedef float f32x4 __attribute__((ext_vector_type(4)));

// async global->LDS, 16B per lane (m97 pattern)
__device__ __forceinline__ void gl16(void* lds, const void* g) {
  __builtin_amdgcn_global_load_lds((const __attribute__((address_space(1))) void*)g,
                                   (__attribute__((address_space(3))) void*)lds,
                                   16, 0, 0);
}

__device__ __forceinline__ float frcp(float x) { return __builtin_amdgcn_rcpf(x); }

// ---------------------------------------------------------------- transposes
// z-merged 512x512 weight transposes; outputs contiguous at dst + z*C*C
__global__ __launch_bounds__(256) void transpose_w5(const float* __restrict__ Wq,
                                                    const float* __restrict__ Wk,
                                                    const float* __restrict__ Wv,
                                                    const float* __restrict__ Wkq,
                                                    const float* __restrict__ Wkk,
                                                    f16* __restrict__ dst) {
  int z = blockIdx.z;
  const float* W = (z == 0) ? Wq : (z == 1) ? Wk : (z == 2) ? Wv : (z == 3) ? Wkq : Wkk;
  f16* Wt = dst + (size_t)z * C_ * C_;
  __shared__ float tile[32][33];
  int n0 = blockIdx.x * 32, k0 = blockIdx.y * 32;
  int tx = threadIdx.x & 31, ty = threadIdx.x >> 5;
#pragma unroll
  for (int i = 0; i < 4; ++i)
    tile[ty + i * 8][tx] = W[(size_t)(k0 + ty + i * 8) * C_ + n0 + tx];
  __syncthreads();
#pragma unroll
  for (int i = 0; i < 4; ++i)
    Wt[(size_t)(n0 + ty + i * 8) * C_ + k0 + tx] = (f16)tile[tx][ty + i * 8];
}

__global__ __launch_bounds__(256) void transpose_w(const float* __restrict__ W,
                                                   f16* __restrict__ Wt, int K, int N) {
  __shared__ float tile[32][33];
  int n0 = blockIdx.x * 32, k0 = blockIdx.y * 32;
  int tx = threadIdx.x & 31, ty = threadIdx.x >> 5;
#pragma unroll
  for (int i = 0; i < 4; ++i)
    tile[ty + i * 8][tx] = W[(size_t)(k0 + ty + i * 8) * N + n0 + tx];
  __syncthreads();
#pragma unroll
  for (int i = 0; i < 4; ++i)
    Wt[(size_t)(n0 + ty + i * 8) * K + k0 + tx] = (f16)tile[tx][ty + i * 8];
}

__global__ __launch_bounds__(256) void transpose_x(const float* __restrict__ x,
                                                   f16* __restrict__ xf) {
  __shared__ float tile[32][33];
  int b = blockIdx.z;
  int l0 = blockIdx.x * 32, c0 = blockIdx.y * 32;
  int tx = threadIdx.x & 31, ty = threadIdx.x >> 5;
#pragma unroll
  for (int i = 0; i < 4; ++i)
    tile[ty + i * 8][tx] = x[((size_t)b * C_ + c0 + ty + i * 8) * L_ + l0 + tx];
  __syncthreads();
#pragma unroll
  for (int i = 0; i < 4; ++i)
    xf[((size_t)b * L_ + l0 + ty + i * 8) * C_ + c0 + tx] = (f16)tile[tx][ty + i * 8];
}

// ------------------------------------------------- pack small param vectors
__global__ __launch_bounds__(256) void pack_params(
    const float* bq, const float* bk, const float* bv,
    const float* gq, const float* gk, const float* gv,
    const float* betaq, const float* betak, const float* betav,
    const float* bkq, const float* bkk,
    float* bqkv, float* gqkv, float* betaqkv, float* bphi) {
  int i = blockIdx.x * 256 + threadIdx.x;  // 0..1535
  int w = i >> 9, c = i & 511;
  bqkv[i]    = (w == 0 ? bq : (w == 1 ? bk : bv))[c];
  gqkv[i]    = (w == 0 ? gq : (w == 1 ? gk : gv))[c];
  betaqkv[i] = (w == 0 ? betaq : (w == 1 ? betak : betav))[c];
  if (i < 1024) bphi[i] = (i < 512) ? bkq[i] : bkk[i - 512];
}

// ---------------------------------------------------------------- GEMM 256x256 (counted-vmcnt)
// C[M,N](f16) = act(A[M,K] @ Bt[N,K]^T + bias)
// 256x256 tile, BK=64, 512 thr = 8 waves (2 wm x 4 wn), per-wave out 128x64.
// LDS 128 KB: 2 buffers x (A 256x64 + B 256x64) f16. 1 block/CU, 8 waves.
// Pipeline (T3/T4: loads span barriers, vmcnt NEVER drains to 0 in loop):
//   per tile t: vmcnt(8) [stage(t) landed, stage(t+1)'s 8 in flight]
//     -> s_barrier [all waves' portions of tile t landed: per-wave FIFO +
//        every wave waited its own vmcnt before the barrier]
//     -> 24x ds_read_b128 (full-tile operands -> regs; split 16+8 with 32
//        MFMA between to cap live VGPR)
//     -> lgkmcnt(0) -> s_barrier [all waves done reading buf[t&1]]
//     -> stage(t+2) into buf[t&1] (issued after the seal barrier: race-free)
//     -> 32 MFMA (regs only).
//   64 MFMA per barrier-pair; stage(t+2) has ~2 iters (>1000 cyc) to land.
// Staging/read XOR chunk swizzle identical to the proven 128^2 kernel
// (SQ_LDS_BANK_CONFLICT measured 0).
// EPI: 1 tanh(v)+1   2 gelu (tanh approx)   5 plain bias
template <int EPI>
__global__ __launch_bounds__(512, 2) void gemm256(const f16* __restrict__ A,
                                                  const f16* __restrict__ Bt,
                                                  const float* __restrict__ bias,
                                                  f16* __restrict__ Ch,
                                                  int N, int K,
                                                  long long zA, long long zB,
                                                  long long zC, long long zBias) {
  __shared__ f16 smem[65536];  // 128 KB; epilogue reuses as [256][256]
  A  += (size_t)blockIdx.z * zA;
  Bt += (size_t)blockIdx.z * zB;
  Ch += (size_t)blockIdx.z * zC;
  bias += (size_t)blockIdx.z * zBias;

  const int tid = threadIdx.x;
  const int lane = tid & 63, wv = tid >> 6;
  const int wm = wv >> 2, wn = wv & 3;           // 2 x 4 waves
  const int bm = blockIdx.x * 256, bn = blockIdx.y * 256;
  const int l15 = lane & 15, q = lane >> 4;

  // staging: inst p covers rows p*64+(tid>>3); lane fetches global k-chunk
  // (tid&7)^(row&7) into LDS slot tid*16B -> LDS[r][slot c] = chunk c^(r&7)
  const int srow = tid >> 3;                     // 0..63
  const int schunk = (tid & 7) ^ (srow & 7);
  const f16* pa = A + (size_t)(bm + srow) * K + schunk * 8;
  const f16* pb = Bt + (size_t)(bn + srow) * K + schunk * 8;
  const int sw0 = (q ^ (lane & 7)) * 8;          // frag read swizzle, ks=0
  const int sw1 = ((4 + q) ^ (lane & 7)) * 8;    // ks=1
  const int NT = K >> 6;                         // 8 for K=512

  auto STAGE = [&](int t) {
    f16* bs = smem + (t & 1) * 32768;
    const f16* pat = pa + t * 64;
    const f16* pbt = pb + t * 64;
#pragma unroll
    for (int p = 0; p < 4; ++p) gl16(bs + p * 4096 + tid * 8, pat + (size_t)p * 64 * K);
#pragma unroll
    for (int p = 0; p < 4; ++p) gl16(bs + 16384 + p * 4096 + tid * 8, pbt + (size_t)p * 64 * K);
  };

  f32x4 acc[8][4] = {};

  // prologue: stage tiles 0 and 1 (16 loads/wave outstanding)
  STAGE(0);
  STAGE(1);

  for (int t = 0; t < NT; ++t) {
    // (a) wait for tile t only (stage(t+1)'s 8 loads stay in flight)
    if (t < NT - 1) asm volatile("s_waitcnt vmcnt(8)" ::: "memory");
    else            asm volatile("s_waitcnt vmcnt(0)" ::: "memory");
    // (b) all waves confirmed their own portions -> tile t complete in LDS
    __builtin_amdgcn_s_barrier();
    asm volatile("" ::: "memory");

    const f16* As = smem + (t & 1) * 32768;
    const f16* Bs = As + 16384;

    // (c) operand reads: B (8) + A rows 0..63 of wave half (8)
    f16x8 bfr[4][2], afr[4][2];
#pragma unroll
    for (int n = 0; n < 4; ++n) {
      bfr[n][0] = *(const f16x8*)&Bs[(wn * 64 + n * 16 + l15) * 64 + sw0];
      bfr[n][1] = *(const f16x8*)&Bs[(wn * 64 + n * 16 + l15) * 64 + sw1];
    }
#pragma unroll
    for (int m = 0; m < 4; ++m) {
      afr[m][0] = *(const f16x8*)&As[(wm * 128 + m * 16 + l15) * 64 + sw0];
      afr[m][1] = *(const f16x8*)&As[(wm * 128 + m * 16 + l15) * 64 + sw1];
    }
    // first MFMA half (m 0..3)
#pragma unroll
    for (int ks = 0; ks < 2; ++ks)
#pragma unroll
      for (int m = 0; m < 4; ++m)
#pragma unroll
        for (int n = 0; n < 4; ++n)
          acc[m][n] = __builtin_amdgcn_mfma_f32_16x16x32_f16(afr[m][ks], bfr[n][ks], acc[m][n], 0, 0, 0);
    // A rows 64..127 of wave half
#pragma unroll
    for (int m = 0; m < 4; ++m) {
      afr[m][0] = *(const f16x8*)&As[(wm * 128 + (m + 4) * 16 + l15) * 64 + sw0];
      afr[m][1] = *(const f16x8*)&As[(wm * 128 + (m + 4) * 16 + l15) * 64 + sw1];
    }
    // all LDS reads of buf[t&1] complete before the seal barrier
    asm volatile("s_waitcnt lgkmcnt(0)" ::: "memory");
    // (d) seal: every wave done reading buf[t&1]
    __builtin_amdgcn_s_barrier();
    asm volatile("" ::: "memory");
    // (e) overwrite the sealed buffer with tile t+2 (lands ~2 iters later)
    if (t + 2 < NT) STAGE(t + 2);
    // (f) second MFMA half (m 4..7), register-only: overlaps (e)'s loads
#pragma unroll
    for (int ks = 0; ks < 2; ++ks)
#pragma unroll
      for (int m = 0; m < 4; ++m)
#pragma unroll
        for (int n = 0; n < 4; ++n)
          acc[m + 4][n] = __builtin_amdgcn_mfma_f32_16x16x32_f16(afr[m][ks], bfr[n][ks], acc[m + 4][n], 0, 0, 0);
  }

  // ---- epilogue: act -> smem [256][256] (col-chunk XOR swizzle)
  __syncthreads();
#pragma unroll
  for (int n = 0; n < 4; ++n) {
    int lc = wn * 64 + n * 16 + l15;
    float bb = bias[bn + lc];
#pragma unroll
    for (int m = 0; m < 8; ++m) {
#pragma unroll
      for (int r = 0; r < 4; ++r) {
        int lr = wm * 128 + m * 16 + q * 4 + r;
        float v = acc[m][n][r] + bb;
        if (EPI == 1) {
          v = 2.0f * frcp(1.0f + __expf(-2.0f * v));      // tanh(v)+1
        } else if (EPI == 2) {
          v = v * frcp(1.0f + __expf(-1.5957691f * (v + 0.044715f * v * v * v)));
        }
        smem[lr * 256 + ((((lc >> 3) ^ (lr & 31)) << 3) | (lc & 7))] = (f16)v;
      }
    }
  }
  __syncthreads();

  // coalesced f16x8 row stores
#pragma unroll
  for (int p = 0; p < 16; ++p) {
    int idx = p * 512 + tid;
    int row = idx >> 5, ch = idx & 31;
    f16x8 vv = *(const f16x8*)&smem[row * 256 + ((ch ^ (row & 31)) << 3)];
    *(f16x8*)&Ch[(size_t)(bm + row) * N + bn + ch * 8] = vv;
  }
}

// ---------------------------------------------------------------- GEMM 128x128 (dbuf, for MLP-down)
// round-0 verified config; kept for the grid-limited K=2048 MLP-down.
// EPI 6: plain bias + a-residual + transposed f32 out (+x)
template <int EPI>
__global__ __launch_bounds__(256, 2) void gemm64(const f16* __restrict__ A,
                                                 const f16* __restrict__ Bt,
                                                 const float* __restrict__ bias,
                                                 f16* __restrict__ Ch,
                                                 int N, int K,
                                                 const f16* __restrict__ Ares,
                                                 const float* __restrict__ Xres,
                                                 float* __restrict__ Fout,
                                                 long long zA, long long zB,
                                                 long long zC, long long zBias) {
  __shared__ f16 smem[2 * 128 * 128];  // 64 KB
  A  += (size_t)blockIdx.z * zA;
  Bt += (size_t)blockIdx.z * zB;
  if (EPI != 6) Ch += (size_t)blockIdx.z * zC;
  bias += (size_t)blockIdx.z * zBias;

  const int tid = threadIdx.x;
  const int lane = tid & 63, wv = tid >> 6;
  const int wm = wv >> 1, wn = wv & 1;
  const int bm = blockIdx.x * 128, bn = blockIdx.y * 128;
  const int l15 = lane & 15, q = lane >> 4;

  const int srow = tid >> 3;
  const int schunk = (tid & 7) ^ (srow & 7);
  const f16* pa = A + (size_t)(bm + srow) * K + schunk * 8;
  const f16* pb = Bt + (size_t)(bn + srow) * K + schunk * 8;
  f16* la = smem + tid * 8;
  f16* lb = smem + 8192 + tid * 8;
  const int sw0 = (q ^ (lane & 7)) * 8;
  const int sw1 = ((4 + q) ^ (lane & 7)) * 8;

  f32x4 acc[4][4] = {};

#pragma unroll
  for (int p = 0; p < 4; ++p) gl16(la + p * 2048, pa + (size_t)p * 32 * K);
#pragma unroll
  for (int p = 0; p < 4; ++p) gl16(lb + p * 2048, pb + (size_t)p * 32 * K);

  int cur = 0;
  for (int k0 = 0; k0 < K; k0 += 64) {
    __syncthreads();
    const int nxt = cur ^ 1;
    if (k0 + 64 < K) {
#pragma unroll
      for (int p = 0; p < 4; ++p) gl16(la + nxt * 16384 + p * 2048, pa + (size_t)p * 32 * K + k0 + 64);
#pragma unroll
      for (int p = 0; p < 4; ++p) gl16(lb + nxt * 16384 + p * 2048, pb + (size_t)p * 32 * K + k0 + 64);
    }
    const f16* As = smem + cur * 16384;
    const f16* Bs = As + 8192;
#pragma unroll
    for (int ks = 0; ks < 2; ++ks) {
      const int sw = ks ? sw1 : sw0;
      f16x8 af[4], bf[4];
#pragma unroll
      for (int i = 0; i < 4; ++i)
        af[i] = *(const f16x8*)&As[(wm * 64 + i * 16 + l15) * 64 + sw];
#pragma unroll
      for (int j = 0; j < 4; ++j)
        bf[j] = *(const f16x8*)&Bs[(wn * 64 + j * 16 + l15) * 64 + sw];
#pragma unroll
      for (int i = 0; i < 4; ++i)
#pragma unroll
        for (int j = 0; j < 4; ++j)
          acc[i][j] = __builtin_amdgcn_mfma_f32_16x16x32_f16(af[i], bf[j], acc[i][j], 0, 0, 0);
    }
    cur = nxt;
  }

  __syncthreads();
#pragma unroll
  for (int j = 0; j < 4; ++j) {
    int lc = wn * 64 + j * 16 + l15;
    float bb = bias[bn + lc];
#pragma unroll
    for (int i = 0; i < 4; ++i) {
#pragma unroll
      for (int r = 0; r < 4; ++r) {
        int lr = wm * 64 + i * 16 + q * 4 + r;
        float v = acc[i][j][r] + bb;
        smem[lr * 128 + ((((lc >> 3) ^ (lr & 15)) << 3) | (lc & 7))] = (f16)v;
      }
    }
  }
  __syncthreads();

  if (EPI != 6) {
#pragma unroll
    for (int p = 0; p < 8; ++p) {
      int idx = p * 256 + tid;
      int row = idx >> 4, ch = idx & 15;
      f16x8 vv = *(const f16x8*)&smem[row * 128 + ((ch ^ (row & 15)) << 3)];
      *(f16x8*)&Ch[(size_t)(bm + row) * N + bn + ch * 8] = vv;
    }
  } else {
#pragma unroll
    for (int p = 0; p < 8; ++p) {
      int idx = p * 256 + tid;
      int row = idx >> 4, ch = idx & 15;
      f16x8 av = *(const f16x8*)&Ares[(size_t)(bm + row) * C_ + bn + ch * 8];
      f16* sp = &smem[row * 128 + ((ch ^ (row & 15)) << 3)];
      f16x8 sv = *(const f16x8*)sp;
#pragma unroll
      for (int jj = 0; jj < 8; ++jj) sv[jj] = (f16)((float)sv[jj] + (float)av[jj]);
      *(f16x8*)sp = sv;
    }
    __syncthreads();
    int c = tid & 127, lh = tid >> 7;
    int b = bm >> 12, lbase = (bm & 4095) + lh * 64;
    const float* xp = Xres + ((size_t)b * C_ + bn + c) * L_ + lbase;
    float* op = Fout + ((size_t)b * C_ + bn + c) * L_ + lbase;
    int chi = c >> 3, clo = c & 7;
#pragma unroll
    for (int s = 0; s < 16; ++s) {
      int l = lh * 64 + s * 4;
      float4 xv = *(const float4*)(xp + s * 4);
      float4 r;
      r.x = (float)smem[(l + 0) * 128 + (((chi ^ ((l + 0) & 15)) << 3) | clo)] + xv.x;
      r.y = (float)smem[(l + 1) * 128 + (((chi ^ ((l + 1) & 15)) << 3) | clo)] + xv.y;
      r.z = (float)smem[(l + 2) * 128 + (((chi ^ ((l + 2) & 15)) << 3) | clo)] + xv.z;
      r.w = (float)smem[(l + 3) * 128 + (((chi ^ ((l + 3) & 15)) << 3) | clo)] + xv.w;
      *(float4*)(op + s * 4) = r;
    }
  }
}

// ---------------------------------------------------------------- attention out
// O[l, h*64+e] = (sum_d phiQ[l, h*64+d] * kvT[b][h][e][d]) / (bot[l,h] + 1e-6)
__global__ __launch_bounds__(256, 4) void attn_out(const f16* __restrict__ phiQ,
                                                   const f16* __restrict__ kvt,
                                                   const float* __restrict__ bot,
                                                   f16* __restrict__ Ch) {
  __shared__ f16 smem[12288];
  const int tid = threadIdx.x;
  const int lane = tid & 63, wv = tid >> 6;
  const int bm = blockIdx.x * 128;
  const int h = blockIdx.y;
  const int b = bm >> 12;
  const int l15 = lane & 15, q = lane >> 4;

  const int srow = tid >> 3;
  const int schunk = (tid & 7) ^ (srow & 7);
  const f16* pa = phiQ + (size_t)(bm + srow) * C_ + h * DH_ + schunk * 8;
  const f16* pb = kvt + ((size_t)(b * H_ + h) * DH_ + srow) * DH_ + schunk * 8;
  f16* la = smem + tid * 8;
  f16* lb = smem + 8192 + tid * 8;
  const int sw0 = (q ^ (lane & 7)) * 8;
  const int sw1 = ((4 + q) ^ (lane & 7)) * 8;

#pragma unroll
  for (int p = 0; p < 4; ++p) gl16(la + p * 2048, pa + (size_t)p * 32 * C_);
#pragma unroll
  for (int p = 0; p < 2; ++p) gl16(lb + p * 2048, pb + (size_t)p * 32 * DH_);
  __syncthreads();

  f32x4 acc[2][4] = {};
#pragma unroll
  for (int ks = 0; ks < 2; ++ks) {
    const int sw = ks ? sw1 : sw0;
    f16x8 af[2], bf[4];
#pragma unroll
    for (int i = 0; i < 2; ++i)
      af[i] = *(const f16x8*)&smem[(wv * 32 + i * 16 + l15) * 64 + sw];
#pragma unroll
    for (int j = 0; j < 4; ++j)
      bf[j] = *(const f16x8*)&smem[8192 + (j * 16 + l15) * 64 + sw];
#pragma unroll
    for (int i = 0; i < 2; ++i)
#pragma unroll
      for (int j = 0; j < 4; ++j)
        acc[i][j] = __builtin_amdgcn_mfma_f32_16x16x32_f16(af[i], bf[j], acc[i][j], 0, 0, 0);
  }
  __syncthreads();

#pragma unroll
  for (int j = 0; j < 4; ++j) {
    int lc = j * 16 + l15;
#pragma unroll
    for (int i = 0; i < 2; ++i) {
#pragma unroll
      for (int r = 0; r < 4; ++r) {
        int lr = wv * 32 + i * 16 + q * 4 + r;
        float v = acc[i][j][r] * frcp(bot[(size_t)(bm + lr) * H_ + h] + 1e-6f);
        smem[lr * 64 + ((((lc >> 3) ^ (lr & 7)) << 3) | (lc & 7))] = (f16)v;
      }
    }
  }
  __syncthreads();

#pragma unroll
  for (int p = 0; p < 4; ++p) {
    int idx = p * 256 + tid;
    int row = idx >> 3, ch = idx & 7;
    f16x8 vv = *(const f16x8*)&smem[row * 64 + ((ch ^ (row & 7)) << 3)];
    *(f16x8*)&Ch[(size_t)(bm + row) * C_ + h * DH_ + ch * 8] = vv;
  }
}

// ---------------------------------------------------------------- LayerNorm (f16 in/out)
__global__ __launch_bounds__(256) void ln16(const f16* __restrict__ X,
                                            const float* __restrict__ g,
                                            const float* __restrict__ bta,
                                            f16* __restrict__ Y, int threeway) {
  int wv = threadIdx.x >> 6, lane = threadIdx.x & 63;
  int r = blockIdx.x * 4 + wv;
  int token = r, which = 0;
  if (threeway) { token = r / 3; which = r - token * 3; }
  const f16* xr = X + (size_t)r * C_;
  f16x8 v = *(const f16x8*)(xr + lane * 8);
  float vals[8];
  float s = 0.f, s2 = 0.f;
#pragma unroll
  for (int j = 0; j < 8; ++j) { vals[j] = (float)v[j]; s += vals[j]; s2 += vals[j] * vals[j]; }
#pragma unroll
  for (int m_ = 1; m_ < 64; m_ <<= 1) { s += __shfl_xor(s, m_); s2 += __shfl_xor(s2, m_); }
  float mu = s * (1.f / C_);
  float var = s2 * (1.f / C_) - mu * mu;
  float rstd = rsqrtf(var + 1e-5f);
  const float* gp = g + which * C_;
  const float* bp = bta + which * C_;
  f16x8 o;
#pragma unroll
  for (int j = 0; j < 8; ++j) {
    int c = lane * 8 + j;
    o[j] = (f16)((vals[j] - mu) * rstd * gp[c] + bp[c]);
  }
  *(f16x8*)(Y + ((size_t)which * BL_ + token) * C_ + lane * 8) = o;
}

// ---------------------------------------------------------------- q_probe
__global__ __launch_bounds__(256) void qprobe2(const f16* __restrict__ Q,
                                               float* __restrict__ qp) {
  int blk = blockIdx.x;
  int b = blk >> 6;
  int r0 = blk * 64;
  int t = threadIdx.x;
  int c8 = (t & 63) * 8, rg = t >> 6;
  float s[8] = {0.f, 0.f, 0.f, 0.f, 0.f, 0.f, 0.f, 0.f};
#pragma unroll
  for (int i = 0; i < 16; ++i) {
    const f16* row = Q + ((size_t)r0 + rg + i * 4) * C_ + c8;
    f16x8 v = *(const f16x8*)row;
#pragma unroll
    for (int j = 0; j < 8; ++j) s[j] += (float)v[j];
  }
  __shared__ float red[4][520];
#pragma unroll
  for (int j = 0; j < 8; ++j) red[rg][c8 + j] = s[j];
  __syncthreads();
  int c = t * 2;
  float a0 = red[0][c] + red[1][c] + red[2][c] + red[3][c];
  float a1 = red[0][c + 1] + red[1][c + 1] + red[2][c + 1] + red[3][c + 1];
  atomicAdd(&qp[b * C_ + c], a0);
  atomicAdd(&qp[b * C_ + c + 1], a1);
}

// ---------------------------------------------------------------- score logits
__global__ __launch_bounds__(256) void logits_kernel(const f16* __restrict__ Kh,
                                                     const float* __restrict__ qp,
                                                     float* __restrict__ score) {
  int wv = threadIdx.x >> 6, lane = threadIdx.x & 63;
  int token = blockIdx.x * 4 + wv;
  int b = token >> 12;
  int l = token & (L_ - 1);
  const f16* row = Kh + (size_t)token * C_;
  int h = lane >> 3, j0 = (lane & 7) * 8;
  const float* qph = qp + b * C_ + h * DH_ + j0;
  float p = 0.f;
#pragma unroll
  for (int j = 0; j < 8; ++j) p += qph[j] * (float)row[h * DH_ + j0 + j];
  p += __shfl_xor(p, 1); p += __shfl_xor(p, 2); p += __shfl_xor(p, 4);
  if ((lane & 7) == 0)
    score[((size_t)b * H_ + h) * LK_ + 1 + l] = p * (1.f / L_) * 0.125f;
}

__global__ __launch_bounds__(256) void softmax_kernel(float* __restrict__ score) {
  int bh = blockIdx.x, t = threadIdx.x;
  float* s = score + (size_t)bh * LK_;
  __shared__ float red[256];
  float mx = 0.f;
  for (int i = t; i < L_; i += 256) mx = fmaxf(mx, s[1 + i]);
  red[t] = mx; __syncthreads();
  for (int k = 128; k; k >>= 1) { if (t < k) red[t] = fmaxf(red[t], red[t + k]); __syncthreads(); }
  mx = red[0]; __syncthreads();
  float sum = (t == 0) ? expf(-mx) : 0.f;
  for (int i = t; i < L_; i += 256) { float e = expf(s[1 + i] - mx); s[1 + i] = e; sum += e; }
  red[t] = sum; __syncthreads();
  for (int k = 128; k; k >>= 1) { if (t < k) red[t] += red[t + k]; __syncthreads(); }
  float inv = 1.f / red[0];
  __syncthreads();
  for (int i = t; i < L_; i += 256) s[1 + i] *= inv;
  if (t == 0) s[0] = expf(-mx) * inv;
}

// ---------------------------------------------------------------- kv / ksum
__global__ __launch_bounds__(256) void ksum_init(const float* __restrict__ score,
                                                 const float* __restrict__ bkk,
                                                 float* __restrict__ ksum) {
  int i = blockIdx.x * 256 + threadIdx.x;
  int bh = i >> 6, d = i & 63, h = bh & 7;
  float pk0 = tanhf(bkk[h * DH_ + d]) + 1.f;
  ksum[i] = score[(size_t)bh * LK_] * pk0;
}

#define PIDX(l, c) ((l) * 68 + (c))
#define AIDX(d, e) ((d) * 68 + (e) + ((((d) >> 3)) << 2))
__global__ __launch_bounds__(256, 2) void kv_part_kernel(const f16* __restrict__ phiK,
                                                         const f16* __restrict__ Vh,
                                                         const float* __restrict__ score,
                                                         float* __restrict__ kvp,
                                                         float* __restrict__ ksum) {
  __shared__ float sm0[4416];
  __shared__ float sm1[4416];
  int bh = blockIdx.y, b = bh >> 3, h = bh & 7;
  int part = blockIdx.x;
  int l0 = part * 256;
  int t = threadIdx.x, lane = t & 63, wv = t >> 6;
  int R = (lane >> 3) * 8, Cc = (lane & 7) * 8;
  float acc[8][8] = {};
  float ks[8] = {0.f, 0.f, 0.f, 0.f, 0.f, 0.f, 0.f, 0.f};

  for (int c = 0; c < 4; ++c) {
    int lc = l0 + c * 64;
    __syncthreads();
#pragma unroll
    for (int p = 0; p < 4; ++p) {
      int l = p * 16 + (t >> 4);
      int c4 = (t & 15) * 4;
      size_t grow = ((size_t)b * L_ + lc + l) * C_ + h * DH_ + c4;
      float w = score[(size_t)bh * LK_ + 1 + lc + l];
      f16x4 pk = *(const f16x4*)(phiK + grow);
      f16x4 vvv = *(const f16x4*)(Vh + grow);
      sm0[PIDX(l, c4) + 0] = w * (float)pk[0];
      sm0[PIDX(l, c4) + 1] = w * (float)pk[1];
      sm0[PIDX(l, c4) + 2] = w * (float)pk[2];
      sm0[PIDX(l, c4) + 3] = w * (float)pk[3];
      sm1[PIDX(l, c4) + 0] = (float)vvv[0];
      sm1[PIDX(l, c4) + 1] = (float)vvv[1];
      sm1[PIDX(l, c4) + 2] = (float)vvv[2];
      sm1[PIDX(l, c4) + 3] = (float)vvv[3];
    }
    __syncthreads();
#pragma unroll
    for (int i = 0; i < 16; ++i) {
      int ll = wv * 16 + i;
      float4 a0 = *(const float4*)&sm0[PIDX(ll, R)];
      float4 a1 = *(const float4*)&sm0[PIDX(ll, R + 4)];
      float4 b0 = *(const float4*)&sm1[PIDX(ll, Cc)];
      float4 b1 = *(const float4*)&sm1[PIDX(ll, Cc + 4)];
      float av[8] = {a0.x, a0.y, a0.z, a0.w, a1.x, a1.y, a1.z, a1.w};
      float bv2[8] = {b0.x, b0.y, b0.z, b0.w, b1.x, b1.y, b1.z, b1.w};
#pragma unroll
      for (int ii = 0; ii < 8; ++ii)
#pragma unroll
        for (int jj = 0; jj < 8; ++jj) acc[ii][jj] += av[ii] * bv2[jj];
      if ((lane & 7) == 0) {
#pragma unroll
        for (int ii = 0; ii < 8; ++ii) ks[ii] += av[ii];
      }
    }
  }

  __syncthreads();
  if ((lane & 7) == 0) {
#pragma unroll
    for (int i = 0; i < 8; ++i) sm1[wv * 64 + R + i] = ks[i];
  }
  for (int w = 0; w < 4; ++w) {
    if (wv == w) {
#pragma unroll
      for (int i = 0; i < 8; ++i) {
        float* p0 = &sm0[AIDX(R + i, Cc)];
        if (w == 0) {
          *(float4*)p0 = make_float4(acc[i][0], acc[i][1], acc[i][2], acc[i][3]);
          *(float4*)(p0 + 4) = make_float4(acc[i][4], acc[i][5], acc[i][6], acc[i][7]);
        } else {
          float4 o0 = *(const float4*)p0, o1 = *(const float4*)(p0 + 4);
          o0.x += acc[i][0]; o0.y += acc[i][1]; o0.z += acc[i][2]; o0.w += acc[i][3];
          o1.x += acc[i][4]; o1.y += acc[i][5]; o1.z += acc[i][6]; o1.w += acc[i][7];
          *(float4*)p0 = o0;
          *(float4*)(p0 + 4) = o1;
        }
      }
    }
    __syncthreads();
  }
  if (t < 64) {
    float s = sm1[t] + sm1[64 + t] + sm1[128 + t] + sm1[192 + t];
    atomicAdd(&ksum[bh * 64 + t], s);
  }
  float* dst = kvp + ((size_t)bh * 16 + part) * 4096;
#pragma unroll
  for (int i = 0; i < 16; ++i) {
    int idx = i * 256 + t;
    dst[idx] = sm0[AIDX(idx & 63, idx >> 6)];
  }
}

// compact per-head kvT[b][h][e][d] (f16), summing 16 partials.
__global__ __launch_bounds__(256) void build_kvt(const float* __restrict__ kvp,
                                                 f16* __restrict__ kvt) {
  int i = blockIdx.x * 256 + threadIdx.x;
  int bh = i >> 12;
  const float* p = kvp + ((size_t)bh * 16) * 4096 + (i & 4095);
  float v = 0.f;
#pragma unroll
  for (int pp = 0; pp < 16; ++pp) v += p[pp * 4096];
  kvt[i] = (f16)v;
}

// bottom[b*L*H]: phiQ . ksum per (token, head)
__global__ __launch_bounds__(256) void bottom_kernel(const f16* __restrict__ phiQ,
                                                     const float* __restrict__ ksum,
                                                     float* __restrict__ bot) {
  int wv = threadIdx.x >> 6, lane = threadIdx.x & 63;
  int token = blockIdx.x * 4 + wv;
  int b = token >> 12;
  const f16* row = phiQ + (size_t)token * C_;
  int h = lane >> 3, j0 = (lane & 7) * 8;
  const float* ks = ksum + (b * H_ + h) * 64 + j0;
  float p = 0.f;
#pragma unroll
  for (int j = 0; j < 8; ++j) p += ks[j] * (float)row[h * DH_ + j0 + j];
  p += __shfl_xor(p, 1); p += __shfl_xor(p, 2); p += __shfl_xor(p, 4);
  if ((lane & 7) == 0) bot[(size_t)token * H_ + h] = p;
}

// ---------------------------------------------------------------- launch
extern "C" void kernel_launch(void* const* d_in, const int* in_sizes, int n_in,
                              void* d_out, int out_size, void* d_ws, size_t ws_size,
                              hipStream_t stream) {
  (void)in_sizes; (void)n_in; (void)out_size; (void)ws_size;
  const float* x     = (const float*)d_in[0];
  const float* Wq    = (const float*)d_in[1];
  const float* bq    = (const float*)d_in[2];
  const float* gq    = (const float*)d_in[3];
  const float* betaq = (const float*)d_in[4];
  const float* Wk    = (const float*)d_in[5];
  const float* bk    = (const float*)d_in[6];
  const float* gk    = (const float*)d_in[7];
  const float* betak = (const float*)d_in[8];
  const float* Wv    = (const float*)d_in[9];
  const float* bv    = (const float*)d_in[10];
  const float* gv    = (const float*)d_in[11];
  const float* betav = (const float*)d_in[12];
  const float* Wkq   = (const float*)d_in[13];
  const float* bkq   = (const float*)d_in[14];
  const float* Wkk   = (const float*)d_in[15];
  const float* bkk   = (const float*)d_in[16];
  const float* g_at  = (const float*)d_in[17];
  const float* b_at  = (const float*)d_in[18];
  const float* W1    = (const float*)d_in[19];
  const float* b1    = (const float*)d_in[20];
  const float* W2    = (const float*)d_in[21];
  const float* b2    = (const float*)d_in[22];
  float* out = (float*)d_out;

  char* ws = (char*)d_ws;
  size_t off = 0;
  auto alloc = [&](size_t bytes) -> void* {
    void* p = ws + off;
    off += (bytes + 255) & ~(size_t)255;
    return p;
  };
  f16* U1    = (f16*)alloc((size_t)BL_ * MLP_ * 2);       // 64 MB
  f16* QKVh  = (f16*)alloc((size_t)3 * BL_ * C_ * 2);     // 48 MB
  f16* phiQK = (f16*)alloc((size_t)2 * BL_ * C_ * 2);     // 32 MB
  f16* xf    = (f16*)alloc((size_t)BL_ * C_ * 2);         // 16 MB
  f16* WqkvT = (f16*)alloc((size_t)3 * C_ * C_ * 2);
  f16* WkqT  = (f16*)alloc((size_t)C_ * C_ * 2);
  f16* WkkT  = (f16*)alloc((size_t)C_ * C_ * 2);
  f16* W1T   = (f16*)alloc((size_t)C_ * MLP_ * 2);
  f16* W2T   = (f16*)alloc((size_t)MLP_ * C_ * 2);
  f16* kvt   = (f16*)alloc((size_t)B_ * H_ * DH_ * DH_ * 2);
  float* score = (float*)alloc((size_t)B_ * H_ * LK_ * 4);
  float* qp    = (float*)alloc((size_t)B_ * C_ * 4);
  float* kvp   = (float*)alloc((size_t)B_ * H_ * 16 * 4096 * 4);
  float* ksum  = (float*)alloc((size_t)B_ * H_ * DH_ * 4);
  float* bot   = (float*)alloc((size_t)BL_ * H_ * 4);
  float* bqkv    = (float*)alloc(1536 * 4);
  float* gqkv    = (float*)alloc(1536 * 4);
  float* betaqkv = (float*)alloc(1536 * 4);
  float* bphi    = (float*)alloc(1024 * 4);

  f16* tmpqkv = U1;
  f16* tmpA   = U1;
  f16* h1     = U1;
  f16* Qh = QKVh;
  f16* Kh = QKVh + (size_t)BL_ * C_;
  f16* Vh = QKVh + (size_t)2 * BL_ * C_;
  f16* ah = QKVh;
  f16* phiQ = phiQK;
  f16* phiK = phiQK + (size_t)BL_ * C_;

  dim3 blk(256);
  dim3 blk512(512);

  pack_params<<<6, blk, 0, stream>>>(bq, bk, bv, gq, gk, gv, betaq, betak, betav,
                                     bkq, bkk, bqkv, gqkv, betaqkv, bphi);

  transpose_w5<<<dim3(16, 16, 5), blk, 0, stream>>>(Wq, Wk, Wv, Wkq, Wkk, WqkvT);
  transpose_w<<<dim3(MLP_ / 32, C_ / 32), blk, 0, stream>>>(W1, W1T, C_, MLP_);
  transpose_w<<<dim3(C_ / 32, MLP_ / 32), blk, 0, stream>>>(W2, W2T, MLP_, C_);

  transpose_x<<<dim3(L_ / 32, C_ / 32, B_), blk, 0, stream>>>(x, xf);

  // fused QKV projection: [16384,512] @ [512,1536] -> tmpqkv f16 (256^2 pipeline)
  gemm256<5><<<dim3(BL_ / 256, 1536 / 256), blk512, 0, stream>>>(
      xf, WqkvT, bqkv, tmpqkv, 1536, C_, 0, 0, 0, 0);
  ln16<<<3 * BL_ / 4, blk, 0, stream>>>(tmpqkv, gqkv, betaqkv, QKVh, 1);

  hipMemsetAsync(qp, 0, (size_t)B_ * C_ * 4, stream);
  qprobe2<<<BL_ / 64, blk, 0, stream>>>(Qh, qp);

  // phi projections, z-batched (z=0: Qh@Wkq->phiQ, z=1: Kh@Wkk->phiK)
  gemm256<1><<<dim3(BL_ / 256, C_ / 256, 2), blk512, 0, stream>>>(
      Qh, WkqT, bphi, phiQ, C_, C_,
      (long long)BL_ * C_, (long long)C_ * C_, (long long)BL_ * C_, (long long)C_);

  logits_kernel<<<BL_ / 4, blk, 0, stream>>>(Kh, qp, score);
  softmax_kernel<<<B_ * H_, blk, 0, stream>>>(score);

  ksum_init<<<(B_ * H_ * DH_) / 256, blk, 0, stream>>>(score, bkk, ksum);
  kv_part_kernel<<<dim3(16, B_ * H_), blk, 0, stream>>>(phiK, Vh, score, kvp, ksum);

  build_kvt<<<(B_ * H_ * DH_ * DH_) / 256, blk, 0, stream>>>(kvp, kvt);
  bottom_kernel<<<BL_ / 4, blk, 0, stream>>>(phiQ, ksum, bot);

  attn_out<<<dim3(BL_ / 128, H_), blk, 0, stream>>>(phiQ, kvt, bot, tmpA);

  ln16<<<BL_ / 4, blk, 0, stream>>>(tmpA, g_at, b_at, ah, 0);

  // MLP up (256^2 pipeline)
  gemm256<2><<<dim3(BL_ / 256, MLP_ / 256), blk512, 0, stream>>>(
      ah, W1T, b1, h1, MLP_, C_, 0, 0, 0, 0);
  // MLP down fused with residual-add + transpose + x-add -> out (kept: grid-limited at 256^2)
  gemm64<6><<<dim3(BL_ / 128, C_ / 128), blk, 0, stream>>>(
      h1, W2T, b2, nullptr, C_, MLP_, ah, x, out, 0, 0, 0, 0);
}

// Round 7
// 392.547 us; speedup vs baseline: 1.0549x; 1.0136x over previous
//
#include <hip/hip_runtime.h>
#include <math.h>

#define B_ 4
#define C_ 512
#define L_ 4096
#define H_ 8
#define DH_ 64
#define MLP_ 2048
#define BL_ (B_*L_)      // 16384
#define LK_ (L_+1)       // 4097

typedef _Float16 f16;
typedef _Float16 f16x8 __attribute__((ext_vector_type(8)));
typedef _Float16 f16x4 __attribute__((ext_vector_type(4)));
typedef float f32x4 __attribute__((ext_vector_type(4)));

// async global->LDS, 16B per lane (m97 pattern)
__device__ __forceinline__ void gl16(void* lds, const void* g) {
  __builtin_amdgcn_global_load_lds((const __attribute__((address_space(1))) void*)g,
                                   (__attribute__((address_space(3))) void*)lds,
                                   16, 0, 0);
}

__device__ __forceinline__ float frcp(float x) { return __builtin_amdgcn_rcpf(x); }

// ---------------------------------------------------------------- transposes
__global__ __launch_bounds__(256) void transpose_w5(const float* __restrict__ Wq,
                                                    const float* __restrict__ Wk,
                                                    const float* __restrict__ Wv,
                                                    const float* __restrict__ Wkq,
                                                    const float* __restrict__ Wkk,
                                                    f16* __restrict__ dst) {
  int z = blockIdx.z;
  const float* W = (z == 0) ? Wq : (z == 1) ? Wk : (z == 2) ? Wv : (z == 3) ? Wkq : Wkk;
  f16* Wt = dst + (size_t)z * C_ * C_;
  __shared__ float tile[32][33];
  int n0 = blockIdx.x * 32, k0 = blockIdx.y * 32;
  int tx = threadIdx.x & 31, ty = threadIdx.x >> 5;
#pragma unroll
  for (int i = 0; i < 4; ++i)
    tile[ty + i * 8][tx] = W[(size_t)(k0 + ty + i * 8) * C_ + n0 + tx];
  __syncthreads();
#pragma unroll
  for (int i = 0; i < 4; ++i)
    Wt[(size_t)(n0 + ty + i * 8) * C_ + k0 + tx] = (f16)tile[tx][ty + i * 8];
}

__global__ __launch_bounds__(256) void transpose_w(const float* __restrict__ W,
                                                   f16* __restrict__ Wt, int K, int N) {
  __shared__ float tile[32][33];
  int n0 = blockIdx.x * 32, k0 = blockIdx.y * 32;
  int tx = threadIdx.x & 31, ty = threadIdx.x >> 5;
#pragma unroll
  for (int i = 0; i < 4; ++i)
    tile[ty + i * 8][tx] = W[(size_t)(k0 + ty + i * 8) * N + n0 + tx];
  __syncthreads();
#pragma unroll
  for (int i = 0; i < 4; ++i)
    Wt[(size_t)(n0 + ty + i * 8) * K + k0 + tx] = (f16)tile[tx][ty + i * 8];
}

__global__ __launch_bounds__(256) void transpose_x(const float* __restrict__ x,
                                                   f16* __restrict__ xf) {
  __shared__ float tile[32][33];
  int b = blockIdx.z;
  int l0 = blockIdx.x * 32, c0 = blockIdx.y * 32;
  int tx = threadIdx.x & 31, ty = threadIdx.x >> 5;
#pragma unroll
  for (int i = 0; i < 4; ++i)
    tile[ty + i * 8][tx] = x[((size_t)b * C_ + c0 + ty + i * 8) * L_ + l0 + tx];
  __syncthreads();
#pragma unroll
  for (int i = 0; i < 4; ++i)
    xf[((size_t)b * L_ + l0 + ty + i * 8) * C_ + c0 + tx] = (f16)tile[tx][ty + i * 8];
}

// ------------------------------------------------- pack small param vectors
__global__ __launch_bounds__(256) void pack_params(
    const float* bq, const float* bk, const float* bv,
    const float* gq, const float* gk, const float* gv,
    const float* betaq, const float* betak, const float* betav,
    const float* bkq, const float* bkk,
    float* bqkv, float* gqkv, float* betaqkv, float* bphi) {
  int i = blockIdx.x * 256 + threadIdx.x;  // 0..1535
  int w = i >> 9, c = i & 511;
  bqkv[i]    = (w == 0 ? bq : (w == 1 ? bk : bv))[c];
  gqkv[i]    = (w == 0 ? gq : (w == 1 ? gk : gv))[c];
  betaqkv[i] = (w == 0 ? betaq : (w == 1 ? betak : betav))[c];
  if (i < 1024) bphi[i] = (i < 512) ? bkq[i] : bkk[i - 512];
}

// ---------------------------------------------------------------- GEMM 128x128 single-buffer (m97 structure)
// C[M,N](f16) = act(A[M,K] @ Bt[N,K]^T + bias)
// BK=64, SINGLE-buffered 32 KB LDS, 2 barriers/k-step — the m97-exact
// structure (912 TF measured at these parameters, m103). 4-5 blocks/CU by
// LDS at __launch_bounds__(256,4): cross-BLOCK wave overlap (independent
// barriers) hides stage latency — the mechanism intra-block pipelining
// failed to provide (rounds 2/4/6 all ~575 TF).
// GRID ROLE SWAP: blockIdx.x = N-tile, blockIdx.y = M-tile, so the blocks
// sharing an A-panel are launch-adjacent (A over-fetch was 2.7x measured).
// EPI: 1 tanh(v)+1   2 gelu (tanh approx)
template <int EPI>
__global__ __launch_bounds__(256, 4) void gemm128s(const f16* __restrict__ A,
                                                   const f16* __restrict__ Bt,
                                                   const float* __restrict__ bias,
                                                   f16* __restrict__ Ch,
                                                   int N, int K,
                                                   long long zA, long long zB,
                                                   long long zC, long long zBias) {
  __shared__ f16 smem[16384];  // 32 KB: As(16K)|Bs(16K); epilogue: [128][128]
  A  += (size_t)blockIdx.z * zA;
  Bt += (size_t)blockIdx.z * zB;
  Ch += (size_t)blockIdx.z * zC;
  bias += (size_t)blockIdx.z * zBias;

  const int tid = threadIdx.x;
  const int lane = tid & 63, wv = tid >> 6;
  const int wm = wv >> 1, wn = wv & 1;
  const int bm = blockIdx.y * 128, bn = blockIdx.x * 128;   // swapped roles
  const int l15 = lane & 15, q = lane >> 4;

  const int srow = tid >> 3;
  const int schunk = (tid & 7) ^ (srow & 7);
  const f16* pa = A + (size_t)(bm + srow) * K + schunk * 8;
  const f16* pb = Bt + (size_t)(bn + srow) * K + schunk * 8;
  f16* la = smem + tid * 8;
  f16* lb = smem + 8192 + tid * 8;
  const int sw0 = (q ^ (lane & 7)) * 8;
  const int sw1 = ((4 + q) ^ (lane & 7)) * 8;

  f32x4 acc[4][4] = {};

  for (int k0 = 0; k0 < K; k0 += 64) {
    __syncthreads();               // prev k-step's reads of smem done
#pragma unroll
    for (int p = 0; p < 4; ++p) gl16(la + p * 2048, pa + (size_t)p * 32 * K + k0);
#pragma unroll
    for (int p = 0; p < 4; ++p) gl16(lb + p * 2048, pb + (size_t)p * 32 * K + k0);
    __syncthreads();               // compiler emits vmcnt(0) drain -> staged
#pragma unroll
    for (int ks = 0; ks < 2; ++ks) {
      const int sw = ks ? sw1 : sw0;
      f16x8 af[4], bf[4];
#pragma unroll
      for (int i = 0; i < 4; ++i)
        af[i] = *(const f16x8*)&smem[(wm * 64 + i * 16 + l15) * 64 + sw];
#pragma unroll
      for (int j = 0; j < 4; ++j)
        bf[j] = *(const f16x8*)&smem[8192 + (wn * 64 + j * 16 + l15) * 64 + sw];
#pragma unroll
      for (int i = 0; i < 4; ++i)
#pragma unroll
        for (int j = 0; j < 4; ++j)
          acc[i][j] = __builtin_amdgcn_mfma_f32_16x16x32_f16(af[i], bf[j], acc[i][j], 0, 0, 0);
    }
  }

  // epilogue: act -> smem [128][128] (col-chunk XOR swizzle)
  __syncthreads();
#pragma unroll
  for (int j = 0; j < 4; ++j) {
    int lc = wn * 64 + j * 16 + l15;
    float bb = bias[bn + lc];
#pragma unroll
    for (int i = 0; i < 4; ++i) {
#pragma unroll
      for (int r = 0; r < 4; ++r) {
        int lr = wm * 64 + i * 16 + q * 4 + r;
        float v = acc[i][j][r] + bb;
        if (EPI == 1) {
          v = 2.0f * frcp(1.0f + __expf(-2.0f * v));      // tanh(v)+1
        } else if (EPI == 2) {
          v = v * frcp(1.0f + __expf(-1.5957691f * (v + 0.044715f * v * v * v)));
        }
        smem[lr * 128 + ((((lc >> 3) ^ (lr & 15)) << 3) | (lc & 7))] = (f16)v;
      }
    }
  }
  __syncthreads();
#pragma unroll
  for (int p = 0; p < 8; ++p) {
    int idx = p * 256 + tid;
    int row = idx >> 4, ch = idx & 15;
    f16x8 vv = *(const f16x8*)&smem[row * 128 + ((ch ^ (row & 15)) << 3)];
    *(f16x8*)&Ch[(size_t)(bm + row) * N + bn + ch * 8] = vv;
  }
}

// ---------------------------------------------------------------- GEMM 256x256 (counted-vmcnt + setprio)
// round-6 structure + T5 setprio around MFMA clusters. Used for QKV (<5>).
template <int EPI>
__global__ __launch_bounds__(512, 2) void gemm256(const f16* __restrict__ A,
                                                  const f16* __restrict__ Bt,
                                                  const float* __restrict__ bias,
                                                  f16* __restrict__ Ch,
                                                  int N, int K,
                                                  long long zA, long long zB,
                                                  long long zC, long long zBias) {
  __shared__ f16 smem[65536];  // 128 KB
  A  += (size_t)blockIdx.z * zA;
  Bt += (size_t)blockIdx.z * zB;
  Ch += (size_t)blockIdx.z * zC;
  bias += (size_t)blockIdx.z * zBias;

  const int tid = threadIdx.x;
  const int lane = tid & 63, wv = tid >> 6;
  const int wm = wv >> 2, wn = wv & 3;
  const int bm = blockIdx.x * 256, bn = blockIdx.y * 256;
  const int l15 = lane & 15, q = lane >> 4;

  const int srow = tid >> 3;
  const int schunk = (tid & 7) ^ (srow & 7);
  const f16* pa = A + (size_t)(bm + srow) * K + schunk * 8;
  const f16* pb = Bt + (size_t)(bn + srow) * K + schunk * 8;
  const int sw0 = (q ^ (lane & 7)) * 8;
  const int sw1 = ((4 + q) ^ (lane & 7)) * 8;
  const int NT = K >> 6;

  auto STAGE = [&](int t) {
    f16* bs = smem + (t & 1) * 32768;
    const f16* pat = pa + t * 64;
    const f16* pbt = pb + t * 64;
#pragma unroll
    for (int p = 0; p < 4; ++p) gl16(bs + p * 4096 + tid * 8, pat + (size_t)p * 64 * K);
#pragma unroll
    for (int p = 0; p < 4; ++p) gl16(bs + 16384 + p * 4096 + tid * 8, pbt + (size_t)p * 64 * K);
  };

  f32x4 acc[8][4] = {};

  STAGE(0);
  STAGE(1);

  for (int t = 0; t < NT; ++t) {
    if (t < NT - 1) asm volatile("s_waitcnt vmcnt(8)" ::: "memory");
    else            asm volatile("s_waitcnt vmcnt(0)" ::: "memory");
    __builtin_amdgcn_s_barrier();
    asm volatile("" ::: "memory");

    const f16* As = smem + (t & 1) * 32768;
    const f16* Bs = As + 16384;

    f16x8 bfr[4][2], afr[4][2];
#pragma unroll
    for (int n = 0; n < 4; ++n) {
      bfr[n][0] = *(const f16x8*)&Bs[(wn * 64 + n * 16 + l15) * 64 + sw0];
      bfr[n][1] = *(const f16x8*)&Bs[(wn * 64 + n * 16 + l15) * 64 + sw1];
    }
#pragma unroll
    for (int m = 0; m < 4; ++m) {
      afr[m][0] = *(const f16x8*)&As[(wm * 128 + m * 16 + l15) * 64 + sw0];
      afr[m][1] = *(const f16x8*)&As[(wm * 128 + m * 16 + l15) * 64 + sw1];
    }
    __builtin_amdgcn_s_setprio(1);
#pragma unroll
    for (int ks = 0; ks < 2; ++ks)
#pragma unroll
      for (int m = 0; m < 4; ++m)
#pragma unroll
        for (int n = 0; n < 4; ++n)
          acc[m][n] = __builtin_amdgcn_mfma_f32_16x16x32_f16(afr[m][ks], bfr[n][ks], acc[m][n], 0, 0, 0);
    __builtin_amdgcn_s_setprio(0);
#pragma unroll
    for (int m = 0; m < 4; ++m) {
      afr[m][0] = *(const f16x8*)&As[(wm * 128 + (m + 4) * 16 + l15) * 64 + sw0];
      afr[m][1] = *(const f16x8*)&As[(wm * 128 + (m + 4) * 16 + l15) * 64 + sw1];
    }
    asm volatile("s_waitcnt lgkmcnt(0)" ::: "memory");
    __builtin_amdgcn_s_barrier();
    asm volatile("" ::: "memory");
    if (t + 2 < NT) STAGE(t + 2);
    __builtin_amdgcn_s_setprio(1);
#pragma unroll
    for (int ks = 0; ks < 2; ++ks)
#pragma unroll
      for (int m = 0; m < 4; ++m)
#pragma unroll
        for (int n = 0; n < 4; ++n)
          acc[m + 4][n] = __builtin_amdgcn_mfma_f32_16x16x32_f16(afr[m][ks], bfr[n][ks], acc[m + 4][n], 0, 0, 0);
    __builtin_amdgcn_s_setprio(0);
  }

  __syncthreads();
#pragma unroll
  for (int n = 0; n < 4; ++n) {
    int lc = wn * 64 + n * 16 + l15;
    float bb = bias[bn + lc];
#pragma unroll
    for (int m = 0; m < 8; ++m) {
#pragma unroll
      for (int r = 0; r < 4; ++r) {
        int lr = wm * 128 + m * 16 + q * 4 + r;
        float v = acc[m][n][r] + bb;
        if (EPI == 1) {
          v = 2.0f * frcp(1.0f + __expf(-2.0f * v));
        } else if (EPI == 2) {
          v = v * frcp(1.0f + __expf(-1.5957691f * (v + 0.044715f * v * v * v)));
        }
        smem[lr * 256 + ((((lc >> 3) ^ (lr & 31)) << 3) | (lc & 7))] = (f16)v;
      }
    }
  }
  __syncthreads();
#pragma unroll
  for (int p = 0; p < 16; ++p) {
    int idx = p * 512 + tid;
    int row = idx >> 5, ch = idx & 31;
    f16x8 vv = *(const f16x8*)&smem[row * 256 + ((ch ^ (row & 31)) << 3)];
    *(f16x8*)&Ch[(size_t)(bm + row) * N + bn + ch * 8] = vv;
  }
}

// ---------------------------------------------------------------- GEMM 128x128 dbuf (MLP-down)
// EPI 6: plain bias + a-residual + transposed f32 out (+x)
template <int EPI>
__global__ __launch_bounds__(256, 2) void gemm64(const f16* __restrict__ A,
                                                 const f16* __restrict__ Bt,
                                                 const float* __restrict__ bias,
                                                 f16* __restrict__ Ch,
                                                 int N, int K,
                                                 const f16* __restrict__ Ares,
                                                 const float* __restrict__ Xres,
                                                 float* __restrict__ Fout,
                                                 long long zA, long long zB,
                                                 long long zC, long long zBias) {
  __shared__ f16 smem[2 * 128 * 128];  // 64 KB
  A  += (size_t)blockIdx.z * zA;
  Bt += (size_t)blockIdx.z * zB;
  if (EPI != 6) Ch += (size_t)blockIdx.z * zC;
  bias += (size_t)blockIdx.z * zBias;

  const int tid = threadIdx.x;
  const int lane = tid & 63, wv = tid >> 6;
  const int wm = wv >> 1, wn = wv & 1;
  const int bm = blockIdx.x * 128, bn = blockIdx.y * 128;
  const int l15 = lane & 15, q = lane >> 4;

  const int srow = tid >> 3;
  const int schunk = (tid & 7) ^ (srow & 7);
  const f16* pa = A + (size_t)(bm + srow) * K + schunk * 8;
  const f16* pb = Bt + (size_t)(bn + srow) * K + schunk * 8;
  f16* la = smem + tid * 8;
  f16* lb = smem + 8192 + tid * 8;
  const int sw0 = (q ^ (lane & 7)) * 8;
  const int sw1 = ((4 + q) ^ (lane & 7)) * 8;

  f32x4 acc[4][4] = {};

#pragma unroll
  for (int p = 0; p < 4; ++p) gl16(la + p * 2048, pa + (size_t)p * 32 * K);
#pragma unroll
  for (int p = 0; p < 4; ++p) gl16(lb + p * 2048, pb + (size_t)p * 32 * K);

  int cur = 0;
  for (int k0 = 0; k0 < K; k0 += 64) {
    __syncthreads();
    const int nxt = cur ^ 1;
    if (k0 + 64 < K) {
#pragma unroll
      for (int p = 0; p < 4; ++p) gl16(la + nxt * 16384 + p * 2048, pa + (size_t)p * 32 * K + k0 + 64);
#pragma unroll
      for (int p = 0; p < 4; ++p) gl16(lb + nxt * 16384 + p * 2048, pb + (size_t)p * 32 * K + k0 + 64);
    }
    const f16* As = smem + cur * 16384;
    const f16* Bs = As + 8192;
#pragma unroll
    for (int ks = 0; ks < 2; ++ks) {
      const int sw = ks ? sw1 : sw0;
      f16x8 af[4], bf[4];
#pragma unroll
      for (int i = 0; i < 4; ++i)
        af[i] = *(const f16x8*)&As[(wm * 64 + i * 16 + l15) * 64 + sw];
#pragma unroll
      for (int j = 0; j < 4; ++j)
        bf[j] = *(const f16x8*)&Bs[(wn * 64 + j * 16 + l15) * 64 + sw];
#pragma unroll
      for (int i = 0; i < 4; ++i)
#pragma unroll
        for (int j = 0; j < 4; ++j)
          acc[i][j] = __builtin_amdgcn_mfma_f32_16x16x32_f16(af[i], bf[j], acc[i][j], 0, 0, 0);
    }
    cur = nxt;
  }

  __syncthreads();
#pragma unroll
  for (int j = 0; j < 4; ++j) {
    int lc = wn * 64 + j * 16 + l15;
    float bb = bias[bn + lc];
#pragma unroll
    for (int i = 0; i < 4; ++i) {
#pragma unroll
      for (int r = 0; r < 4; ++r) {
        int lr = wm * 64 + i * 16 + q * 4 + r;
        float v = acc[i][j][r] + bb;
        smem[lr * 128 + ((((lc >> 3) ^ (lr & 15)) << 3) | (lc & 7))] = (f16)v;
      }
    }
  }
  __syncthreads();

  if (EPI != 6) {
#pragma unroll
    for (int p = 0; p < 8; ++p) {
      int idx = p * 256 + tid;
      int row = idx >> 4, ch = idx & 15;
      f16x8 vv = *(const f16x8*)&smem[row * 128 + ((ch ^ (row & 15)) << 3)];
      *(f16x8*)&Ch[(size_t)(bm + row) * N + bn + ch * 8] = vv;
    }
  } else {
#pragma unroll
    for (int p = 0; p < 8; ++p) {
      int idx = p * 256 + tid;
      int row = idx >> 4, ch = idx & 15;
      f16x8 av = *(const f16x8*)&Ares[(size_t)(bm + row) * C_ + bn + ch * 8];
      f16* sp = &smem[row * 128 + ((ch ^ (row & 15)) << 3)];
      f16x8 sv = *(const f16x8*)sp;
#pragma unroll
      for (int jj = 0; jj < 8; ++jj) sv[jj] = (f16)((float)sv[jj] + (float)av[jj]);
      *(f16x8*)sp = sv;
    }
    __syncthreads();
    int c = tid & 127, lh = tid >> 7;
    int b = bm >> 12, lbase = (bm & 4095) + lh * 64;
    const float* xp = Xres + ((size_t)b * C_ + bn + c) * L_ + lbase;
    float* op = Fout + ((size_t)b * C_ + bn + c) * L_ + lbase;
    int chi = c >> 3, clo = c & 7;
#pragma unroll
    for (int s = 0; s < 16; ++s) {
      int l = lh * 64 + s * 4;
      float4 xv = *(const float4*)(xp + s * 4);
      float4 r;
      r.x = (float)smem[(l + 0) * 128 + (((chi ^ ((l + 0) & 15)) << 3) | clo)] + xv.x;
      r.y = (float)smem[(l + 1) * 128 + (((chi ^ ((l + 1) & 15)) << 3) | clo)] + xv.y;
      r.z = (float)smem[(l + 2) * 128 + (((chi ^ ((l + 2) & 15)) << 3) | clo)] + xv.z;
      r.w = (float)smem[(l + 3) * 128 + (((chi ^ ((l + 3) & 15)) << 3) | clo)] + xv.w;
      *(float4*)(op + s * 4) = r;
    }
  }
}

// ---------------------------------------------------------------- attention out
__global__ __launch_bounds__(256, 4) void attn_out(const f16* __restrict__ phiQ,
                                                   const f16* __restrict__ kvt,
                                                   const float* __restrict__ bot,
                                                   f16* __restrict__ Ch) {
  __shared__ f16 smem[12288];
  const int tid = threadIdx.x;
  const int lane = tid & 63, wv = tid >> 6;
  const int bm = blockIdx.x * 128;
  const int h = blockIdx.y;
  const int b = bm >> 12;
  const int l15 = lane & 15, q = lane >> 4;

  const int srow = tid >> 3;
  const int schunk = (tid & 7) ^ (srow & 7);
  const f16* pa = phiQ + (size_t)(bm + srow) * C_ + h * DH_ + schunk * 8;
  const f16* pb = kvt + ((size_t)(b * H_ + h) * DH_ + srow) * DH_ + schunk * 8;
  f16* la = smem + tid * 8;
  f16* lb = smem + 8192 + tid * 8;
  const int sw0 = (q ^ (lane & 7)) * 8;
  const int sw1 = ((4 + q) ^ (lane & 7)) * 8;

#pragma unroll
  for (int p = 0; p < 4; ++p) gl16(la + p * 2048, pa + (size_t)p * 32 * C_);
#pragma unroll
  for (int p = 0; p < 2; ++p) gl16(lb + p * 2048, pb + (size_t)p * 32 * DH_);
  __syncthreads();

  f32x4 acc[2][4] = {};
#pragma unroll
  for (int ks = 0; ks < 2; ++ks) {
    const int sw = ks ? sw1 : sw0;
    f16x8 af[2], bf[4];
#pragma unroll
    for (int i = 0; i < 2; ++i)
      af[i] = *(const f16x8*)&smem[(wv * 32 + i * 16 + l15) * 64 + sw];
#pragma unroll
    for (int j = 0; j < 4; ++j)
      bf[j] = *(const f16x8*)&smem[8192 + (j * 16 + l15) * 64 + sw];
#pragma unroll
    for (int i = 0; i < 2; ++i)
#pragma unroll
      for (int j = 0; j < 4; ++j)
        acc[i][j] = __builtin_amdgcn_mfma_f32_16x16x32_f16(af[i], bf[j], acc[i][j], 0, 0, 0);
  }
  __syncthreads();

#pragma unroll
  for (int j = 0; j < 4; ++j) {
    int lc = j * 16 + l15;
#pragma unroll
    for (int i = 0; i < 2; ++i) {
#pragma unroll
      for (int r = 0; r < 4; ++r) {
        int lr = wv * 32 + i * 16 + q * 4 + r;
        float v = acc[i][j][r] * frcp(bot[(size_t)(bm + lr) * H_ + h] + 1e-6f);
        smem[lr * 64 + ((((lc >> 3) ^ (lr & 7)) << 3) | (lc & 7))] = (f16)v;
      }
    }
  }
  __syncthreads();

#pragma unroll
  for (int p = 0; p < 4; ++p) {
    int idx = p * 256 + tid;
    int row = idx >> 3, ch = idx & 7;
    f16x8 vv = *(const f16x8*)&smem[row * 64 + ((ch ^ (row & 7)) << 3)];
    *(f16x8*)&Ch[(size_t)(bm + row) * C_ + h * DH_ + ch * 8] = vv;
  }
}

// ---------------------------------------------------------------- LayerNorm (f16 in/out)
__global__ __launch_bounds__(256) void ln16(const f16* __restrict__ X,
                                            const float* __restrict__ g,
                                            const float* __restrict__ bta,
                                            f16* __restrict__ Y, int threeway) {
  int wv = threadIdx.x >> 6, lane = threadIdx.x & 63;
  int r = blockIdx.x * 4 + wv;
  int token = r, which = 0;
  if (threeway) { token = r / 3; which = r - token * 3; }
  const f16* xr = X + (size_t)r * C_;
  f16x8 v = *(const f16x8*)(xr + lane * 8);
  float vals[8];
  float s = 0.f, s2 = 0.f;
#pragma unroll
  for (int j = 0; j < 8; ++j) { vals[j] = (float)v[j]; s += vals[j]; s2 += vals[j] * vals[j]; }
#pragma unroll
  for (int m_ = 1; m_ < 64; m_ <<= 1) { s += __shfl_xor(s, m_); s2 += __shfl_xor(s2, m_); }
  float mu = s * (1.f / C_);
  float var = s2 * (1.f / C_) - mu * mu;
  float rstd = rsqrtf(var + 1e-5f);
  const float* gp = g + which * C_;
  const float* bp = bta + which * C_;
  f16x8 o;
#pragma unroll
  for (int j = 0; j < 8; ++j) {
    int c = lane * 8 + j;
    o[j] = (f16)((vals[j] - mu) * rstd * gp[c] + bp[c]);
  }
  *(f16x8*)(Y + ((size_t)which * BL_ + token) * C_ + lane * 8) = o;
}

// ---------------------------------------------------------------- q_probe
__global__ __launch_bounds__(256) void qprobe2(const f16* __restrict__ Q,
                                               float* __restrict__ qp) {
  int blk = blockIdx.x;
  int b = blk >> 6;
  int r0 = blk * 64;
  int t = threadIdx.x;
  int c8 = (t & 63) * 8, rg = t >> 6;
  float s[8] = {0.f, 0.f, 0.f, 0.f, 0.f, 0.f, 0.f, 0.f};
#pragma unroll
  for (int i = 0; i < 16; ++i) {
    const f16* row = Q + ((size_t)r0 + rg + i * 4) * C_ + c8;
    f16x8 v = *(const f16x8*)row;
#pragma unroll
    for (int j = 0; j < 8; ++j) s[j] += (float)v[j];
  }
  __shared__ float red[4][520];
#pragma unroll
  for (int j = 0; j < 8; ++j) red[rg][c8 + j] = s[j];
  __syncthreads();
  int c = t * 2;
  float a0 = red[0][c] + red[1][c] + red[2][c] + red[3][c];
  float a1 = red[0][c + 1] + red[1][c + 1] + red[2][c + 1] + red[3][c + 1];
  atomicAdd(&qp[b * C_ + c], a0);
  atomicAdd(&qp[b * C_ + c + 1], a1);
}

// ---------------------------------------------------------------- score logits
__global__ __launch_bounds__(256) void logits_kernel(const f16* __restrict__ Kh,
                                                     const float* __restrict__ qp,
                                                     float* __restrict__ score) {
  int wv = threadIdx.x >> 6, lane = threadIdx.x & 63;
  int token = blockIdx.x * 4 + wv;
  int b = token >> 12;
  int l = token & (L_ - 1);
  const f16* row = Kh + (size_t)token * C_;
  int h = lane >> 3, j0 = (lane & 7) * 8;
  const float* qph = qp + b * C_ + h * DH_ + j0;
  float p = 0.f;
#pragma unroll
  for (int j = 0; j < 8; ++j) p += qph[j] * (float)row[h * DH_ + j0 + j];
  p += __shfl_xor(p, 1); p += __shfl_xor(p, 2); p += __shfl_xor(p, 4);
  if ((lane & 7) == 0)
    score[((size_t)b * H_ + h) * LK_ + 1 + l] = p * (1.f / L_) * 0.125f;
}

__global__ __launch_bounds__(256) void softmax_kernel(float* __restrict__ score) {
  int bh = blockIdx.x, t = threadIdx.x;
  float* s = score + (size_t)bh * LK_;
  __shared__ float red[256];
  float mx = 0.f;
  for (int i = t; i < L_; i += 256) mx = fmaxf(mx, s[1 + i]);
  red[t] = mx; __syncthreads();
  for (int k = 128; k; k >>= 1) { if (t < k) red[t] = fmaxf(red[t], red[t + k]); __syncthreads(); }
  mx = red[0]; __syncthreads();
  float sum = (t == 0) ? expf(-mx) : 0.f;
  for (int i = t; i < L_; i += 256) { float e = expf(s[1 + i] - mx); s[1 + i] = e; sum += e; }
  red[t] = sum; __syncthreads();
  for (int k = 128; k; k >>= 1) { if (t < k) red[t] += red[t + k]; __syncthreads(); }
  float inv = 1.f / red[0];
  __syncthreads();
  for (int i = t; i < L_; i += 256) s[1 + i] *= inv;
  if (t == 0) s[0] = expf(-mx) * inv;
}

// ---------------------------------------------------------------- kv / ksum
__global__ __launch_bounds__(256) void ksum_init(const float* __restrict__ score,
                                                 const float* __restrict__ bkk,
                                                 float* __restrict__ ksum) {
  int i = blockIdx.x * 256 + threadIdx.x;
  int bh = i >> 6, d = i & 63, h = bh & 7;
  float pk0 = tanhf(bkk[h * DH_ + d]) + 1.f;
  ksum[i] = score[(size_t)bh * LK_] * pk0;
}

#define PIDX(l, c) ((l) * 68 + (c))
#define AIDX(d, e) ((d) * 68 + (e) + ((((d) >> 3)) << 2))
__global__ __launch_bounds__(256, 2) void kv_part_kernel(const f16* __restrict__ phiK,
                                                         const f16* __restrict__ Vh,
                                                         const float* __restrict__ score,
                                                         float* __restrict__ kvp,
                                                         float* __restrict__ ksum) {
  __shared__ float sm0[4416];
  __shared__ float sm1[4416];
  int bh = blockIdx.y, b = bh >> 3, h = bh & 7;
  int part = blockIdx.x;
  int l0 = part * 256;
  int t = threadIdx.x, lane = t & 63, wv = t >> 6;
  int R = (lane >> 3) * 8, Cc = (lane & 7) * 8;
  float acc[8][8] = {};
  float ks[8] = {0.f, 0.f, 0.f, 0.f, 0.f, 0.f, 0.f, 0.f};

  for (int c = 0; c < 4; ++c) {
    int lc = l0 + c * 64;
    __syncthreads();
#pragma unroll
    for (int p = 0; p < 4; ++p) {
      int l = p * 16 + (t >> 4);
      int c4 = (t & 15) * 4;
      size_t grow = ((size_t)b * L_ + lc + l) * C_ + h * DH_ + c4;
      float w = score[(size_t)bh * LK_ + 1 + lc + l];
      f16x4 pk = *(const f16x4*)(phiK + grow);
      f16x4 vvv = *(const f16x4*)(Vh + grow);
      sm0[PIDX(l, c4) + 0] = w * (float)pk[0];
      sm0[PIDX(l, c4) + 1] = w * (float)pk[1];
      sm0[PIDX(l, c4) + 2] = w * (float)pk[2];
      sm0[PIDX(l, c4) + 3] = w * (float)pk[3];
      sm1[PIDX(l, c4) + 0] = (float)vvv[0];
      sm1[PIDX(l, c4) + 1] = (float)vvv[1];
      sm1[PIDX(l, c4) + 2] = (float)vvv[2];
      sm1[PIDX(l, c4) + 3] = (float)vvv[3];
    }
    __syncthreads();
#pragma unroll
    for (int i = 0; i < 16; ++i) {
      int ll = wv * 16 + i;
      float4 a0 = *(const float4*)&sm0[PIDX(ll, R)];
      float4 a1 = *(const float4*)&sm0[PIDX(ll, R + 4)];
      float4 b0 = *(const float4*)&sm1[PIDX(ll, Cc)];
      float4 b1 = *(const float4*)&sm1[PIDX(ll, Cc + 4)];
      float av[8] = {a0.x, a0.y, a0.z, a0.w, a1.x, a1.y, a1.z, a1.w};
      float bv2[8] = {b0.x, b0.y, b0.z, b0.w, b1.x, b1.y, b1.z, b1.w};
#pragma unroll
      for (int ii = 0; ii < 8; ++ii)
#pragma unroll
        for (int jj = 0; jj < 8; ++jj) acc[ii][jj] += av[ii] * bv2[jj];
      if ((lane & 7) == 0) {
#pragma unroll
        for (int ii = 0; ii < 8; ++ii) ks[ii] += av[ii];
      }
    }
  }

  __syncthreads();
  if ((lane & 7) == 0) {
#pragma unroll
    for (int i = 0; i < 8; ++i) sm1[wv * 64 + R + i] = ks[i];
  }
  for (int w = 0; w < 4; ++w) {
    if (wv == w) {
#pragma unroll
      for (int i = 0; i < 8; ++i) {
        float* p0 = &sm0[AIDX(R + i, Cc)];
        if (w == 0) {
          *(float4*)p0 = make_float4(acc[i][0], acc[i][1], acc[i][2], acc[i][3]);
          *(float4*)(p0 + 4) = make_float4(acc[i][4], acc[i][5], acc[i][6], acc[i][7]);
        } else {
          float4 o0 = *(const float4*)p0, o1 = *(const float4*)(p0 + 4);
          o0.x += acc[i][0]; o0.y += acc[i][1]; o0.z += acc[i][2]; o0.w += acc[i][3];
          o1.x += acc[i][4]; o1.y += acc[i][5]; o1.z += acc[i][6]; o1.w += acc[i][7];
          *(float4*)p0 = o0;
          *(float4*)(p0 + 4) = o1;
        }
      }
    }
    __syncthreads();
  }
  if (t < 64) {
    float s = sm1[t] + sm1[64 + t] + sm1[128 + t] + sm1[192 + t];
    atomicAdd(&ksum[bh * 64 + t], s);
  }
  float* dst = kvp + ((size_t)bh * 16 + part) * 4096;
#pragma unroll
  for (int i = 0; i < 16; ++i) {
    int idx = i * 256 + t;
    dst[idx] = sm0[AIDX(idx & 63, idx >> 6)];
  }
}

// compact per-head kvT[b][h][e][d] (f16), summing 16 partials.
__global__ __launch_bounds__(256) void build_kvt(const float* __restrict__ kvp,
                                                 f16* __restrict__ kvt) {
  int i = blockIdx.x * 256 + threadIdx.x;
  int bh = i >> 12;
  const float* p = kvp + ((size_t)bh * 16) * 4096 + (i & 4095);
  float v = 0.f;
#pragma unroll
  for (int pp = 0; pp < 16; ++pp) v += p[pp * 4096];
  kvt[i] = (f16)v;
}

// bottom[b*L*H]: phiQ . ksum per (token, head)
__global__ __launch_bounds__(256) void bottom_kernel(const f16* __restrict__ phiQ,
                                                     const float* __restrict__ ksum,
                                                     float* __restrict__ bot) {
  int wv = threadIdx.x >> 6, lane = threadIdx.x & 63;
  int token = blockIdx.x * 4 + wv;
  int b = token >> 12;
  const f16* row = phiQ + (size_t)token * C_;
  int h = lane >> 3, j0 = (lane & 7) * 8;
  const float* ks = ksum + (b * H_ + h) * 64 + j0;
  float p = 0.f;
#pragma unroll
  for (int j = 0; j < 8; ++j) p += ks[j] * (float)row[h * DH_ + j0 + j];
  p += __shfl_xor(p, 1); p += __shfl_xor(p, 2); p += __shfl_xor(p, 4);
  if ((lane & 7) == 0) bot[(size_t)token * H_ + h] = p;
}

// ---------------------------------------------------------------- launch
extern "C" void kernel_launch(void* const* d_in, const int* in_sizes, int n_in,
                              void* d_out, int out_size, void* d_ws, size_t ws_size,
                              hipStream_t stream) {
  (void)in_sizes; (void)n_in; (void)out_size; (void)ws_size;
  const float* x     = (const float*)d_in[0];
  const float* Wq    = (const float*)d_in[1];
  const float* bq    = (const float*)d_in[2];
  const float* gq    = (const float*)d_in[3];
  const float* betaq = (const float*)d_in[4];
  const float* Wk    = (const float*)d_in[5];
  const float* bk    = (const float*)d_in[6];
  const float* gk    = (const float*)d_in[7];
  const float* betak = (const float*)d_in[8];
  const float* Wv    = (const float*)d_in[9];
  const float* bv    = (const float*)d_in[10];
  const float* gv    = (const float*)d_in[11];
  const float* betav = (const float*)d_in[12];
  const float* Wkq   = (const float*)d_in[13];
  const float* bkq   = (const float*)d_in[14];
  const float* Wkk   = (const float*)d_in[15];
  const float* bkk   = (const float*)d_in[16];
  const float* g_at  = (const float*)d_in[17];
  const float* b_at  = (const float*)d_in[18];
  const float* W1    = (const float*)d_in[19];
  const float* b1    = (const float*)d_in[20];
  const float* W2    = (const float*)d_in[21];
  const float* b2    = (const float*)d_in[22];
  float* out = (float*)d_out;

  char* ws = (char*)d_ws;
  size_t off = 0;
  auto alloc = [&](size_t bytes) -> void* {
    void* p = ws + off;
    off += (bytes + 255) & ~(size_t)255;
    return p;
  };
  f16* U1    = (f16*)alloc((size_t)BL_ * MLP_ * 2);       // 64 MB
  f16* QKVh  = (f16*)alloc((size_t)3 * BL_ * C_ * 2);     // 48 MB
  f16* phiQK = (f16*)alloc((size_t)2 * BL_ * C_ * 2);     // 32 MB
  f16* xf    = (f16*)alloc((size_t)BL_ * C_ * 2);         // 16 MB
  f16* WqkvT = (f16*)alloc((size_t)3 * C_ * C_ * 2);
  f16* WkqT  = (f16*)alloc((size_t)C_ * C_ * 2);
  f16* WkkT  = (f16*)alloc((size_t)C_ * C_ * 2);
  f16* W1T   = (f16*)alloc((size_t)C_ * MLP_ * 2);
  f16* W2T   = (f16*)alloc((size_t)MLP_ * C_ * 2);
  f16* kvt   = (f16*)alloc((size_t)B_ * H_ * DH_ * DH_ * 2);
  float* score = (float*)alloc((size_t)B_ * H_ * LK_ * 4);
  float* qp    = (float*)alloc((size_t)B_ * C_ * 4);
  float* kvp   = (float*)alloc((size_t)B_ * H_ * 16 * 4096 * 4);
  float* ksum  = (float*)alloc((size_t)B_ * H_ * DH_ * 4);
  float* bot   = (float*)alloc((size_t)BL_ * H_ * 4);
  float* bqkv    = (float*)alloc(1536 * 4);
  float* gqkv    = (float*)alloc(1536 * 4);
  float* betaqkv = (float*)alloc(1536 * 4);
  float* bphi    = (float*)alloc(1024 * 4);

  f16* tmpqkv = U1;
  f16* tmpA   = U1;
  f16* h1     = U1;
  f16* Qh = QKVh;
  f16* Kh = QKVh + (size_t)BL_ * C_;
  f16* Vh = QKVh + (size_t)2 * BL_ * C_;
  f16* ah = QKVh;
  f16* phiQ = phiQK;
  f16* phiK = phiQK + (size_t)BL_ * C_;

  dim3 blk(256);
  dim3 blk512(512);

  pack_params<<<6, blk, 0, stream>>>(bq, bk, bv, gq, gk, gv, betaq, betak, betav,
                                     bkq, bkk, bqkv, gqkv, betaqkv, bphi);

  transpose_w5<<<dim3(16, 16, 5), blk, 0, stream>>>(Wq, Wk, Wv, Wkq, Wkk, WqkvT);
  transpose_w<<<dim3(MLP_ / 32, C_ / 32), blk, 0, stream>>>(W1, W1T, C_, MLP_);
  transpose_w<<<dim3(C_ / 32, MLP_ / 32), blk, 0, stream>>>(W2, W2T, MLP_, C_);

  transpose_x<<<dim3(L_ / 32, C_ / 32, B_), blk, 0, stream>>>(x, xf);

  // fused QKV projection (256^2 counted-vmcnt + setprio)
  gemm256<5><<<dim3(BL_ / 256, 1536 / 256), blk512, 0, stream>>>(
      xf, WqkvT, bqkv, tmpqkv, 1536, C_, 0, 0, 0, 0);
  ln16<<<3 * BL_ / 4, blk, 0, stream>>>(tmpqkv, gqkv, betaqkv, QKVh, 1);

  hipMemsetAsync(qp, 0, (size_t)B_ * C_ * 4, stream);
  qprobe2<<<BL_ / 64, blk, 0, stream>>>(Qh, qp);

  // phi projections (m97-sbuf 128^2; grid = (N-tiles, M-tiles, z))
  gemm128s<1><<<dim3(C_ / 128, BL_ / 128, 2), blk, 0, stream>>>(
      Qh, WkqT, bphi, phiQ, C_, C_,
      (long long)BL_ * C_, (long long)C_ * C_, (long long)BL_ * C_, (long long)C_);

  logits_kernel<<<BL_ / 4, blk, 0, stream>>>(Kh, qp, score);
  softmax_kernel<<<B_ * H_, blk, 0, stream>>>(score);

  ksum_init<<<(B_ * H_ * DH_) / 256, blk, 0, stream>>>(score, bkk, ksum);
  kv_part_kernel<<<dim3(16, B_ * H_), blk, 0, stream>>>(phiK, Vh, score, kvp, ksum);

  build_kvt<<<(B_ * H_ * DH_ * DH_) / 256, blk, 0, stream>>>(kvp, kvt);
  bottom_kernel<<<BL_ / 4, blk, 0, stream>>>(phiQ, ksum, bot);

  attn_out<<<dim3(BL_ / 128, H_), blk, 0, stream>>>(phiQ, kvt, bot, tmpA);

  ln16<<<BL_ / 4, blk, 0, stream>>>(tmpA, g_at, b_at, ah, 0);

  // MLP up (m97-sbuf 128^2; grid = (N-tiles, M-tiles))
  gemm128s<2><<<dim3(MLP_ / 128, BL_ / 128), blk, 0, stream>>>(
      ah, W1T, b1, h1, MLP_, C_, 0, 0, 0, 0);
  // MLP down fused with residual-add + transpose + x-add -> out
  gemm64<6><<<dim3(BL_ / 128, C_ / 128), blk, 0, stream>>>(
      h1, W2T, b2, nullptr, C_, MLP_, ah, x, out, 0, 0, 0, 0);
}

// Round 8
// 390.069 us; speedup vs baseline: 1.0616x; 1.0064x over previous
//
#include <hip/hip_runtime.h>
#include <math.h>

#define B_ 4
#define C_ 512
#define L_ 4096
#define H_ 8
#define DH_ 64
#define MLP_ 2048
#define BL_ (B_*L_)      // 16384
#define LK_ (L_+1)       // 4097

typedef _Float16 f16;
typedef _Float16 f16x8 __attribute__((ext_vector_type(8)));
typedef _Float16 f16x4 __attribute__((ext_vector_type(4)));
typedef float f32x4 __attribute__((ext_vector_type(4)));

// async global->LDS, 16B per lane (m97 pattern)
__device__ __forceinline__ void gl16(void* lds, const void* g) {
  __builtin_amdgcn_global_load_lds((const __attribute__((address_space(1))) void*)g,
                                   (__attribute__((address_space(3))) void*)lds,
                                   16, 0, 0);
}

__device__ __forceinline__ float frcp(float x) { return __builtin_amdgcn_rcpf(x); }

// ---------------------------------------------------------------- transposes
__global__ __launch_bounds__(256) void transpose_w5(const float* __restrict__ Wq,
                                                    const float* __restrict__ Wk,
                                                    const float* __restrict__ Wv,
                                                    const float* __restrict__ Wkq,
                                                    const float* __restrict__ Wkk,
                                                    f16* __restrict__ dst) {
  int z = blockIdx.z;
  const float* W = (z == 0) ? Wq : (z == 1) ? Wk : (z == 2) ? Wv : (z == 3) ? Wkq : Wkk;
  f16* Wt = dst + (size_t)z * C_ * C_;
  __shared__ float tile[32][33];
  int n0 = blockIdx.x * 32, k0 = blockIdx.y * 32;
  int tx = threadIdx.x & 31, ty = threadIdx.x >> 5;
#pragma unroll
  for (int i = 0; i < 4; ++i)
    tile[ty + i * 8][tx] = W[(size_t)(k0 + ty + i * 8) * C_ + n0 + tx];
  __syncthreads();
#pragma unroll
  for (int i = 0; i < 4; ++i)
    Wt[(size_t)(n0 + ty + i * 8) * C_ + k0 + tx] = (f16)tile[tx][ty + i * 8];
}

__global__ __launch_bounds__(256) void transpose_w(const float* __restrict__ W,
                                                   f16* __restrict__ Wt, int K, int N) {
  __shared__ float tile[32][33];
  int n0 = blockIdx.x * 32, k0 = blockIdx.y * 32;
  int tx = threadIdx.x & 31, ty = threadIdx.x >> 5;
#pragma unroll
  for (int i = 0; i < 4; ++i)
    tile[ty + i * 8][tx] = W[(size_t)(k0 + ty + i * 8) * N + n0 + tx];
  __syncthreads();
#pragma unroll
  for (int i = 0; i < 4; ++i)
    Wt[(size_t)(n0 + ty + i * 8) * K + k0 + tx] = (f16)tile[tx][ty + i * 8];
}

__global__ __launch_bounds__(256) void transpose_x(const float* __restrict__ x,
                                                   f16* __restrict__ xf) {
  __shared__ float tile[32][33];
  int b = blockIdx.z;
  int l0 = blockIdx.x * 32, c0 = blockIdx.y * 32;
  int tx = threadIdx.x & 31, ty = threadIdx.x >> 5;
#pragma unroll
  for (int i = 0; i < 4; ++i)
    tile[ty + i * 8][tx] = x[((size_t)b * C_ + c0 + ty + i * 8) * L_ + l0 + tx];
  __syncthreads();
#pragma unroll
  for (int i = 0; i < 4; ++i)
    xf[((size_t)b * L_ + l0 + ty + i * 8) * C_ + c0 + tx] = (f16)tile[tx][ty + i * 8];
}

// ------------------------------------------------- pack small param vectors
__global__ __launch_bounds__(256) void pack_params(
    const float* bq, const float* bk, const float* bv,
    const float* gq, const float* gk, const float* gv,
    const float* betaq, const float* betak, const float* betav,
    const float* bkq, const float* bkk,
    float* bqkv, float* gqkv, float* betaqkv, float* bphi) {
  int i = blockIdx.x * 256 + threadIdx.x;  // 0..1535
  int w = i >> 9, c = i & 511;
  bqkv[i]    = (w == 0 ? bq : (w == 1 ? bk : bv))[c];
  gqkv[i]    = (w == 0 ? gq : (w == 1 ? gk : gv))[c];
  betaqkv[i] = (w == 0 ? betaq : (w == 1 ? betak : betav))[c];
  if (i < 1024) bphi[i] = (i < 512) ? bkq[i] : bkk[i - 512];
}

// ---------------------------------------------------------------- GEMM 128x128 single-buffer (m97 structure)
// BK=64, SINGLE-buffered 32 KB LDS, 2 barriers/k-step, 4 blocks/CU —
// round-7 A/B winner for high-grid GEMMs (dropped below the <6> cutoff).
// Grid roles: blockIdx.x = N-tile, blockIdx.y = M-tile (A-panel L2 locality).
// EPI: 1 tanh(v)+1   2 gelu (tanh approx)   5 plain bias
template <int EPI>
__global__ __launch_bounds__(256, 4) void gemm128s(const f16* __restrict__ A,
                                                   const f16* __restrict__ Bt,
                                                   const float* __restrict__ bias,
                                                   f16* __restrict__ Ch,
                                                   int N, int K,
                                                   long long zA, long long zB,
                                                   long long zC, long long zBias) {
  __shared__ f16 smem[16384];  // 32 KB: As(16K)|Bs(16K); epilogue: [128][128]
  A  += (size_t)blockIdx.z * zA;
  Bt += (size_t)blockIdx.z * zB;
  Ch += (size_t)blockIdx.z * zC;
  bias += (size_t)blockIdx.z * zBias;

  const int tid = threadIdx.x;
  const int lane = tid & 63, wv = tid >> 6;
  const int wm = wv >> 1, wn = wv & 1;
  const int bm = blockIdx.y * 128, bn = blockIdx.x * 128;   // swapped roles
  const int l15 = lane & 15, q = lane >> 4;

  const int srow = tid >> 3;
  const int schunk = (tid & 7) ^ (srow & 7);
  const f16* pa = A + (size_t)(bm + srow) * K + schunk * 8;
  const f16* pb = Bt + (size_t)(bn + srow) * K + schunk * 8;
  f16* la = smem + tid * 8;
  f16* lb = smem + 8192 + tid * 8;
  const int sw0 = (q ^ (lane & 7)) * 8;
  const int sw1 = ((4 + q) ^ (lane & 7)) * 8;

  f32x4 acc[4][4] = {};

  for (int k0 = 0; k0 < K; k0 += 64) {
    __syncthreads();               // prev k-step's reads of smem done
#pragma unroll
    for (int p = 0; p < 4; ++p) gl16(la + p * 2048, pa + (size_t)p * 32 * K + k0);
#pragma unroll
    for (int p = 0; p < 4; ++p) gl16(lb + p * 2048, pb + (size_t)p * 32 * K + k0);
    __syncthreads();               // compiler emits vmcnt(0) drain -> staged
#pragma unroll
    for (int ks = 0; ks < 2; ++ks) {
      const int sw = ks ? sw1 : sw0;
      f16x8 af[4], bf[4];
#pragma unroll
      for (int i = 0; i < 4; ++i)
        af[i] = *(const f16x8*)&smem[(wm * 64 + i * 16 + l15) * 64 + sw];
#pragma unroll
      for (int j = 0; j < 4; ++j)
        bf[j] = *(const f16x8*)&smem[8192 + (wn * 64 + j * 16 + l15) * 64 + sw];
#pragma unroll
      for (int i = 0; i < 4; ++i)
#pragma unroll
        for (int j = 0; j < 4; ++j)
          acc[i][j] = __builtin_amdgcn_mfma_f32_16x16x32_f16(af[i], bf[j], acc[i][j], 0, 0, 0);
    }
  }

  // epilogue: act -> smem [128][128] (col-chunk XOR swizzle)
  __syncthreads();
#pragma unroll
  for (int j = 0; j < 4; ++j) {
    int lc = wn * 64 + j * 16 + l15;
    float bb = bias[bn + lc];
#pragma unroll
    for (int i = 0; i < 4; ++i) {
#pragma unroll
      for (int r = 0; r < 4; ++r) {
        int lr = wm * 64 + i * 16 + q * 4 + r;
        float v = acc[i][j][r] + bb;
        if (EPI == 1) {
          v = 2.0f * frcp(1.0f + __expf(-2.0f * v));      // tanh(v)+1
        } else if (EPI == 2) {
          v = v * frcp(1.0f + __expf(-1.5957691f * (v + 0.044715f * v * v * v)));
        }
        smem[lr * 128 + ((((lc >> 3) ^ (lr & 15)) << 3) | (lc & 7))] = (f16)v;
      }
    }
  }
  __syncthreads();
#pragma unroll
  for (int p = 0; p < 8; ++p) {
    int idx = p * 256 + tid;
    int row = idx >> 4, ch = idx & 15;
    f16x8 vv = *(const f16x8*)&smem[row * 128 + ((ch ^ (row & 15)) << 3)];
    *(f16x8*)&Ch[(size_t)(bm + row) * N + bn + ch * 8] = vv;
  }
}

// ---------------------------------------------------------------- GEMM 256x256 (counted-vmcnt + setprio)
// round-6/7 structure. Used for QKV (<5>) — dropped below cutoff in round 7.
template <int EPI>
__global__ __launch_bounds__(512, 2) void gemm256(const f16* __restrict__ A,
                                                  const f16* __restrict__ Bt,
                                                  const float* __restrict__ bias,
                                                  f16* __restrict__ Ch,
                                                  int N, int K,
                                                  long long zA, long long zB,
                                                  long long zC, long long zBias) {
  __shared__ f16 smem[65536];  // 128 KB
  A  += (size_t)blockIdx.z * zA;
  Bt += (size_t)blockIdx.z * zB;
  Ch += (size_t)blockIdx.z * zC;
  bias += (size_t)blockIdx.z * zBias;

  const int tid = threadIdx.x;
  const int lane = tid & 63, wv = tid >> 6;
  const int wm = wv >> 2, wn = wv & 3;
  const int bm = blockIdx.x * 256, bn = blockIdx.y * 256;
  const int l15 = lane & 15, q = lane >> 4;

  const int srow = tid >> 3;
  const int schunk = (tid & 7) ^ (srow & 7);
  const f16* pa = A + (size_t)(bm + srow) * K + schunk * 8;
  const f16* pb = Bt + (size_t)(bn + srow) * K + schunk * 8;
  const int sw0 = (q ^ (lane & 7)) * 8;
  const int sw1 = ((4 + q) ^ (lane & 7)) * 8;
  const int NT = K >> 6;

  auto STAGE = [&](int t) {
    f16* bs = smem + (t & 1) * 32768;
    const f16* pat = pa + t * 64;
    const f16* pbt = pb + t * 64;
#pragma unroll
    for (int p = 0; p < 4; ++p) gl16(bs + p * 4096 + tid * 8, pat + (size_t)p * 64 * K);
#pragma unroll
    for (int p = 0; p < 4; ++p) gl16(bs + 16384 + p * 4096 + tid * 8, pbt + (size_t)p * 64 * K);
  };

  f32x4 acc[8][4] = {};

  STAGE(0);
  STAGE(1);

  for (int t = 0; t < NT; ++t) {
    if (t < NT - 1) asm volatile("s_waitcnt vmcnt(8)" ::: "memory");
    else            asm volatile("s_waitcnt vmcnt(0)" ::: "memory");
    __builtin_amdgcn_s_barrier();
    asm volatile("" ::: "memory");

    const f16* As = smem + (t & 1) * 32768;
    const f16* Bs = As + 16384;

    f16x8 bfr[4][2], afr[4][2];
#pragma unroll
    for (int n = 0; n < 4; ++n) {
      bfr[n][0] = *(const f16x8*)&Bs[(wn * 64 + n * 16 + l15) * 64 + sw0];
      bfr[n][1] = *(const f16x8*)&Bs[(wn * 64 + n * 16 + l15) * 64 + sw1];
    }
#pragma unroll
    for (int m = 0; m < 4; ++m) {
      afr[m][0] = *(const f16x8*)&As[(wm * 128 + m * 16 + l15) * 64 + sw0];
      afr[m][1] = *(const f16x8*)&As[(wm * 128 + m * 16 + l15) * 64 + sw1];
    }
    __builtin_amdgcn_s_setprio(1);
#pragma unroll
    for (int ks = 0; ks < 2; ++ks)
#pragma unroll
      for (int m = 0; m < 4; ++m)
#pragma unroll
        for (int n = 0; n < 4; ++n)
          acc[m][n] = __builtin_amdgcn_mfma_f32_16x16x32_f16(afr[m][ks], bfr[n][ks], acc[m][n], 0, 0, 0);
    __builtin_amdgcn_s_setprio(0);
#pragma unroll
    for (int m = 0; m < 4; ++m) {
      afr[m][0] = *(const f16x8*)&As[(wm * 128 + (m + 4) * 16 + l15) * 64 + sw0];
      afr[m][1] = *(const f16x8*)&As[(wm * 128 + (m + 4) * 16 + l15) * 64 + sw1];
    }
    asm volatile("s_waitcnt lgkmcnt(0)" ::: "memory");
    __builtin_amdgcn_s_barrier();
    asm volatile("" ::: "memory");
    if (t + 2 < NT) STAGE(t + 2);
    __builtin_amdgcn_s_setprio(1);
#pragma unroll
    for (int ks = 0; ks < 2; ++ks)
#pragma unroll
      for (int m = 0; m < 4; ++m)
#pragma unroll
        for (int n = 0; n < 4; ++n)
          acc[m + 4][n] = __builtin_amdgcn_mfma_f32_16x16x32_f16(afr[m][ks], bfr[n][ks], acc[m + 4][n], 0, 0, 0);
    __builtin_amdgcn_s_setprio(0);
  }

  __syncthreads();
#pragma unroll
  for (int n = 0; n < 4; ++n) {
    int lc = wn * 64 + n * 16 + l15;
    float bb = bias[bn + lc];
#pragma unroll
    for (int m = 0; m < 8; ++m) {
#pragma unroll
      for (int r = 0; r < 4; ++r) {
        int lr = wm * 128 + m * 16 + q * 4 + r;
        float v = acc[m][n][r] + bb;
        if (EPI == 1) {
          v = 2.0f * frcp(1.0f + __expf(-2.0f * v));
        } else if (EPI == 2) {
          v = v * frcp(1.0f + __expf(-1.5957691f * (v + 0.044715f * v * v * v)));
        }
        smem[lr * 256 + ((((lc >> 3) ^ (lr & 31)) << 3) | (lc & 7))] = (f16)v;
      }
    }
  }
  __syncthreads();
#pragma unroll
  for (int p = 0; p < 16; ++p) {
    int idx = p * 512 + tid;
    int row = idx >> 5, ch = idx & 31;
    f16x8 vv = *(const f16x8*)&smem[row * 256 + ((ch ^ (row & 31)) << 3)];
    *(f16x8*)&Ch[(size_t)(bm + row) * N + bn + ch * 8] = vv;
  }
}

// ---------------------------------------------------------------- GEMM 128x128 dbuf, 512 threads (MLP-down)
// Identical LDS layout/swizzles/barrier structure to the verified 256-thr
// dbuf kernel; re-partitioned to 8 waves (2 wm x 4 wn, per-wave 64x32 out).
// 2 blocks/CU x 8 waves = 16 waves/CU: during one block's vmcnt(0) barrier
// drain, the other block now has 2 waves/SIMD (vs 1) to cover the MFMA pipe.
// EPI 6 fused epilogue: bias + a-residual + transposed f32 out (+x).
__global__ __launch_bounds__(512, 2) void gemm512d6(const f16* __restrict__ A,
                                                    const f16* __restrict__ Bt,
                                                    const float* __restrict__ bias,
                                                    int N, int K,
                                                    const f16* __restrict__ Ares,
                                                    const float* __restrict__ Xres,
                                                    float* __restrict__ Fout) {
  __shared__ f16 smem[2 * 128 * 128];  // 64 KB
  const int tid = threadIdx.x;
  const int lane = tid & 63, wv = tid >> 6;      // 8 waves
  const int wm = wv >> 2, wn = wv & 3;           // 2 x 4
  const int bm = blockIdx.x * 128, bn = blockIdx.y * 128;
  const int l15 = lane & 15, q = lane >> 4;

  const int srow = tid >> 3;                     // 0..63
  const int schunk = (tid & 7) ^ (srow & 7);
  const f16* pa = A + (size_t)(bm + srow) * K + schunk * 8;
  const f16* pb = Bt + (size_t)(bn + srow) * K + schunk * 8;
  f16* la = smem + tid * 8;                      // inst p covers rows p*64+srow
  f16* lb = smem + 8192 + tid * 8;
  const int sw0 = (q ^ (lane & 7)) * 8;
  const int sw1 = ((4 + q) ^ (lane & 7)) * 8;

  f32x4 acc[4][2] = {};

#pragma unroll
  for (int p = 0; p < 2; ++p) gl16(la + p * 4096, pa + (size_t)p * 64 * K);
#pragma unroll
  for (int p = 0; p < 2; ++p) gl16(lb + p * 4096, pb + (size_t)p * 64 * K);

  int cur = 0;
  for (int k0 = 0; k0 < K; k0 += 64) {
    __syncthreads();                 // vmcnt(0) drain: buf(cur) staged; buf(nxt) readers done
    const int nxt = cur ^ 1;
    if (k0 + 64 < K) {
#pragma unroll
      for (int p = 0; p < 2; ++p) gl16(la + nxt * 16384 + p * 4096, pa + (size_t)p * 64 * K + k0 + 64);
#pragma unroll
      for (int p = 0; p < 2; ++p) gl16(lb + nxt * 16384 + p * 4096, pb + (size_t)p * 64 * K + k0 + 64);
    }
    const f16* As = smem + cur * 16384;
    const f16* Bs = As + 8192;
#pragma unroll
    for (int ks = 0; ks < 2; ++ks) {
      const int sw = ks ? sw1 : sw0;
      f16x8 af[4], bf[2];
#pragma unroll
      for (int i = 0; i < 4; ++i)
        af[i] = *(const f16x8*)&As[(wm * 64 + i * 16 + l15) * 64 + sw];
#pragma unroll
      for (int j = 0; j < 2; ++j)
        bf[j] = *(const f16x8*)&Bs[(wn * 32 + j * 16 + l15) * 64 + sw];
#pragma unroll
      for (int i = 0; i < 4; ++i)
#pragma unroll
        for (int j = 0; j < 2; ++j)
          acc[i][j] = __builtin_amdgcn_mfma_f32_16x16x32_f16(af[i], bf[j], acc[i][j], 0, 0, 0);
    }
    cur = nxt;
  }

  // epilogue: bias -> smem [128][128] (col-chunk XOR swizzle)
  __syncthreads();
#pragma unroll
  for (int j = 0; j < 2; ++j) {
    int lc = wn * 32 + j * 16 + l15;
    float bb = bias[bn + lc];
#pragma unroll
    for (int i = 0; i < 4; ++i) {
#pragma unroll
      for (int r = 0; r < 4; ++r) {
        int lr = wm * 64 + i * 16 + q * 4 + r;
        float v = acc[i][j][r] + bb;
        smem[lr * 128 + ((((lc >> 3) ^ (lr & 15)) << 3) | (lc & 7))] = (f16)v;
      }
    }
  }
  __syncthreads();
  // a-residual (row-coalesced RMW in LDS)
#pragma unroll
  for (int p = 0; p < 4; ++p) {
    int idx = p * 512 + tid;
    int row = idx >> 4, ch = idx & 15;
    f16x8 av = *(const f16x8*)&Ares[(size_t)(bm + row) * C_ + bn + ch * 8];
    f16* sp = &smem[row * 128 + ((ch ^ (row & 15)) << 3)];
    f16x8 sv = *(const f16x8*)sp;
#pragma unroll
    for (int jj = 0; jj < 8; ++jj) sv[jj] = (f16)((float)sv[jj] + (float)av[jj]);
    *(f16x8*)sp = sv;
  }
  __syncthreads();
  // transposed f32 write: out[b][c][l] = tile[l][c] + x[b][c][l]
  int c = tid & 127, lh = tid >> 7;              // lh 0..3
  int b = bm >> 12, lbase = (bm & 4095) + lh * 32;
  const float* xp = Xres + ((size_t)b * C_ + bn + c) * L_ + lbase;
  float* op = Fout + ((size_t)b * C_ + bn + c) * L_ + lbase;
  int chi = c >> 3, clo = c & 7;
#pragma unroll
  for (int s = 0; s < 8; ++s) {
    int l = lh * 32 + s * 4;
    float4 xv = *(const float4*)(xp + s * 4);
    float4 r;
    r.x = (float)smem[(l + 0) * 128 + (((chi ^ ((l + 0) & 15)) << 3) | clo)] + xv.x;
    r.y = (float)smem[(l + 1) * 128 + (((chi ^ ((l + 1) & 15)) << 3) | clo)] + xv.y;
    r.z = (float)smem[(l + 2) * 128 + (((chi ^ ((l + 2) & 15)) << 3) | clo)] + xv.z;
    r.w = (float)smem[(l + 3) * 128 + (((chi ^ ((l + 3) & 15)) << 3) | clo)] + xv.w;
    *(float4*)(op + s * 4) = r;
  }
}

// ---------------------------------------------------------------- attention out (+ fused bottom)
// O[l, h*64+e] = (sum_d phiQ[l,h*64+d] * kvT[b][h][e][d]) / (phiQ[l,h].ksum[h] + 1e-6)
// bottom is computed from the ALREADY-STAGED phiQ A-tile (saves the separate
// bottom_kernel and its 16 MB phiQ re-read).
__global__ __launch_bounds__(256, 4) void attn_out(const f16* __restrict__ phiQ,
                                                   const f16* __restrict__ kvt,
                                                   const float* __restrict__ ksum,
                                                   f16* __restrict__ Ch) {
  __shared__ f16 smem[12288];
  __shared__ float bots[128];
  const int tid = threadIdx.x;
  const int lane = tid & 63, wv = tid >> 6;
  const int bm = blockIdx.x * 128;
  const int h = blockIdx.y;
  const int b = bm >> 12;
  const int l15 = lane & 15, q = lane >> 4;

  const int srow = tid >> 3;
  const int schunk = (tid & 7) ^ (srow & 7);
  const f16* pa = phiQ + (size_t)(bm + srow) * C_ + h * DH_ + schunk * 8;
  const f16* pb = kvt + ((size_t)(b * H_ + h) * DH_ + srow) * DH_ + schunk * 8;
  f16* la = smem + tid * 8;
  f16* lb = smem + 8192 + tid * 8;
  const int sw0 = (q ^ (lane & 7)) * 8;
  const int sw1 = ((4 + q) ^ (lane & 7)) * 8;

#pragma unroll
  for (int p = 0; p < 4; ++p) gl16(la + p * 2048, pa + (size_t)p * 32 * C_);
#pragma unroll
  for (int p = 0; p < 2; ++p) gl16(lb + p * 2048, pb + (size_t)p * 32 * DH_);
  __syncthreads();

  // bottom: row dot ksum from staged A (swizzled chunk slots)
  {
    int row = tid >> 1, hf = tid & 1;
    const float* ksh = ksum + ((size_t)(b * H_ + h)) * 64 + hf * 32;
    float bsum = 0.f;
#pragma unroll
    for (int cc = 0; cc < 4; ++cc) {
      int ch = hf * 4 + cc;
      f16x8 vv2 = *(const f16x8*)&smem[row * 64 + ((ch ^ (row & 7)) << 3)];
#pragma unroll
      for (int j = 0; j < 8; ++j) bsum += (float)vv2[j] * ksh[cc * 8 + j];
    }
    bsum += __shfl_xor(bsum, 1);
    if (hf == 0) bots[row] = bsum;
  }

  f32x4 acc[2][4] = {};
#pragma unroll
  for (int ks = 0; ks < 2; ++ks) {
    const int sw = ks ? sw1 : sw0;
    f16x8 af[2], bf[4];
#pragma unroll
    for (int i = 0; i < 2; ++i)
      af[i] = *(const f16x8*)&smem[(wv * 32 + i * 16 + l15) * 64 + sw];
#pragma unroll
    for (int j = 0; j < 4; ++j)
      bf[j] = *(const f16x8*)&smem[8192 + (j * 16 + l15) * 64 + sw];
#pragma unroll
    for (int i = 0; i < 2; ++i)
#pragma unroll
      for (int j = 0; j < 4; ++j)
        acc[i][j] = __builtin_amdgcn_mfma_f32_16x16x32_f16(af[i], bf[j], acc[i][j], 0, 0, 0);
  }
  __syncthreads();   // MFMA reads done; bots visible to all

#pragma unroll
  for (int j = 0; j < 4; ++j) {
    int lc = j * 16 + l15;
#pragma unroll
    for (int i = 0; i < 2; ++i) {
#pragma unroll
      for (int r = 0; r < 4; ++r) {
        int lr = wv * 32 + i * 16 + q * 4 + r;
        float v = acc[i][j][r] * frcp(bots[lr] + 1e-6f);
        smem[lr * 64 + ((((lc >> 3) ^ (lr & 7)) << 3) | (lc & 7))] = (f16)v;
      }
    }
  }
  __syncthreads();

#pragma unroll
  for (int p = 0; p < 4; ++p) {
    int idx = p * 256 + tid;
    int row = idx >> 3, ch = idx & 7;
    f16x8 vv = *(const f16x8*)&smem[row * 64 + ((ch ^ (row & 7)) << 3)];
    *(f16x8*)&Ch[(size_t)(bm + row) * C_ + h * DH_ + ch * 8] = vv;
  }
}

// ---------------------------------------------------------------- LayerNorm (f16 in/out)
__global__ __launch_bounds__(256) void ln16(const f16* __restrict__ X,
                                            const float* __restrict__ g,
                                            const float* __restrict__ bta,
                                            f16* __restrict__ Y, int threeway) {
  int wv = threadIdx.x >> 6, lane = threadIdx.x & 63;
  int r = blockIdx.x * 4 + wv;
  int token = r, which = 0;
  if (threeway) { token = r / 3; which = r - token * 3; }
  const f16* xr = X + (size_t)r * C_;
  f16x8 v = *(const f16x8*)(xr + lane * 8);
  float vals[8];
  float s = 0.f, s2 = 0.f;
#pragma unroll
  for (int j = 0; j < 8; ++j) { vals[j] = (float)v[j]; s += vals[j]; s2 += vals[j] * vals[j]; }
#pragma unroll
  for (int m_ = 1; m_ < 64; m_ <<= 1) { s += __shfl_xor(s, m_); s2 += __shfl_xor(s2, m_); }
  float mu = s * (1.f / C_);
  float var = s2 * (1.f / C_) - mu * mu;
  float rstd = rsqrtf(var + 1e-5f);
  const float* gp = g + which * C_;
  const float* bp = bta + which * C_;
  f16x8 o;
#pragma unroll
  for (int j = 0; j < 8; ++j) {
    int c = lane * 8 + j;
    o[j] = (f16)((vals[j] - mu) * rstd * gp[c] + bp[c]);
  }
  *(f16x8*)(Y + ((size_t)which * BL_ + token) * C_ + lane * 8) = o;
}

// ---------------------------------------------------------------- q_probe
__global__ __launch_bounds__(256) void qprobe2(const f16* __restrict__ Q,
                                               float* __restrict__ qp) {
  int blk = blockIdx.x;
  int b = blk >> 6;
  int r0 = blk * 64;
  int t = threadIdx.x;
  int c8 = (t & 63) * 8, rg = t >> 6;
  float s[8] = {0.f, 0.f, 0.f, 0.f, 0.f, 0.f, 0.f, 0.f};
#pragma unroll
  for (int i = 0; i < 16; ++i) {
    const f16* row = Q + ((size_t)r0 + rg + i * 4) * C_ + c8;
    f16x8 v = *(const f16x8*)row;
#pragma unroll
    for (int j = 0; j < 8; ++j) s[j] += (float)v[j];
  }
  __shared__ float red[4][520];
#pragma unroll
  for (int j = 0; j < 8; ++j) red[rg][c8 + j] = s[j];
  __syncthreads();
  int c = t * 2;
  float a0 = red[0][c] + red[1][c] + red[2][c] + red[3][c];
  float a1 = red[0][c + 1] + red[1][c + 1] + red[2][c + 1] + red[3][c + 1];
  atomicAdd(&qp[b * C_ + c], a0);
  atomicAdd(&qp[b * C_ + c + 1], a1);
}

// ---------------------------------------------------------------- score logits
__global__ __launch_bounds__(256) void logits_kernel(const f16* __restrict__ Kh,
                                                     const float* __restrict__ qp,
                                                     float* __restrict__ score) {
  int wv = threadIdx.x >> 6, lane = threadIdx.x & 63;
  int token = blockIdx.x * 4 + wv;
  int b = token >> 12;
  int l = token & (L_ - 1);
  const f16* row = Kh + (size_t)token * C_;
  int h = lane >> 3, j0 = (lane & 7) * 8;
  const float* qph = qp + b * C_ + h * DH_ + j0;
  float p = 0.f;
#pragma unroll
  for (int j = 0; j < 8; ++j) p += qph[j] * (float)row[h * DH_ + j0 + j];
  p += __shfl_xor(p, 1); p += __shfl_xor(p, 2); p += __shfl_xor(p, 4);
  if ((lane & 7) == 0)
    score[((size_t)b * H_ + h) * LK_ + 1 + l] = p * (1.f / L_) * 0.125f;
}

__global__ __launch_bounds__(256) void softmax_kernel(float* __restrict__ score) {
  int bh = blockIdx.x, t = threadIdx.x;
  float* s = score + (size_t)bh * LK_;
  __shared__ float red[256];
  float mx = 0.f;
  for (int i = t; i < L_; i += 256) mx = fmaxf(mx, s[1 + i]);
  red[t] = mx; __syncthreads();
  for (int k = 128; k; k >>= 1) { if (t < k) red[t] = fmaxf(red[t], red[t + k]); __syncthreads(); }
  mx = red[0]; __syncthreads();
  float sum = (t == 0) ? expf(-mx) : 0.f;
  for (int i = t; i < L_; i += 256) { float e = expf(s[1 + i] - mx); s[1 + i] = e; sum += e; }
  red[t] = sum; __syncthreads();
  for (int k = 128; k; k >>= 1) { if (t < k) red[t] += red[t + k]; __syncthreads(); }
  float inv = 1.f / red[0];
  __syncthreads();
  for (int i = t; i < L_; i += 256) s[1 + i] *= inv;
  if (t == 0) s[0] = expf(-mx) * inv;
}

// ---------------------------------------------------------------- kv / ksum
__global__ __launch_bounds__(256) void ksum_init(const float* __restrict__ score,
                                                 const float* __restrict__ bkk,
                                                 float* __restrict__ ksum) {
  int i = blockIdx.x * 256 + threadIdx.x;
  int bh = i >> 6, d = i & 63, h = bh & 7;
  float pk0 = tanhf(bkk[h * DH_ + d]) + 1.f;
  ksum[i] = score[(size_t)bh * LK_] * pk0;
}

#define PIDX(l, c) ((l) * 68 + (c))
#define AIDX(d, e) ((d) * 68 + (e) + ((((d) >> 3)) << 2))
__global__ __launch_bounds__(256, 2) void kv_part_kernel(const f16* __restrict__ phiK,
                                                         const f16* __restrict__ Vh,
                                                         const float* __restrict__ score,
                                                         float* __restrict__ kvp,
                                                         float* __restrict__ ksum) {
  __shared__ float sm0[4416];
  __shared__ float sm1[4416];
  int bh = blockIdx.y, b = bh >> 3, h = bh & 7;
  int part = blockIdx.x;
  int l0 = part * 256;
  int t = threadIdx.x, lane = t & 63, wv = t >> 6;
  int R = (lane >> 3) * 8, Cc = (lane & 7) * 8;
  float acc[8][8] = {};
  float ks[8] = {0.f, 0.f, 0.f, 0.f, 0.f, 0.f, 0.f, 0.f};

  for (int c = 0; c < 4; ++c) {
    int lc = l0 + c * 64;
    __syncthreads();
#pragma unroll
    for (int p = 0; p < 4; ++p) {
      int l = p * 16 + (t >> 4);
      int c4 = (t & 15) * 4;
      size_t grow = ((size_t)b * L_ + lc + l) * C_ + h * DH_ + c4;
      float w = score[(size_t)bh * LK_ + 1 + lc + l];
      f16x4 pk = *(const f16x4*)(phiK + grow);
      f16x4 vvv = *(const f16x4*)(Vh + grow);
      sm0[PIDX(l, c4) + 0] = w * (float)pk[0];
      sm0[PIDX(l, c4) + 1] = w * (float)pk[1];
      sm0[PIDX(l, c4) + 2] = w * (float)pk[2];
      sm0[PIDX(l, c4) + 3] = w * (float)pk[3];
      sm1[PIDX(l, c4) + 0] = (float)vvv[0];
      sm1[PIDX(l, c4) + 1] = (float)vvv[1];
      sm1[PIDX(l, c4) + 2] = (float)vvv[2];
      sm1[PIDX(l, c4) + 3] = (float)vvv[3];
    }
    __syncthreads();
#pragma unroll
    for (int i = 0; i < 16; ++i) {
      int ll = wv * 16 + i;
      float4 a0 = *(const float4*)&sm0[PIDX(ll, R)];
      float4 a1 = *(const float4*)&sm0[PIDX(ll, R + 4)];
      float4 b0 = *(const float4*)&sm1[PIDX(ll, Cc)];
      float4 b1 = *(const float4*)&sm1[PIDX(ll, Cc + 4)];
      float av[8] = {a0.x, a0.y, a0.z, a0.w, a1.x, a1.y, a1.z, a1.w};
      float bv2[8] = {b0.x, b0.y, b0.z, b0.w, b1.x, b1.y, b1.z, b1.w};
#pragma unroll
      for (int ii = 0; ii < 8; ++ii)
#pragma unroll
        for (int jj = 0; jj < 8; ++jj) acc[ii][jj] += av[ii] * bv2[jj];
      if ((lane & 7) == 0) {
#pragma unroll
        for (int ii = 0; ii < 8; ++ii) ks[ii] += av[ii];
      }
    }
  }

  __syncthreads();
  if ((lane & 7) == 0) {
#pragma unroll
    for (int i = 0; i < 8; ++i) sm1[wv * 64 + R + i] = ks[i];
  }
  for (int w = 0; w < 4; ++w) {
    if (wv == w) {
#pragma unroll
      for (int i = 0; i < 8; ++i) {
        float* p0 = &sm0[AIDX(R + i, Cc)];
        if (w == 0) {
          *(float4*)p0 = make_float4(acc[i][0], acc[i][1], acc[i][2], acc[i][3]);
          *(float4*)(p0 + 4) = make_float4(acc[i][4], acc[i][5], acc[i][6], acc[i][7]);
        } else {
          float4 o0 = *(const float4*)p0, o1 = *(const float4*)(p0 + 4);
          o0.x += acc[i][0]; o0.y += acc[i][1]; o0.z += acc[i][2]; o0.w += acc[i][3];
          o1.x += acc[i][4]; o1.y += acc[i][5]; o1.z += acc[i][6]; o1.w += acc[i][7];
          *(float4*)p0 = o0;
          *(float4*)(p0 + 4) = o1;
        }
      }
    }
    __syncthreads();
  }
  if (t < 64) {
    float s = sm1[t] + sm1[64 + t] + sm1[128 + t] + sm1[192 + t];
    atomicAdd(&ksum[bh * 64 + t], s);
  }
  float* dst = kvp + ((size_t)bh * 16 + part) * 4096;
#pragma unroll
  for (int i = 0; i < 16; ++i) {
    int idx = i * 256 + t;
    dst[idx] = sm0[AIDX(idx & 63, idx >> 6)];
  }
}

// compact per-head kvT[b][h][e][d] (f16), summing 16 partials.
__global__ __launch_bounds__(256) void build_kvt(const float* __restrict__ kvp,
                                                 f16* __restrict__ kvt) {
  int i = blockIdx.x * 256 + threadIdx.x;
  int bh = i >> 12;
  const float* p = kvp + ((size_t)bh * 16) * 4096 + (i & 4095);
  float v = 0.f;
#pragma unroll
  for (int pp = 0; pp < 16; ++pp) v += p[pp * 4096];
  kvt[i] = (f16)v;
}

// ---------------------------------------------------------------- launch
extern "C" void kernel_launch(void* const* d_in, const int* in_sizes, int n_in,
                              void* d_out, int out_size, void* d_ws, size_t ws_size,
                              hipStream_t stream) {
  (void)in_sizes; (void)n_in; (void)out_size; (void)ws_size;
  const float* x     = (const float*)d_in[0];
  const float* Wq    = (const float*)d_in[1];
  const float* bq    = (const float*)d_in[2];
  const float* gq    = (const float*)d_in[3];
  const float* betaq = (const float*)d_in[4];
  const float* Wk    = (const float*)d_in[5];
  const float* bk    = (const float*)d_in[6];
  const float* gk    = (const float*)d_in[7];
  const float* betak = (const float*)d_in[8];
  const float* Wv    = (const float*)d_in[9];
  const float* bv    = (const float*)d_in[10];
  const float* gv    = (const float*)d_in[11];
  const float* betav = (const float*)d_in[12];
  const float* Wkq   = (const float*)d_in[13];
  const float* bkq   = (const float*)d_in[14];
  const float* Wkk   = (const float*)d_in[15];
  const float* bkk   = (const float*)d_in[16];
  const float* g_at  = (const float*)d_in[17];
  const float* b_at  = (const float*)d_in[18];
  const float* W1    = (const float*)d_in[19];
  const float* b1    = (const float*)d_in[20];
  const float* W2    = (const float*)d_in[21];
  const float* b2    = (const float*)d_in[22];
  float* out = (float*)d_out;

  char* ws = (char*)d_ws;
  size_t off = 0;
  auto alloc = [&](size_t bytes) -> void* {
    void* p = ws + off;
    off += (bytes + 255) & ~(size_t)255;
    return p;
  };
  f16* U1    = (f16*)alloc((size_t)BL_ * MLP_ * 2);       // 64 MB
  f16* QKVh  = (f16*)alloc((size_t)3 * BL_ * C_ * 2);     // 48 MB
  f16* phiQK = (f16*)alloc((size_t)2 * BL_ * C_ * 2);     // 32 MB
  f16* xf    = (f16*)alloc((size_t)BL_ * C_ * 2);         // 16 MB
  f16* WqkvT = (f16*)alloc((size_t)3 * C_ * C_ * 2);
  f16* WkqT  = (f16*)alloc((size_t)C_ * C_ * 2);
  f16* WkkT  = (f16*)alloc((size_t)C_ * C_ * 2);
  f16* W1T   = (f16*)alloc((size_t)C_ * MLP_ * 2);
  f16* W2T   = (f16*)alloc((size_t)MLP_ * C_ * 2);
  f16* kvt   = (f16*)alloc((size_t)B_ * H_ * DH_ * DH_ * 2);
  float* score = (float*)alloc((size_t)B_ * H_ * LK_ * 4);
  float* qp    = (float*)alloc((size_t)B_ * C_ * 4);
  float* kvp   = (float*)alloc((size_t)B_ * H_ * 16 * 4096 * 4);
  float* ksum  = (float*)alloc((size_t)B_ * H_ * DH_ * 4);
  float* bqkv    = (float*)alloc(1536 * 4);
  float* gqkv    = (float*)alloc(1536 * 4);
  float* betaqkv = (float*)alloc(1536 * 4);
  float* bphi    = (float*)alloc(1024 * 4);

  f16* tmpqkv = U1;
  f16* tmpA   = U1;
  f16* h1     = U1;
  f16* Qh = QKVh;
  f16* Kh = QKVh + (size_t)BL_ * C_;
  f16* Vh = QKVh + (size_t)2 * BL_ * C_;
  f16* ah = QKVh;
  f16* phiQ = phiQK;
  f16* phiK = phiQK + (size_t)BL_ * C_;

  dim3 blk(256);
  dim3 blk512(512);

  pack_params<<<6, blk, 0, stream>>>(bq, bk, bv, gq, gk, gv, betaq, betak, betav,
                                     bkq, bkk, bqkv, gqkv, betaqkv, bphi);

  transpose_w5<<<dim3(16, 16, 5), blk, 0, stream>>>(Wq, Wk, Wv, Wkq, Wkk, WqkvT);
  transpose_w<<<dim3(MLP_ / 32, C_ / 32), blk, 0, stream>>>(W1, W1T, C_, MLP_);
  transpose_w<<<dim3(C_ / 32, MLP_ / 32), blk, 0, stream>>>(W2, W2T, MLP_, C_);

  transpose_x<<<dim3(L_ / 32, C_ / 32, B_), blk, 0, stream>>>(x, xf);

  // fused QKV projection (256^2 counted-vmcnt + setprio)
  gemm256<5><<<dim3(BL_ / 256, 1536 / 256), blk512, 0, stream>>>(
      xf, WqkvT, bqkv, tmpqkv, 1536, C_, 0, 0, 0, 0);
  ln16<<<3 * BL_ / 4, blk, 0, stream>>>(tmpqkv, gqkv, betaqkv, QKVh, 1);

  hipMemsetAsync(qp, 0, (size_t)B_ * C_ * 4, stream);
  qprobe2<<<BL_ / 64, blk, 0, stream>>>(Qh, qp);

  // phi projections (m97-sbuf 128^2; grid = (N-tiles, M-tiles, z))
  gemm128s<1><<<dim3(C_ / 128, BL_ / 128, 2), blk, 0, stream>>>(
      Qh, WkqT, bphi, phiQ, C_, C_,
      (long long)BL_ * C_, (long long)C_ * C_, (long long)BL_ * C_, (long long)C_);

  logits_kernel<<<BL_ / 4, blk, 0, stream>>>(Kh, qp, score);
  softmax_kernel<<<B_ * H_, blk, 0, stream>>>(score);

  ksum_init<<<(B_ * H_ * DH_) / 256, blk, 0, stream>>>(score, bkk, ksum);
  kv_part_kernel<<<dim3(16, B_ * H_), blk, 0, stream>>>(phiK, Vh, score, kvp, ksum);

  build_kvt<<<(B_ * H_ * DH_ * DH_) / 256, blk, 0, stream>>>(kvp, kvt);

  // attention out (bottom fused from staged A-tile)
  attn_out<<<dim3(BL_ / 128, H_), blk, 0, stream>>>(phiQ, kvt, ksum, tmpA);

  ln16<<<BL_ / 4, blk, 0, stream>>>(tmpA, g_at, b_at, ah, 0);

  // MLP up (m97-sbuf 128^2; grid = (N-tiles, M-tiles))
  gemm128s<2><<<dim3(MLP_ / 128, BL_ / 128), blk, 0, stream>>>(
      ah, W1T, b1, h1, MLP_, C_, 0, 0, 0, 0);
  // MLP down fused with residual-add + transpose + x-add -> out (512-thr dbuf)
  gemm512d6<<<dim3(BL_ / 128, C_ / 128), blk512, 0, stream>>>(
      h1, W2T, b2, C_, MLP_, ah, x, out);
}

// Round 9
// 374.144 us; speedup vs baseline: 1.1068x; 1.0426x over previous
//
#include <hip/hip_runtime.h>
#include <math.h>

#define B_ 4
#define C_ 512
#define L_ 4096
#define H_ 8
#define DH_ 64
#define MLP_ 2048
#define BL_ (B_*L_)      // 16384
#define LK_ (L_+1)       // 4097

typedef _Float16 f16;
typedef _Float16 f16x8 __attribute__((ext_vector_type(8)));
typedef _Float16 f16x4 __attribute__((ext_vector_type(4)));
typedef float f32x4 __attribute__((ext_vector_type(4)));

// async global->LDS, 16B per lane (m97 pattern)
__device__ __forceinline__ void gl16(void* lds, const void* g) {
  __builtin_amdgcn_global_load_lds((const __attribute__((address_space(1))) void*)g,
                                   (__attribute__((address_space(3))) void*)lds,
                                   16, 0, 0);
}

__device__ __forceinline__ float frcp(float x) { return __builtin_amdgcn_rcpf(x); }

// ---------------------------------------------------------------- transposes
__global__ __launch_bounds__(256) void transpose_w5(const float* __restrict__ Wq,
                                                    const float* __restrict__ Wk,
                                                    const float* __restrict__ Wv,
                                                    const float* __restrict__ Wkq,
                                                    const float* __restrict__ Wkk,
                                                    f16* __restrict__ dst) {
  int z = blockIdx.z;
  const float* W = (z == 0) ? Wq : (z == 1) ? Wk : (z == 2) ? Wv : (z == 3) ? Wkq : Wkk;
  f16* Wt = dst + (size_t)z * C_ * C_;
  __shared__ float tile[32][33];
  int n0 = blockIdx.x * 32, k0 = blockIdx.y * 32;
  int tx = threadIdx.x & 31, ty = threadIdx.x >> 5;
#pragma unroll
  for (int i = 0; i < 4; ++i)
    tile[ty + i * 8][tx] = W[(size_t)(k0 + ty + i * 8) * C_ + n0 + tx];
  __syncthreads();
#pragma unroll
  for (int i = 0; i < 4; ++i)
    Wt[(size_t)(n0 + ty + i * 8) * C_ + k0 + tx] = (f16)tile[tx][ty + i * 8];
}

// W1 (512x2048) and W2 (2048x512) transposes in one z=2 launch.
// z=0: W1, n0 = bx*32 (64 tiles), k0 = by*32 (16); z=1: W2, roles swapped.
__global__ __launch_bounds__(256) void transpose_w12(const float* __restrict__ W1,
                                                     const float* __restrict__ W2,
                                                     f16* __restrict__ W1T,
                                                     f16* __restrict__ W2T) {
  __shared__ float tile[32][33];
  int z = blockIdx.z;
  const float* W = z ? W2 : W1;
  f16* Wt = z ? W2T : W1T;
  int K = z ? MLP_ : C_;
  int N = z ? C_ : MLP_;
  int n0 = (z ? blockIdx.y : blockIdx.x) * 32;
  int k0 = (z ? blockIdx.x : blockIdx.y) * 32;
  int tx = threadIdx.x & 31, ty = threadIdx.x >> 5;
#pragma unroll
  for (int i = 0; i < 4; ++i)
    tile[ty + i * 8][tx] = W[(size_t)(k0 + ty + i * 8) * N + n0 + tx];
  __syncthreads();
#pragma unroll
  for (int i = 0; i < 4; ++i)
    Wt[(size_t)(n0 + ty + i * 8) * K + k0 + tx] = (f16)tile[tx][ty + i * 8];
}

__global__ __launch_bounds__(256) void transpose_x(const float* __restrict__ x,
                                                   f16* __restrict__ xf) {
  __shared__ float tile[32][33];
  int b = blockIdx.z;
  int l0 = blockIdx.x * 32, c0 = blockIdx.y * 32;
  int tx = threadIdx.x & 31, ty = threadIdx.x >> 5;
#pragma unroll
  for (int i = 0; i < 4; ++i)
    tile[ty + i * 8][tx] = x[((size_t)b * C_ + c0 + ty + i * 8) * L_ + l0 + tx];
  __syncthreads();
#pragma unroll
  for (int i = 0; i < 4; ++i)
    xf[((size_t)b * L_ + l0 + ty + i * 8) * C_ + c0 + tx] = (f16)tile[tx][ty + i * 8];
}

// ------------------------------------------------- pack small param vectors
__global__ __launch_bounds__(256) void pack_params(
    const float* bq, const float* bk, const float* bv,
    const float* gq, const float* gk, const float* gv,
    const float* betaq, const float* betak, const float* betav,
    const float* bkq, const float* bkk,
    float* bqkv, float* gqkv, float* betaqkv, float* bphi, float* pk0t) {
  int i = blockIdx.x * 256 + threadIdx.x;  // 0..1535
  int w = i >> 9, c = i & 511;
  bqkv[i]    = (w == 0 ? bq : (w == 1 ? bk : bv))[c];
  gqkv[i]    = (w == 0 ? gq : (w == 1 ? gk : gv))[c];
  betaqkv[i] = (w == 0 ? betaq : (w == 1 ? betak : betav))[c];
  if (i < 1024) bphi[i] = (i < 512) ? bkq[i] : bkk[i - 512];
  if (i < 512) pk0t[i] = tanhf(bkk[i]) + 1.f;   // zero-token phiK
}

// ---------------------------------------------------------------- GEMM 128x128 single-buffer (m97 structure)
// BK=64, SINGLE-buffered 32 KB LDS, 2 barriers/k-step, 4 blocks/CU —
// round-7 A/B winner for high-grid GEMMs.
// Grid roles: blockIdx.x = N-tile, blockIdx.y = M-tile (A-panel L2 locality).
// EPI: 1 tanh(v)+1   2 gelu (tanh approx)   5 plain bias
template <int EPI>
__global__ __launch_bounds__(256, 4) void gemm128s(const f16* __restrict__ A,
                                                   const f16* __restrict__ Bt,
                                                   const float* __restrict__ bias,
                                                   f16* __restrict__ Ch,
                                                   int N, int K,
                                                   long long zA, long long zB,
                                                   long long zC, long long zBias) {
  __shared__ f16 smem[16384];  // 32 KB: As(16K)|Bs(16K); epilogue: [128][128]
  A  += (size_t)blockIdx.z * zA;
  Bt += (size_t)blockIdx.z * zB;
  Ch += (size_t)blockIdx.z * zC;
  bias += (size_t)blockIdx.z * zBias;

  const int tid = threadIdx.x;
  const int lane = tid & 63, wv = tid >> 6;
  const int wm = wv >> 1, wn = wv & 1;
  const int bm = blockIdx.y * 128, bn = blockIdx.x * 128;   // swapped roles
  const int l15 = lane & 15, q = lane >> 4;

  const int srow = tid >> 3;
  const int schunk = (tid & 7) ^ (srow & 7);
  const f16* pa = A + (size_t)(bm + srow) * K + schunk * 8;
  const f16* pb = Bt + (size_t)(bn + srow) * K + schunk * 8;
  f16* la = smem + tid * 8;
  f16* lb = smem + 8192 + tid * 8;
  const int sw0 = (q ^ (lane & 7)) * 8;
  const int sw1 = ((4 + q) ^ (lane & 7)) * 8;

  f32x4 acc[4][4] = {};

  for (int k0 = 0; k0 < K; k0 += 64) {
    __syncthreads();               // prev k-step's reads of smem done
#pragma unroll
    for (int p = 0; p < 4; ++p) gl16(la + p * 2048, pa + (size_t)p * 32 * K + k0);
#pragma unroll
    for (int p = 0; p < 4; ++p) gl16(lb + p * 2048, pb + (size_t)p * 32 * K + k0);
    __syncthreads();               // compiler emits vmcnt(0) drain -> staged
#pragma unroll
    for (int ks = 0; ks < 2; ++ks) {
      const int sw = ks ? sw1 : sw0;
      f16x8 af[4], bf[4];
#pragma unroll
      for (int i = 0; i < 4; ++i)
        af[i] = *(const f16x8*)&smem[(wm * 64 + i * 16 + l15) * 64 + sw];
#pragma unroll
      for (int j = 0; j < 4; ++j)
        bf[j] = *(const f16x8*)&smem[8192 + (wn * 64 + j * 16 + l15) * 64 + sw];
#pragma unroll
      for (int i = 0; i < 4; ++i)
#pragma unroll
        for (int j = 0; j < 4; ++j)
          acc[i][j] = __builtin_amdgcn_mfma_f32_16x16x32_f16(af[i], bf[j], acc[i][j], 0, 0, 0);
    }
  }

  // epilogue: act -> smem [128][128] (col-chunk XOR swizzle)
  __syncthreads();
#pragma unroll
  for (int j = 0; j < 4; ++j) {
    int lc = wn * 64 + j * 16 + l15;
    float bb = bias[bn + lc];
#pragma unroll
    for (int i = 0; i < 4; ++i) {
#pragma unroll
      for (int r = 0; r < 4; ++r) {
        int lr = wm * 64 + i * 16 + q * 4 + r;
        float v = acc[i][j][r] + bb;
        if (EPI == 1) {
          v = 2.0f * frcp(1.0f + __expf(-2.0f * v));      // tanh(v)+1
        } else if (EPI == 2) {
          v = v * frcp(1.0f + __expf(-1.5957691f * (v + 0.044715f * v * v * v)));
        }
        smem[lr * 128 + ((((lc >> 3) ^ (lr & 15)) << 3) | (lc & 7))] = (f16)v;
      }
    }
  }
  __syncthreads();
#pragma unroll
  for (int p = 0; p < 8; ++p) {
    int idx = p * 256 + tid;
    int row = idx >> 4, ch = idx & 15;
    f16x8 vv = *(const f16x8*)&smem[row * 128 + ((ch ^ (row & 15)) << 3)];
    *(f16x8*)&Ch[(size_t)(bm + row) * N + bn + ch * 8] = vv;
  }
}

// ---------------------------------------------------------------- GEMM 256x256 (counted-vmcnt + setprio)
template <int EPI>
__global__ __launch_bounds__(512, 2) void gemm256(const f16* __restrict__ A,
                                                  const f16* __restrict__ Bt,
                                                  const float* __restrict__ bias,
                                                  f16* __restrict__ Ch,
                                                  int N, int K,
                                                  long long zA, long long zB,
                                                  long long zC, long long zBias) {
  __shared__ f16 smem[65536];  // 128 KB
  A  += (size_t)blockIdx.z * zA;
  Bt += (size_t)blockIdx.z * zB;
  Ch += (size_t)blockIdx.z * zC;
  bias += (size_t)blockIdx.z * zBias;

  const int tid = threadIdx.x;
  const int lane = tid & 63, wv = tid >> 6;
  const int wm = wv >> 2, wn = wv & 3;
  const int bm = blockIdx.x * 256, bn = blockIdx.y * 256;
  const int l15 = lane & 15, q = lane >> 4;

  const int srow = tid >> 3;
  const int schunk = (tid & 7) ^ (srow & 7);
  const f16* pa = A + (size_t)(bm + srow) * K + schunk * 8;
  const f16* pb = Bt + (size_t)(bn + srow) * K + schunk * 8;
  const int sw0 = (q ^ (lane & 7)) * 8;
  const int sw1 = ((4 + q) ^ (lane & 7)) * 8;
  const int NT = K >> 6;

  auto STAGE = [&](int t) {
    f16* bs = smem + (t & 1) * 32768;
    const f16* pat = pa + t * 64;
    const f16* pbt = pb + t * 64;
#pragma unroll
    for (int p = 0; p < 4; ++p) gl16(bs + p * 4096 + tid * 8, pat + (size_t)p * 64 * K);
#pragma unroll
    for (int p = 0; p < 4; ++p) gl16(bs + 16384 + p * 4096 + tid * 8, pbt + (size_t)p * 64 * K);
  };

  f32x4 acc[8][4] = {};

  STAGE(0);
  STAGE(1);

  for (int t = 0; t < NT; ++t) {
    if (t < NT - 1) asm volatile("s_waitcnt vmcnt(8)" ::: "memory");
    else            asm volatile("s_waitcnt vmcnt(0)" ::: "memory");
    __builtin_amdgcn_s_barrier();
    asm volatile("" ::: "memory");

    const f16* As = smem + (t & 1) * 32768;
    const f16* Bs = As + 16384;

    f16x8 bfr[4][2], afr[4][2];
#pragma unroll
    for (int n = 0; n < 4; ++n) {
      bfr[n][0] = *(const f16x8*)&Bs[(wn * 64 + n * 16 + l15) * 64 + sw0];
      bfr[n][1] = *(const f16x8*)&Bs[(wn * 64 + n * 16 + l15) * 64 + sw1];
    }
#pragma unroll
    for (int m = 0; m < 4; ++m) {
      afr[m][0] = *(const f16x8*)&As[(wm * 128 + m * 16 + l15) * 64 + sw0];
      afr[m][1] = *(const f16x8*)&As[(wm * 128 + m * 16 + l15) * 64 + sw1];
    }
    __builtin_amdgcn_s_setprio(1);
#pragma unroll
    for (int ks = 0; ks < 2; ++ks)
#pragma unroll
      for (int m = 0; m < 4; ++m)
#pragma unroll
        for (int n = 0; n < 4; ++n)
          acc[m][n] = __builtin_amdgcn_mfma_f32_16x16x32_f16(afr[m][ks], bfr[n][ks], acc[m][n], 0, 0, 0);
    __builtin_amdgcn_s_setprio(0);
#pragma unroll
    for (int m = 0; m < 4; ++m) {
      afr[m][0] = *(const f16x8*)&As[(wm * 128 + (m + 4) * 16 + l15) * 64 + sw0];
      afr[m][1] = *(const f16x8*)&As[(wm * 128 + (m + 4) * 16 + l15) * 64 + sw1];
    }
    asm volatile("s_waitcnt lgkmcnt(0)" ::: "memory");
    __builtin_amdgcn_s_barrier();
    asm volatile("" ::: "memory");
    if (t + 2 < NT) STAGE(t + 2);
    __builtin_amdgcn_s_setprio(1);
#pragma unroll
    for (int ks = 0; ks < 2; ++ks)
#pragma unroll
      for (int m = 0; m < 4; ++m)
#pragma unroll
        for (int n = 0; n < 4; ++n)
          acc[m + 4][n] = __builtin_amdgcn_mfma_f32_16x16x32_f16(afr[m][ks], bfr[n][ks], acc[m + 4][n], 0, 0, 0);
    __builtin_amdgcn_s_setprio(0);
  }

  __syncthreads();
#pragma unroll
  for (int n = 0; n < 4; ++n) {
    int lc = wn * 64 + n * 16 + l15;
    float bb = bias[bn + lc];
#pragma unroll
    for (int m = 0; m < 8; ++m) {
#pragma unroll
      for (int r = 0; r < 4; ++r) {
        int lr = wm * 128 + m * 16 + q * 4 + r;
        float v = acc[m][n][r] + bb;
        if (EPI == 1) {
          v = 2.0f * frcp(1.0f + __expf(-2.0f * v));
        } else if (EPI == 2) {
          v = v * frcp(1.0f + __expf(-1.5957691f * (v + 0.044715f * v * v * v)));
        }
        smem[lr * 256 + ((((lc >> 3) ^ (lr & 31)) << 3) | (lc & 7))] = (f16)v;
      }
    }
  }
  __syncthreads();
#pragma unroll
  for (int p = 0; p < 16; ++p) {
    int idx = p * 512 + tid;
    int row = idx >> 5, ch = idx & 31;
    f16x8 vv = *(const f16x8*)&smem[row * 256 + ((ch ^ (row & 31)) << 3)];
    *(f16x8*)&Ch[(size_t)(bm + row) * N + bn + ch * 8] = vv;
  }
}

// ---------------------------------------------------------------- GEMM 128x128 dbuf, 512 threads (MLP-down)
// EPI 6 fused epilogue: bias + a-residual + transposed f32 out (+x).
__global__ __launch_bounds__(512, 2) void gemm512d6(const f16* __restrict__ A,
                                                    const f16* __restrict__ Bt,
                                                    const float* __restrict__ bias,
                                                    int N, int K,
                                                    const f16* __restrict__ Ares,
                                                    const float* __restrict__ Xres,
                                                    float* __restrict__ Fout) {
  __shared__ f16 smem[2 * 128 * 128];  // 64 KB
  const int tid = threadIdx.x;
  const int lane = tid & 63, wv = tid >> 6;      // 8 waves
  const int wm = wv >> 2, wn = wv & 3;           // 2 x 4
  const int bm = blockIdx.x * 128, bn = blockIdx.y * 128;
  const int l15 = lane & 15, q = lane >> 4;

  const int srow = tid >> 3;                     // 0..63
  const int schunk = (tid & 7) ^ (srow & 7);
  const f16* pa = A + (size_t)(bm + srow) * K + schunk * 8;
  const f16* pb = Bt + (size_t)(bn + srow) * K + schunk * 8;
  f16* la = smem + tid * 8;                      // inst p covers rows p*64+srow
  f16* lb = smem + 8192 + tid * 8;
  const int sw0 = (q ^ (lane & 7)) * 8;
  const int sw1 = ((4 + q) ^ (lane & 7)) * 8;

  f32x4 acc[4][2] = {};

#pragma unroll
  for (int p = 0; p < 2; ++p) gl16(la + p * 4096, pa + (size_t)p * 64 * K);
#pragma unroll
  for (int p = 0; p < 2; ++p) gl16(lb + p * 4096, pb + (size_t)p * 64 * K);

  int cur = 0;
  for (int k0 = 0; k0 < K; k0 += 64) {
    __syncthreads();                 // vmcnt(0) drain: buf(cur) staged; buf(nxt) readers done
    const int nxt = cur ^ 1;
    if (k0 + 64 < K) {
#pragma unroll
      for (int p = 0; p < 2; ++p) gl16(la + nxt * 16384 + p * 4096, pa + (size_t)p * 64 * K + k0 + 64);
#pragma unroll
      for (int p = 0; p < 2; ++p) gl16(lb + nxt * 16384 + p * 4096, pb + (size_t)p * 64 * K + k0 + 64);
    }
    const f16* As = smem + cur * 16384;
    const f16* Bs = As + 8192;
#pragma unroll
    for (int ks = 0; ks < 2; ++ks) {
      const int sw = ks ? sw1 : sw0;
      f16x8 af[4], bf[2];
#pragma unroll
      for (int i = 0; i < 4; ++i)
        af[i] = *(const f16x8*)&As[(wm * 64 + i * 16 + l15) * 64 + sw];
#pragma unroll
      for (int j = 0; j < 2; ++j)
        bf[j] = *(const f16x8*)&Bs[(wn * 32 + j * 16 + l15) * 64 + sw];
#pragma unroll
      for (int i = 0; i < 4; ++i)
#pragma unroll
        for (int j = 0; j < 2; ++j)
          acc[i][j] = __builtin_amdgcn_mfma_f32_16x16x32_f16(af[i], bf[j], acc[i][j], 0, 0, 0);
    }
    cur = nxt;
  }

  // epilogue: bias -> smem [128][128] (col-chunk XOR swizzle)
  __syncthreads();
#pragma unroll
  for (int j = 0; j < 2; ++j) {
    int lc = wn * 32 + j * 16 + l15;
    float bb = bias[bn + lc];
#pragma unroll
    for (int i = 0; i < 4; ++i) {
#pragma unroll
      for (int r = 0; r < 4; ++r) {
        int lr = wm * 64 + i * 16 + q * 4 + r;
        float v = acc[i][j][r] + bb;
        smem[lr * 128 + ((((lc >> 3) ^ (lr & 15)) << 3) | (lc & 7))] = (f16)v;
      }
    }
  }
  __syncthreads();
  // a-residual (row-coalesced RMW in LDS)
#pragma unroll
  for (int p = 0; p < 4; ++p) {
    int idx = p * 512 + tid;
    int row = idx >> 4, ch = idx & 15;
    f16x8 av = *(const f16x8*)&Ares[(size_t)(bm + row) * C_ + bn + ch * 8];
    f16* sp = &smem[row * 128 + ((ch ^ (row & 15)) << 3)];
    f16x8 sv = *(const f16x8*)sp;
#pragma unroll
    for (int jj = 0; jj < 8; ++jj) sv[jj] = (f16)((float)sv[jj] + (float)av[jj]);
    *(f16x8*)sp = sv;
  }
  __syncthreads();
  // transposed f32 write: out[b][c][l] = tile[l][c] + x[b][c][l]
  int c = tid & 127, lh = tid >> 7;              // lh 0..3
  int b = bm >> 12, lbase = (bm & 4095) + lh * 32;
  const float* xp = Xres + ((size_t)b * C_ + bn + c) * L_ + lbase;
  float* op = Fout + ((size_t)b * C_ + bn + c) * L_ + lbase;
  int chi = c >> 3, clo = c & 7;
#pragma unroll
  for (int s = 0; s < 8; ++s) {
    int l = lh * 32 + s * 4;
    float4 xv = *(const float4*)(xp + s * 4);
    float4 r;
    r.x = (float)smem[(l + 0) * 128 + (((chi ^ ((l + 0) & 15)) << 3) | clo)] + xv.x;
    r.y = (float)smem[(l + 1) * 128 + (((chi ^ ((l + 1) & 15)) << 3) | clo)] + xv.y;
    r.z = (float)smem[(l + 2) * 128 + (((chi ^ ((l + 2) & 15)) << 3) | clo)] + xv.z;
    r.w = (float)smem[(l + 3) * 128 + (((chi ^ ((l + 3) & 15)) << 3) | clo)] + xv.w;
    *(float4*)(op + s * 4) = r;
  }
}

// ---------------------------------------------------------------- kv via MFMA
// kv[b][h][d][e] = sum_l w[l]*phiK[l][hd]*V[l][he]  (K = l reduction GEMM).
// Grid (16 parts, 32 bh), 256 thr, 4 waves (2 d-half x 2 e-half).
// Per 64-l chunk: stage TRANSPOSED f16 tiles Pt[d][l], Vt[e][l] (row stride
// 64, chunk-XOR slot layout identical to the verified gemm: element (r,l)
// at slot (l>>3)^(r&7)); fragment reads are byte-identical to gemm128s'
// proven pattern (0-conflict). Stores: thread owns 4 l-contig f16 per row
// -> ds_write_b64 (~4-way, acceptable). 8 MFMA/chunk/wave replaces the old
// kernel's 1024 VALU-FMA/chunk/thread. ksum[d] accumulated during staging.
__global__ __launch_bounds__(256, 2) void kv_mfma(const f16* __restrict__ phiK,
                                                  const f16* __restrict__ Vh,
                                                  const float* __restrict__ score,
                                                  float* __restrict__ kvp,
                                                  float* __restrict__ ksum) {
  __shared__ f16 Pt[4096];      // [d 64][l 64], swizzled slots
  __shared__ f16 Vt[4096];      // [e 64][l 64]
  __shared__ float red[16][64]; // ksum partial reduce
  const int bh = blockIdx.y, b = bh >> 3, h = bh & 7;
  const int l0 = blockIdx.x * 256;
  const int t = threadIdx.x, lane = t & 63, wv = t >> 6;
  const int wd = wv >> 1, we = wv & 1;
  const int l15 = lane & 15, q = lane >> 4;
  const int sw0 = (q ^ (lane & 7)) * 8;
  const int sw1 = ((4 + q) ^ (lane & 7)) * 8;
  const int lb = (t >> 4) * 4;          // l base within chunk (0..60)
  const int c4 = (t & 15) * 4;          // d/e base

  float ksacc[4] = {0.f, 0.f, 0.f, 0.f};
  f32x4 acc[2][2] = {};

  for (int cc = 0; cc < 4; ++cc) {
    __syncthreads();                    // prior MFMA reads done
    // load 4 l-rows x 4 cols, weights
    f16x4 pk4[4], vv4[4];
    float w4[4];
#pragma unroll
    for (int lp = 0; lp < 4; ++lp) {
      int lg = l0 + cc * 64 + lb + lp;
      size_t grow = ((size_t)b * L_ + lg) * C_ + h * DH_ + c4;
      pk4[lp] = *(const f16x4*)(phiK + grow);
      vv4[lp] = *(const f16x4*)(Vh + grow);
      w4[lp] = score[(size_t)bh * LK_ + 1 + lg];
    }
    // transpose in regs, write b64 per row
#pragma unroll
    for (int j = 0; j < 4; ++j) {
      int d = c4 + j;
      f16x4 pw, vw;
#pragma unroll
      for (int lp = 0; lp < 4; ++lp) {
        float wp = w4[lp] * (float)pk4[lp][j];
        ksacc[j] += wp;
        pw[lp] = (f16)wp;
        vw[lp] = vv4[lp][j];
      }
      int addr = d * 64 + ((((lb >> 3) ^ (d & 7)) << 3) | (lb & 7));
      *(f16x4*)&Pt[addr] = pw;
      *(f16x4*)&Vt[addr] = vw;
    }
    __syncthreads();
#pragma unroll
    for (int ks = 0; ks < 2; ++ks) {
      const int sw = ks ? sw1 : sw0;
      f16x8 af[2], bf[2];
#pragma unroll
      for (int i = 0; i < 2; ++i)
        af[i] = *(const f16x8*)&Pt[(wd * 32 + i * 16 + l15) * 64 + sw];
#pragma unroll
      for (int j = 0; j < 2; ++j)
        bf[j] = *(const f16x8*)&Vt[(we * 32 + j * 16 + l15) * 64 + sw];
#pragma unroll
      for (int i = 0; i < 2; ++i)
#pragma unroll
        for (int j = 0; j < 2; ++j)
          acc[i][j] = __builtin_amdgcn_mfma_f32_16x16x32_f16(af[i], bf[j], acc[i][j], 0, 0, 0);
    }
  }

  // ksum partial reduce + atomic (red region is disjoint from tiles)
  __syncthreads();
#pragma unroll
  for (int j = 0; j < 4; ++j) red[t >> 4][c4 + j] = ksacc[j];
  __syncthreads();
  if (t < 64) {
    float s = 0.f;
#pragma unroll
    for (int g = 0; g < 16; ++g) s += red[g][t];
    atomicAdd(&ksum[bh * 64 + t], s);
  }

  // write kv partial, layout [e*64+d] (matches build_kvt)
  float* dst = kvp + ((size_t)bh * 16 + blockIdx.x) * 4096;
#pragma unroll
  for (int i = 0; i < 2; ++i)
#pragma unroll
    for (int j = 0; j < 2; ++j) {
      int d = wd * 32 + i * 16 + q * 4;
      int e = we * 32 + j * 16 + l15;
      *(f32x4*)&dst[e * 64 + d] = acc[i][j];
    }
}

// compact per-head kvT[b][h][e][d] (f16), summing 16 partials.
__global__ __launch_bounds__(256) void build_kvt(const float* __restrict__ kvp,
                                                 f16* __restrict__ kvt) {
  int i = blockIdx.x * 256 + threadIdx.x;
  int bh = i >> 12;
  const float* p = kvp + ((size_t)bh * 16) * 4096 + (i & 4095);
  float v = 0.f;
#pragma unroll
  for (int pp = 0; pp < 16; ++pp) v += p[pp * 4096];
  kvt[i] = (f16)v;
}

// ---------------------------------------------------------------- attention out (+ fused bottom, + zero-token ksum term)
// O[l, h*64+e] = (sum_d phiQ[l,hd]*kvT[b][h][e][d]) / (phiQ[l,h].ksum_eff + 1e-6)
// ksum_eff[d] = ksum[d] + score[bh][0]*pk0t[hd]   (zero-token term fused here,
// replacing the old ksum_init kernel).
__global__ __launch_bounds__(256, 4) void attn_out(const f16* __restrict__ phiQ,
                                                   const f16* __restrict__ kvt,
                                                   const float* __restrict__ ksum,
                                                   const float* __restrict__ score,
                                                   const float* __restrict__ pk0t,
                                                   f16* __restrict__ Ch) {
  __shared__ f16 smem[12288];
  __shared__ float bots[128];
  const int tid = threadIdx.x;
  const int lane = tid & 63, wv = tid >> 6;
  const int bm = blockIdx.x * 128;
  const int h = blockIdx.y;
  const int b = bm >> 12;
  const int l15 = lane & 15, q = lane >> 4;

  const int srow = tid >> 3;
  const int schunk = (tid & 7) ^ (srow & 7);
  const f16* pa = phiQ + (size_t)(bm + srow) * C_ + h * DH_ + schunk * 8;
  const f16* pb = kvt + ((size_t)(b * H_ + h) * DH_ + srow) * DH_ + schunk * 8;
  f16* la = smem + tid * 8;
  f16* lb = smem + 8192 + tid * 8;
  const int sw0 = (q ^ (lane & 7)) * 8;
  const int sw1 = ((4 + q) ^ (lane & 7)) * 8;

#pragma unroll
  for (int p = 0; p < 4; ++p) gl16(la + p * 2048, pa + (size_t)p * 32 * C_);
#pragma unroll
  for (int p = 0; p < 2; ++p) gl16(lb + p * 2048, pb + (size_t)p * 32 * DH_);
  __syncthreads();

  // bottom: row dot ksum_eff from staged A (swizzled chunk slots)
  {
    int row = tid >> 1, hf = tid & 1;
    float s0 = score[(size_t)(b * H_ + h) * LK_];
    const float* ksh = ksum + ((size_t)(b * H_ + h)) * 64 + hf * 32;
    const float* pkh = pk0t + h * DH_ + hf * 32;
    float bsum = 0.f;
#pragma unroll
    for (int cc = 0; cc < 4; ++cc) {
      int ch = hf * 4 + cc;
      f16x8 vv2 = *(const f16x8*)&smem[row * 64 + ((ch ^ (row & 7)) << 3)];
#pragma unroll
      for (int j = 0; j < 8; ++j)
        bsum += (float)vv2[j] * (ksh[cc * 8 + j] + s0 * pkh[cc * 8 + j]);
    }
    bsum += __shfl_xor(bsum, 1);
    if (hf == 0) bots[row] = bsum;
  }

  f32x4 acc[2][4] = {};
#pragma unroll
  for (int ks = 0; ks < 2; ++ks) {
    const int sw = ks ? sw1 : sw0;
    f16x8 af[2], bf[4];
#pragma unroll
    for (int i = 0; i < 2; ++i)
      af[i] = *(const f16x8*)&smem[(wv * 32 + i * 16 + l15) * 64 + sw];
#pragma unroll
    for (int j = 0; j < 4; ++j)
      bf[j] = *(const f16x8*)&smem[8192 + (j * 16 + l15) * 64 + sw];
#pragma unroll
    for (int i = 0; i < 2; ++i)
#pragma unroll
      for (int j = 0; j < 4; ++j)
        acc[i][j] = __builtin_amdgcn_mfma_f32_16x16x32_f16(af[i], bf[j], acc[i][j], 0, 0, 0);
  }
  __syncthreads();   // MFMA reads done; bots visible to all

#pragma unroll
  for (int j = 0; j < 4; ++j) {
    int lc = j * 16 + l15;
#pragma unroll
    for (int i = 0; i < 2; ++i) {
#pragma unroll
      for (int r = 0; r < 4; ++r) {
        int lr = wv * 32 + i * 16 + q * 4 + r;
        float v = acc[i][j][r] * frcp(bots[lr] + 1e-6f);
        smem[lr * 64 + ((((lc >> 3) ^ (lr & 7)) << 3) | (lc & 7))] = (f16)v;
      }
    }
  }
  __syncthreads();

#pragma unroll
  for (int p = 0; p < 4; ++p) {
    int idx = p * 256 + tid;
    int row = idx >> 3, ch = idx & 7;
    f16x8 vv = *(const f16x8*)&smem[row * 64 + ((ch ^ (row & 7)) << 3)];
    *(f16x8*)&Ch[(size_t)(bm + row) * C_ + h * DH_ + ch * 8] = vv;
  }
}

// ---------------------------------------------------------------- LayerNorm (f16 in/out)
__global__ __launch_bounds__(256) void ln16(const f16* __restrict__ X,
                                            const float* __restrict__ g,
                                            const float* __restrict__ bta,
                                            f16* __restrict__ Y, int threeway) {
  int wv = threadIdx.x >> 6, lane = threadIdx.x & 63;
  int r = blockIdx.x * 4 + wv;
  int token = r, which = 0;
  if (threeway) { token = r / 3; which = r - token * 3; }
  const f16* xr = X + (size_t)r * C_;
  f16x8 v = *(const f16x8*)(xr + lane * 8);
  float vals[8];
  float s = 0.f, s2 = 0.f;
#pragma unroll
  for (int j = 0; j < 8; ++j) { vals[j] = (float)v[j]; s += vals[j]; s2 += vals[j] * vals[j]; }
#pragma unroll
  for (int m_ = 1; m_ < 64; m_ <<= 1) { s += __shfl_xor(s, m_); s2 += __shfl_xor(s2, m_); }
  float mu = s * (1.f / C_);
  float var = s2 * (1.f / C_) - mu * mu;
  float rstd = rsqrtf(var + 1e-5f);
  const float* gp = g + which * C_;
  const float* bp = bta + which * C_;
  f16x8 o;
#pragma unroll
  for (int j = 0; j < 8; ++j) {
    int c = lane * 8 + j;
    o[j] = (f16)((vals[j] - mu) * rstd * gp[c] + bp[c]);
  }
  *(f16x8*)(Y + ((size_t)which * BL_ + token) * C_ + lane * 8) = o;
}

// ---------------------------------------------------------------- q_probe
__global__ __launch_bounds__(256) void qprobe2(const f16* __restrict__ Q,
                                               float* __restrict__ qp) {
  int blk = blockIdx.x;
  int b = blk >> 6;
  int r0 = blk * 64;
  int t = threadIdx.x;
  int c8 = (t & 63) * 8, rg = t >> 6;
  float s[8] = {0.f, 0.f, 0.f, 0.f, 0.f, 0.f, 0.f, 0.f};
#pragma unroll
  for (int i = 0; i < 16; ++i) {
    const f16* row = Q + ((size_t)r0 + rg + i * 4) * C_ + c8;
    f16x8 v = *(const f16x8*)row;
#pragma unroll
    for (int j = 0; j < 8; ++j) s[j] += (float)v[j];
  }
  __shared__ float red[4][520];
#pragma unroll
  for (int j = 0; j < 8; ++j) red[rg][c8 + j] = s[j];
  __syncthreads();
  int c = t * 2;
  float a0 = red[0][c] + red[1][c] + red[2][c] + red[3][c];
  float a1 = red[0][c + 1] + red[1][c + 1] + red[2][c + 1] + red[3][c + 1];
  atomicAdd(&qp[b * C_ + c], a0);
  atomicAdd(&qp[b * C_ + c + 1], a1);
}

// ---------------------------------------------------------------- score logits
__global__ __launch_bounds__(256) void logits_kernel(const f16* __restrict__ Kh,
                                                     const float* __restrict__ qp,
                                                     float* __restrict__ score) {
  int wv = threadIdx.x >> 6, lane = threadIdx.x & 63;
  int token = blockIdx.x * 4 + wv;
  int b = token >> 12;
  int l = token & (L_ - 1);
  const f16* row = Kh + (size_t)token * C_;
  int h = lane >> 3, j0 = (lane & 7) * 8;
  const float* qph = qp + b * C_ + h * DH_ + j0;
  float p = 0.f;
#pragma unroll
  for (int j = 0; j < 8; ++j) p += qph[j] * (float)row[h * DH_ + j0 + j];
  p += __shfl_xor(p, 1); p += __shfl_xor(p, 2); p += __shfl_xor(p, 4);
  if ((lane & 7) == 0)
    score[((size_t)b * H_ + h) * LK_ + 1 + l] = p * (1.f / L_) * 0.125f;
}

__global__ __launch_bounds__(256) void softmax_kernel(float* __restrict__ score) {
  int bh = blockIdx.x, t = threadIdx.x;
  float* s = score + (size_t)bh * LK_;
  __shared__ float red[256];
  float mx = 0.f;
  for (int i = t; i < L_; i += 256) mx = fmaxf(mx, s[1 + i]);
  red[t] = mx; __syncthreads();
  for (int k = 128; k; k >>= 1) { if (t < k) red[t] = fmaxf(red[t], red[t + k]); __syncthreads(); }
  mx = red[0]; __syncthreads();
  float sum = (t == 0) ? expf(-mx) : 0.f;
  for (int i = t; i < L_; i += 256) { float e = expf(s[1 + i] - mx); s[1 + i] = e; sum += e; }
  red[t] = sum; __syncthreads();
  for (int k = 128; k; k >>= 1) { if (t < k) red[t] += red[t + k]; __syncthreads(); }
  float inv = 1.f / red[0];
  __syncthreads();
  for (int i = t; i < L_; i += 256) s[1 + i] *= inv;
  if (t == 0) s[0] = expf(-mx) * inv;
}

// ---------------------------------------------------------------- launch
extern "C" void kernel_launch(void* const* d_in, const int* in_sizes, int n_in,
                              void* d_out, int out_size, void* d_ws, size_t ws_size,
                              hipStream_t stream) {
  (void)in_sizes; (void)n_in; (void)out_size; (void)ws_size;
  const float* x     = (const float*)d_in[0];
  const float* Wq    = (const float*)d_in[1];
  const float* bq    = (const float*)d_in[2];
  const float* gq    = (const float*)d_in[3];
  const float* betaq = (const float*)d_in[4];
  const float* Wk    = (const float*)d_in[5];
  const float* bk    = (const float*)d_in[6];
  const float* gk    = (const float*)d_in[7];
  const float* betak = (const float*)d_in[8];
  const float* Wv    = (const float*)d_in[9];
  const float* bv    = (const float*)d_in[10];
  const float* gv    = (const float*)d_in[11];
  const float* betav = (const float*)d_in[12];
  const float* Wkq   = (const float*)d_in[13];
  const float* bkq   = (const float*)d_in[14];
  const float* Wkk   = (const float*)d_in[15];
  const float* bkk   = (const float*)d_in[16];
  const float* g_at  = (const float*)d_in[17];
  const float* b_at  = (const float*)d_in[18];
  const float* W1    = (const float*)d_in[19];
  const float* b1    = (const float*)d_in[20];
  const float* W2    = (const float*)d_in[21];
  const float* b2    = (const float*)d_in[22];
  float* out = (float*)d_out;

  char* ws = (char*)d_ws;
  size_t off = 0;
  auto alloc = [&](size_t bytes) -> void* {
    void* p = ws + off;
    off += (bytes + 255) & ~(size_t)255;
    return p;
  };
  f16* U1    = (f16*)alloc((size_t)BL_ * MLP_ * 2);       // 64 MB
  f16* QKVh  = (f16*)alloc((size_t)3 * BL_ * C_ * 2);     // 48 MB
  f16* phiQK = (f16*)alloc((size_t)2 * BL_ * C_ * 2);     // 32 MB
  f16* xf    = (f16*)alloc((size_t)BL_ * C_ * 2);         // 16 MB
  f16* WqkvT = (f16*)alloc((size_t)3 * C_ * C_ * 2);
  f16* WkqT  = (f16*)alloc((size_t)C_ * C_ * 2);
  f16* WkkT  = (f16*)alloc((size_t)C_ * C_ * 2);
  f16* W1T   = (f16*)alloc((size_t)C_ * MLP_ * 2);
  f16* W2T   = (f16*)alloc((size_t)MLP_ * C_ * 2);
  f16* kvt   = (f16*)alloc((size_t)B_ * H_ * DH_ * DH_ * 2);
  float* qp    = (float*)alloc((size_t)B_ * C_ * 4);          // 8 KB  \ one memset
  float* ksum  = (float*)alloc((size_t)B_ * H_ * DH_ * 4);    // 8 KB  / (adjacent)
  float* score = (float*)alloc((size_t)B_ * H_ * LK_ * 4);
  float* kvp   = (float*)alloc((size_t)B_ * H_ * 16 * 4096 * 4);
  float* bqkv    = (float*)alloc(1536 * 4);
  float* gqkv    = (float*)alloc(1536 * 4);
  float* betaqkv = (float*)alloc(1536 * 4);
  float* bphi    = (float*)alloc(1024 * 4);
  float* pk0t    = (float*)alloc(512 * 4);

  f16* tmpqkv = U1;
  f16* tmpA   = U1;
  f16* h1     = U1;
  f16* Qh = QKVh;
  f16* Kh = QKVh + (size_t)BL_ * C_;
  f16* Vh = QKVh + (size_t)2 * BL_ * C_;
  f16* ah = QKVh;
  f16* phiQ = phiQK;
  f16* phiK = phiQK + (size_t)BL_ * C_;

  dim3 blk(256);
  dim3 blk512(512);

  pack_params<<<6, blk, 0, stream>>>(bq, bk, bv, gq, gk, gv, betaq, betak, betav,
                                     bkq, bkk, bqkv, gqkv, betaqkv, bphi, pk0t);

  transpose_w5<<<dim3(16, 16, 5), blk, 0, stream>>>(Wq, Wk, Wv, Wkq, Wkk, WqkvT);
  transpose_w12<<<dim3(64, 16, 2), blk, 0, stream>>>(W1, W2, W1T, W2T);

  transpose_x<<<dim3(L_ / 32, C_ / 32, B_), blk, 0, stream>>>(x, xf);

  // fused QKV projection (256^2 counted-vmcnt + setprio)
  gemm256<5><<<dim3(BL_ / 256, 1536 / 256), blk512, 0, stream>>>(
      xf, WqkvT, bqkv, tmpqkv, 1536, C_, 0, 0, 0, 0);
  ln16<<<3 * BL_ / 4, blk, 0, stream>>>(tmpqkv, gqkv, betaqkv, QKVh, 1);

  // zero qp + ksum in one shot (adjacent allocations)
  hipMemsetAsync(qp, 0, (size_t)(B_ * C_ + B_ * H_ * DH_) * 4, stream);
  qprobe2<<<BL_ / 64, blk, 0, stream>>>(Qh, qp);

  // phi projections (m97-sbuf 128^2; grid = (N-tiles, M-tiles, z))
  gemm128s<1><<<dim3(C_ / 128, BL_ / 128, 2), blk, 0, stream>>>(
      Qh, WkqT, bphi, phiQ, C_, C_,
      (long long)BL_ * C_, (long long)C_ * C_, (long long)BL_ * C_, (long long)C_);

  logits_kernel<<<BL_ / 4, blk, 0, stream>>>(Kh, qp, score);
  softmax_kernel<<<B_ * H_, blk, 0, stream>>>(score);

  // kv partials + ksum via MFMA
  kv_mfma<<<dim3(16, B_ * H_), blk, 0, stream>>>(phiK, Vh, score, kvp, ksum);
  build_kvt<<<(B_ * H_ * DH_ * DH_) / 256, blk, 0, stream>>>(kvp, kvt);

  // attention out (bottom + zero-token ksum term fused)
  attn_out<<<dim3(BL_ / 128, H_), blk, 0, stream>>>(phiQ, kvt, ksum, score, pk0t, tmpA);

  ln16<<<BL_ / 4, blk, 0, stream>>>(tmpA, g_at, b_at, ah, 0);

  // MLP up (m97-sbuf 128^2; grid = (N-tiles, M-tiles))
  gemm128s<2><<<dim3(MLP_ / 128, BL_ / 128), blk, 0, stream>>>(
      ah, W1T, b1, h1, MLP_, C_, 0, 0, 0, 0);
  // MLP down fused with residual-add + transpose + x-add -> out (512-thr dbuf)
  gemm512d6<<<dim3(BL_ / 128, C_ / 128), blk512, 0, stream>>>(
      h1, W2T, b2, C_, MLP_, ah, x, out);
}